// Round 1
// baseline (8247.444 us; speedup 1.0000x reference)
//
#include <hip/hip_runtime.h>

namespace {

constexpr int kB = 64, kSR = 29, kS = 30, kD = 768, kH = 3072, kL = 12;
constexpr int kNH = 12, kND = 14, kE = 15, kRK = 8, kNE = 6;
constexpr int kRows = kB * kS;  // 1920

__device__ __forceinline__ float gelu_f(float x) {
  return 0.5f * x * (1.0f + erff(x * 0.70710678118654752f));
}

// Block-wide sum over 256 threads (4 waves of 64). Deterministic tree.
__device__ __forceinline__ float block_sum(float v) {
  __shared__ float sb[4];
#pragma unroll
  for (int o = 32; o > 0; o >>= 1) v += __shfl_down(v, o, 64);
  int w = threadIdx.x >> 6;
  __syncthreads();
  if ((threadIdx.x & 63) == 0) sb[w] = v;
  __syncthreads();
  return sb[0] + sb[1] + sb[2] + sb[3];
}

__device__ __forceinline__ float dot8(const float* __restrict__ p,
                                      const float* __restrict__ q) {
  float4 x = *(const float4*)p;
  float4 y = *(const float4*)(p + 4);
  return x.x * q[0] + x.y * q[1] + x.z * q[2] + x.w * q[3] +
         y.x * q[4] + y.y * q[5] + y.z * q[6] + y.w * q[7];
}

// ---------------------------------------------------------------------------
// C[M,N] = A[M,K] @ Bt[N,K]^T (+bias) (+gelu) (+res). K-major LDS tiles so the
// inner loop is pure float4 LDS reads + FMA. Optional batch via blockIdx.z
// strides, or split-K via blockIdx.z + atomicAdd (C must be pre-zeroed).
// ---------------------------------------------------------------------------
template <int BM, int TM, bool KSPLIT>
__global__ __launch_bounds__(256) void gemm_nt(
    const float* __restrict__ A, const float* __restrict__ Bt,
    const float* __restrict__ bias, const float* __restrict__ res,
    float* __restrict__ C, int M, int N, int K, int kspl, int act,
    long sA, long sB, long sBias, long sC) {
  constexpr int BN = 64;
  __shared__ float As[16][BM + 4];
  __shared__ float Bs[16][BN + 4];
  int tid = threadIdx.x;
  int n0 = blockIdx.x * BN;
  int m0 = blockIdx.y * BM;
  int bz = blockIdx.z;
  int k0 = 0, k1 = K;
  if (KSPLIT) {
    int kc = K / kspl;
    k0 = bz * kc;
    k1 = k0 + kc;
  } else {
    A += bz * sA;
    Bt += bz * sB;
    C += bz * sC;
    if (bias) bias += bz * sBias;
  }
  int tx = tid & 15, ty = tid >> 4;
  float acc[TM][4];
#pragma unroll
  for (int i = 0; i < TM; i++)
#pragma unroll
    for (int j = 0; j < 4; j++) acc[i][j] = 0.f;

  constexpr int APT = (BM * 4) / 256;  // float4 loads per thread for A tile
  int brow = tid >> 2, bk4 = (tid & 3) * 4;

  for (int kt = k0; kt < k1; kt += 16) {
#pragma unroll
    for (int q = 0; q < APT; q++) {
      int f4 = tid * APT + q;
      int row = f4 >> 2;
      int kk = (f4 & 3) * 4;
      float4 vA = make_float4(0.f, 0.f, 0.f, 0.f);
      if (m0 + row < M) vA = *(const float4*)&A[(long)(m0 + row) * K + kt + kk];
      As[kk + 0][row] = vA.x;
      As[kk + 1][row] = vA.y;
      As[kk + 2][row] = vA.z;
      As[kk + 3][row] = vA.w;
    }
    {
      float4 vB = make_float4(0.f, 0.f, 0.f, 0.f);
      if (n0 + brow < N) vB = *(const float4*)&Bt[(long)(n0 + brow) * K + kt + bk4];
      Bs[bk4 + 0][brow] = vB.x;
      Bs[bk4 + 1][brow] = vB.y;
      Bs[bk4 + 2][brow] = vB.z;
      Bs[bk4 + 3][brow] = vB.w;
    }
    __syncthreads();
#pragma unroll
    for (int kk = 0; kk < 16; kk++) {
      float4 b4 = *(const float4*)&Bs[kk][tx * 4];
      float a[TM];
#pragma unroll
      for (int p = 0; p < TM / 4; p++) {
        float4 a4 = *(const float4*)&As[kk][ty * TM + p * 4];
        a[p * 4 + 0] = a4.x;
        a[p * 4 + 1] = a4.y;
        a[p * 4 + 2] = a4.z;
        a[p * 4 + 3] = a4.w;
      }
#pragma unroll
      for (int i = 0; i < TM; i++) {
        acc[i][0] += a[i] * b4.x;
        acc[i][1] += a[i] * b4.y;
        acc[i][2] += a[i] * b4.z;
        acc[i][3] += a[i] * b4.w;
      }
    }
    __syncthreads();
  }

  int col = n0 + tx * 4;
  if (KSPLIT && kspl > 1) {
#pragma unroll
    for (int i = 0; i < TM; i++) {
      int row = m0 + ty * TM + i;
      if (row < M) {
#pragma unroll
        for (int j = 0; j < 4; j++)
          if (col + j < N) atomicAdd(&C[(long)row * N + col + j], acc[i][j]);
      }
    }
  } else {
    float4 bb = make_float4(0.f, 0.f, 0.f, 0.f);
    if (bias && col + 3 < N) bb = *(const float4*)&bias[col];
#pragma unroll
    for (int i = 0; i < TM; i++) {
      int row = m0 + ty * TM + i;
      if (row >= M) continue;
      float4 c;
      c.x = acc[i][0] + bb.x;
      c.y = acc[i][1] + bb.y;
      c.z = acc[i][2] + bb.z;
      c.w = acc[i][3] + bb.w;
      if (act == 1) {
        c.x = gelu_f(c.x);
        c.y = gelu_f(c.y);
        c.z = gelu_f(c.z);
        c.w = gelu_f(c.w);
      }
      if (res) {
        float4 r4 = *(const float4*)&res[(long)row * N + col];
        c.x += r4.x;
        c.y += r4.y;
        c.z += r4.z;
        c.w += r4.w;
      }
      if (col + 3 < N) {
        *(float4*)&C[(long)row * N + col] = c;
      } else {
        float cv[4] = {c.x, c.y, c.z, c.w};
        for (int j = 0; j < 4; j++)
          if (col + j < N) C[(long)row * N + col + j] = cv[j];
      }
    }
  }
}

// h = concat(cls, region_features)
__global__ __launch_bounds__(256) void concat_k(const float* __restrict__ rf,
                                                const float* __restrict__ cls,
                                                float* __restrict__ h) {
  int idx = blockIdx.x * 256 + threadIdx.x;
  if (idx >= kRows * kD) return;
  int d = idx % kD;
  int row = idx / kD;
  int s = row % kS;
  int b = row / kS;
  h[idx] = (s == 0) ? cls[d] : rf[((long)b * kSR + (s - 1)) * kD + d];
}

__global__ void cc_k(const float* __restrict__ mask, float* __restrict__ cc) {
  int d = threadIdx.x;
  if (d < kND) {
    float s = 0.f;
    for (int r = 0; r < kSR; r++) s += mask[r * kND + d];
    cc[d] = s;
  }
}

// M[g][rp][r] = sum_h A_down[g,rp,h] * B_up[g,h,r], g = le*15+e
__global__ __launch_bounds__(256) void mmat_k(const float* __restrict__ Adn,
                                              const float* __restrict__ Bup,
                                              float* __restrict__ Mm) {
  int g = blockIdx.x;
  int t = threadIdx.x;
  int pair = t & 63;
  int quarter = t >> 6;
  int rp = pair >> 3, r = pair & 7;
  const float* ad = Adn + (long)(g * 8 + rp) * kH;
  const float* bu = Bup + (long)g * kH * 8 + r;
  float acc = 0.f;
  for (int hh = quarter * 768; hh < quarter * 768 + 768; hh++)
    acc += ad[hh] * bu[hh * 8];
  __shared__ float red[256];
  red[t] = acc;
  __syncthreads();
  if (t < 64) Mm[g * 64 + pair] = red[t] + red[t + 64] + red[t + 128] + red[t + 192];
}

__global__ __launch_bounds__(256) void ln_row_k(const float* __restrict__ x,
                                                const float* __restrict__ g,
                                                const float* __restrict__ b,
                                                float* __restrict__ y, float eps) {
  int row = blockIdx.x;
  int t = threadIdx.x;
  const float* xr = x + (long)row * kD;
  float v0 = xr[t], v1 = xr[t + 256], v2 = xr[t + 512];
  float m = block_sum(v0 + v1 + v2) * (1.0f / 768.0f);
  float d0 = v0 - m, d1 = v1 - m, d2 = v2 - m;
  float q = block_sum(d0 * d0 + d1 * d1 + d2 * d2);
  float inv = rsqrtf(q * (1.0f / 768.0f) + eps);
  float* yr = y + (long)row * kD;
  yr[t] = d0 * inv * g[t] + b[t];
  yr[t + 256] = d1 * inv * g[t + 256] + b[t + 256];
  yr[t + 512] = d2 * inv * g[t + 512] + b[t + 512];
}

// res1 = a + h ; n2 = LN(res1)
__global__ __launch_bounds__(256) void addln_row_k(
    const float* __restrict__ a, const float* __restrict__ hh,
    const float* __restrict__ g, const float* __restrict__ b,
    float* __restrict__ r1, float* __restrict__ n2, float eps) {
  int row = blockIdx.x;
  int t = threadIdx.x;
  long rb = (long)row * kD;
  float v0 = a[rb + t] + hh[rb + t];
  float v1 = a[rb + t + 256] + hh[rb + t + 256];
  float v2 = a[rb + t + 512] + hh[rb + t + 512];
  r1[rb + t] = v0;
  r1[rb + t + 256] = v1;
  r1[rb + t + 512] = v2;
  float m = block_sum(v0 + v1 + v2) * (1.0f / 768.0f);
  float d0 = v0 - m, d1 = v1 - m, d2 = v2 - m;
  float q = block_sum(d0 * d0 + d1 * d1 + d2 * d2);
  float inv = rsqrtf(q * (1.0f / 768.0f) + eps);
  n2[rb + t] = d0 * inv * g[t] + b[t];
  n2[rb + t + 256] = d1 * inv * g[t + 256] + b[t + 256];
  n2[rb + t + 512] = d2 * inv * g[t + 512] + b[t + 512];
}

// One block per (b, head). S=30, dh=64.
__global__ __launch_bounds__(256) void attn_k(const float* __restrict__ q,
                                              const float* __restrict__ k,
                                              const float* __restrict__ v,
                                              float* __restrict__ o) {
  int blk = blockIdx.x;
  int b = blk / kNH, hh = blk % kNH;
  __shared__ float qs[30][65], ks[30][65], vs[30][65], ps[30][32];
  int t = threadIdx.x;
  long base = (long)b * kS * kD + hh * 64;
  for (int idx = t; idx < 1920; idx += 256) {
    int s = idx >> 6, d = idx & 63;
    long a = base + (long)s * kD + d;
    qs[s][d] = q[a];
    ks[s][d] = k[a];
    vs[s][d] = v[a];
  }
  __syncthreads();
  for (int idx = t; idx < 900; idx += 256) {
    int r = idx / 30, c = idx % 30;
    float acc = 0.f;
#pragma unroll
    for (int d = 0; d < 64; d++) acc += qs[r][d] * ks[c][d];
    ps[r][c] = acc * 0.125f;
  }
  __syncthreads();
  if (t < 30) {
    float mx = -1e30f;
#pragma unroll
    for (int c = 0; c < 30; c++) mx = fmaxf(mx, ps[t][c]);
    float sm = 0.f;
#pragma unroll
    for (int c = 0; c < 30; c++) sm += expf(ps[t][c] - mx);
    float inv = 1.0f / sm;
#pragma unroll
    for (int c = 0; c < 30; c++) ps[t][c] = expf(ps[t][c] - mx) * inv;
  }
  __syncthreads();
  for (int idx = t; idx < 1920; idx += 256) {
    int r = idx >> 6, d = idx & 63;
    float acc = 0.f;
#pragma unroll
    for (int c = 0; c < 30; c++) acc += ps[r][c] * vs[c][d];
    o[base + (long)r * kD + d] = acc;
  }
}

// pooled2[(d*64+b)*768+hd] = sum_r mask[r,d]*attnout[b,1+r,hd] / cc[d]
__global__ __launch_bounds__(256) void pool_k(const float* __restrict__ ao,
                                              const float* __restrict__ mask,
                                              const float* __restrict__ cc,
                                              float* __restrict__ pooled) {
  int blk = blockIdx.x;
  int d = blk >> 6, b = blk & 63;
  __shared__ float mr[32];
  int t = threadIdx.x;
  if (t < kSR) mr[t] = mask[t * kND + d];
  __syncthreads();
  float inv = 1.0f / cc[d];
  for (int hd = t; hd < kD; hd += 256) {
    float acc = 0.f;
    for (int r = 0; r < kSR; r++) acc += mr[r] * ao[((long)b * kS + 1 + r) * kD + hd];
    pooled[(long)blk * kD + hd] = acc * inv;
  }
}

// Per (d,b): LN(z) -> gelu -> dot cW2 -> +cb2 -> sigmoid>0.5 -> da[b,d]
__global__ __launch_bounds__(256) void cls2_k(const float* __restrict__ z,
                                              const float* __restrict__ lng,
                                              const float* __restrict__ lnb,
                                              const float* __restrict__ w2,
                                              const float* __restrict__ b2,
                                              float* __restrict__ da) {
  int blk = blockIdx.x;
  int d = blk >> 6, b = blk & 63;
  int t = threadIdx.x;
  const float* zr = z + (long)blk * 384;
  float v0 = zr[t];
  float v1 = (t < 128) ? zr[256 + t] : 0.f;
  float m = block_sum(v0 + v1) * (1.0f / 384.0f);
  float d0 = v0 - m;
  float d1 = (t < 128) ? v1 - m : 0.f;
  float q = block_sum(d0 * d0 + d1 * d1);
  float inv = rsqrtf(q * (1.0f / 384.0f) + 1e-5f);
  const float* lg = lng + (long)d * 384;
  const float* lb = lnb + (long)d * 384;
  const float* wd = w2 + (long)d * 384;
  float p = gelu_f(d0 * inv * lg[t] + lb[t]) * wd[t];
  if (t < 128) p += gelu_f(d1 * inv * lg[256 + t] + lb[256 + t]) * wd[256 + t];
  float ps = block_sum(p);
  if (t == 0) da[b * kND + d] = (ps + b2[d] > 0.f) ? 1.f : 0.f;
}

// vv = IA + SCALE * M_e @ u
__global__ __launch_bounds__(256) void vcomb_k(const float* __restrict__ u,
                                               const float* __restrict__ ia,
                                               const float* __restrict__ Mm,
                                               float* __restrict__ vv) {
  int idx = blockIdx.x * 256 + threadIdx.x;
  if (idx >= kRows * 120) return;
  int row = idx / 120, c = idx % 120;
  int e = c >> 3, rp = c & 7;
  const float* Me = Mm + e * 64 + rp * 8;
  const float* ur = u + (long)row * 120 + e * 8;
  float acc = ia[idx];
#pragma unroll
  for (int r = 0; r < 8; r++) acc += 2.0f * Me[r] * ur[r];
  vv[idx] = acc;
}

// Per (b,s): for each active expert e: y = base + 2*B_down[e]·vv ; LN_plain(y);
// accumulate weight_e * y_norm ; h = acc + res1.
__global__ __launch_bounds__(256) void finaleven_k(
    const float* __restrict__ base, const float* __restrict__ res1,
    const float* __restrict__ vv, const float* __restrict__ Bd,
    const float* __restrict__ da, const float* __restrict__ mask,
    float* __restrict__ h) {
  int row = blockIdx.x;
  int b = row / kS, s = row % kS;
  int t = threadIdx.x;
  __shared__ float w[16];
  __shared__ float vvs[120];
  if (t < 120) vvs[t] = vv[(long)row * 120 + t];
  if (t < kND) w[t] = (s >= 1) ? da[b * kND + t] * mask[(s - 1) * kND + t] : 0.f;
  if (t == kND) w[kND] = 1.f;
  __syncthreads();
  float wsum = 0.f;
#pragma unroll
  for (int e = 0; e < kE; e++) wsum += w[e];
  float winv = 1.0f / wsum;  // wsum >= 1 always
  long rb = (long)row * kD;
  float b0 = base[rb + t], b1 = base[rb + t + 256], b2v = base[rb + t + 512];
  float a0 = 0.f, a1 = 0.f, a2 = 0.f;
  for (int e = 0; e < kE; e++) {
    float we = w[e];
    if (we == 0.f) continue;
    const float* vr = vvs + e * 8;
    float y0 = b0 + 2.0f * dot8(Bd + ((long)(e * kD + t)) * 8, vr);
    float y1 = b1 + 2.0f * dot8(Bd + ((long)(e * kD + t + 256)) * 8, vr);
    float y2 = b2v + 2.0f * dot8(Bd + ((long)(e * kD + t + 512)) * 8, vr);
    float m = block_sum(y0 + y1 + y2) * (1.0f / 768.0f);
    float d0 = y0 - m, d1 = y1 - m, d2 = y2 - m;
    float q = block_sum(d0 * d0 + d1 * d1 + d2 * d2);
    float inv = rsqrtf(q * (1.0f / 768.0f) + 1e-5f);
    float sc = we * winv * inv;
    a0 += sc * d0;
    a1 += sc * d1;
    a2 += sc * d2;
  }
  h[rb + t] = a0 + res1[rb + t];
  h[rb + t + 256] = a1 + res1[rb + t + 256];
  h[rb + t + 512] = a2 + res1[rb + t + 512];
}

}  // namespace

extern "C" void kernel_launch(void* const* d_in, const int* in_sizes, int n_in,
                              void* d_out, int out_size, void* d_ws, size_t ws_size,
                              hipStream_t stream) {
  const float* region = (const float*)d_in[0];
  const float* mask = (const float*)d_in[1];
  const float* cls = (const float*)d_in[2];
  const float* ln1g = (const float*)d_in[3];
  const float* ln1b = (const float*)d_in[4];
  const float* ln2g = (const float*)d_in[5];
  const float* ln2b = (const float*)d_in[6];
  const float* Wq = (const float*)d_in[7];
  const float* bq = (const float*)d_in[8];
  const float* Wk = (const float*)d_in[9];
  const float* bk = (const float*)d_in[10];
  const float* Wv = (const float*)d_in[11];
  const float* bv = (const float*)d_in[12];
  const float* Wao = (const float*)d_in[13];
  const float* bao = (const float*)d_in[14];
  const float* Wi = (const float*)d_in[15];
  const float* bi = (const float*)d_in[16];
  const float* Wo = (const float*)d_in[17];
  const float* bo = (const float*)d_in[18];
  const float* fg = (const float*)d_in[19];
  const float* fb = (const float*)d_in[20];
  const float* cW1 = (const float*)d_in[21];
  const float* cb1 = (const float*)d_in[22];
  const float* clng = (const float*)d_in[23];
  const float* clnb = (const float*)d_in[24];
  const float* cW2 = (const float*)d_in[25];
  const float* cb2 = (const float*)d_in[26];
  const float* Aup = (const float*)d_in[27];
  const float* Bup = (const float*)d_in[28];
  const float* Adn = (const float*)d_in[29];
  const float* Bdn = (const float*)d_in[30];
  float* out = (float*)d_out;

  float* w = (float*)d_ws;
  float* h = w;      w += (long)kRows * kD;
  float* n1 = w;     w += (long)kRows * kD;  // also attention output (pre-proj)
  float* qb = w;     w += (long)kRows * kD;
  float* kb = w;     w += (long)kRows * kD;
  float* vb = w;     w += (long)kRows * kD;
  float* ao = w;     w += (long)kRows * kD;  // attn after Wao (ref `attn`)
  float* res1 = w;   w += (long)kRows * kD;
  float* n2 = w;     w += (long)kRows * kD;
  float* inter = w;  w += (long)kRows * kH;
  float* baseb = w;  w += (long)kRows * kD;
  float* pooled = w; w += (long)kND * kB * kD;
  float* zb = w;     w += (long)kND * kB * 384;
  float* da = w;     w += kB * kND;
  float* ub = w;     w += (long)kRows * 120;
  float* ia = w;     w += (long)kRows * 120;
  float* vvb = w;    w += (long)kRows * 120;
  float* Mm = w;     w += kNE * kE * 64;
  float* cc = w;     w += 16;

  concat_k<<<(kRows * kD + 255) / 256, 256, 0, stream>>>(region, cls, h);
  cc_k<<<1, 32, 0, stream>>>(mask, cc);
  mmat_k<<<kNE * kE, 256, 0, stream>>>(Adn, Bup, Mm);

  dim3 g64(12, 30);
  for (int i = 0; i < kL; i++) {
    int le = i >> 1;
    bool even = (i % 2) == 0;
    ln_row_k<<<kRows, 256, 0, stream>>>(h, ln1g + i * kD, ln1b + i * kD, n1, 1e-12f);
    gemm_nt<64, 4, false><<<g64, 256, 0, stream>>>(
        n1, Wq + (long)i * kD * kD, bq + i * kD, nullptr, qb, kRows, kD, kD, 1, 0, 0, 0, 0, 0);
    gemm_nt<64, 4, false><<<g64, 256, 0, stream>>>(
        n1, Wk + (long)i * kD * kD, bk + i * kD, nullptr, kb, kRows, kD, kD, 1, 0, 0, 0, 0, 0);
    gemm_nt<64, 4, false><<<g64, 256, 0, stream>>>(
        n1, Wv + (long)i * kD * kD, bv + i * kD, nullptr, vb, kRows, kD, kD, 1, 0, 0, 0, 0, 0);
    attn_k<<<kB * kNH, 256, 0, stream>>>(qb, kb, vb, n1);  // heads -> n1
    gemm_nt<64, 4, false><<<g64, 256, 0, stream>>>(
        n1, Wao + (long)i * kD * kD, bao + i * kD, nullptr, ao, kRows, kD, kD, 1, 0, 0, 0, 0, 0);
    addln_row_k<<<kRows, 256, 0, stream>>>(ao, h, ln2g + i * kD, ln2b + i * kD,
                                           res1, n2, 1e-12f);
    gemm_nt<128, 8, false><<<dim3(48, 15), 256, 0, stream>>>(
        n2, Wi + (long)i * kH * kD, bi + i * kH, nullptr, inter, kRows, kH, kD, 1, 1,
        0, 0, 0, 0);
    gemm_nt<64, 4, false><<<g64, 256, 0, stream>>>(
        inter, Wo + (long)i * kD * kH, bo + i * kD, even ? nullptr : res1,
        even ? baseb : h, kRows, kD, kH, 1, 0, 0, 0, 0, 0);
    if (even) {
      pool_k<<<kND * kB, 256, 0, stream>>>(ao, mask, cc, pooled);
      gemm_nt<64, 4, false><<<dim3(6, 1, kND), 256, 0, stream>>>(
          pooled, cW1 + (long)le * kND * 384 * kD, cb1 + (long)le * kND * 384,
          nullptr, zb, 64, 384, kD, 1, 0, (long)64 * kD, (long)384 * kD, 384,
          (long)64 * 384);
      cls2_k<<<kND * kB, 256, 0, stream>>>(zb, clng + (long)le * kND * 384,
                                           clnb + (long)le * kND * 384,
                                           cW2 + (long)le * kND * 384,
                                           cb2 + le * kND, da);
      hipMemsetAsync(ub, 0, (size_t)kRows * 120 * sizeof(float), stream);
      hipMemsetAsync(ia, 0, (size_t)kRows * 120 * sizeof(float), stream);
      gemm_nt<128, 8, true><<<dim3(2, 15, 4), 256, 0, stream>>>(
          n2, Aup + (long)le * kE * kRK * kD, nullptr, nullptr, ub, kRows, 120,
          kD, 4, 0, 0, 0, 0, 0);
      gemm_nt<128, 8, true><<<dim3(2, 15, 8), 256, 0, stream>>>(
          inter, Adn + (long)le * kE * kRK * kH, nullptr, nullptr, ia, kRows, 120,
          kH, 8, 0, 0, 0, 0, 0);
      vcomb_k<<<(kRows * 120 + 255) / 256, 256, 0, stream>>>(ub, ia,
                                                             Mm + le * kE * 64, vvb);
      finaleven_k<<<kRows, 256, 0, stream>>>(baseb, res1, vvb,
                                             Bdn + (long)le * kE * kD * kRK, da,
                                             mask, h);
    }
  }
  ln_row_k<<<kRows, 256, 0, stream>>>(h, fg, fb, out, 1e-12f);
}

// Round 2
// 4418.663 us; speedup vs baseline: 1.8665x; 1.8665x over previous
//
#include <hip/hip_runtime.h>

namespace {

constexpr int kB = 64, kSR = 29, kS = 30, kD = 768, kH = 3072, kL = 12;
constexpr int kNH = 12, kND = 14, kE = 15, kNE = 6;
constexpr int kRows = kB * kS;  // 1920

typedef __attribute__((ext_vector_type(8))) short s16x8;
typedef __attribute__((ext_vector_type(4))) float fx4;

__device__ __forceinline__ float gelu_f(float x) {
  return 0.5f * x * (1.0f + erff(x * 0.70710678118654752f));
}

__device__ __forceinline__ unsigned short f2bf_u(float x) {
  union { float f; unsigned u; } v;
  v.f = x;
  unsigned r = v.u + 0x7fffu + ((v.u >> 16) & 1u);
  return (unsigned short)(r >> 16);
}
__device__ __forceinline__ float bfu2f(unsigned short h) {
  union { unsigned u; float f; } v;
  v.u = ((unsigned)h) << 16;
  return v.f;
}

// Block-wide sum over 256 threads (4 waves of 64). Deterministic tree.
__device__ __forceinline__ float block_sum(float v) {
  __shared__ float sb[4];
#pragma unroll
  for (int o = 32; o > 0; o >>= 1) v += __shfl_down(v, o, 64);
  int w = threadIdx.x >> 6;
  __syncthreads();
  if ((threadIdx.x & 63) == 0) sb[w] = v;
  __syncthreads();
  return sb[0] + sb[1] + sb[2] + sb[3];
}

__device__ __forceinline__ float dot8(const float* __restrict__ p,
                                      const float* __restrict__ q) {
  float4 x = *(const float4*)p;
  float4 y = *(const float4*)(p + 4);
  return x.x * q[0] + x.y * q[1] + x.z * q[2] + x.w * q[3] +
         y.x * q[4] + y.y * q[5] + y.z * q[6] + y.w * q[7];
}

// ---------------------------------------------------------------------------
// MFMA GEMM, C[M,N] = A @ B^T with A,B given as hi/lo bf16 planes (3-pass
// split product: hh + hl + lh -> ~fp32 accuracy). BM=64, BK=32, BN=64|128.
// A planes: [M][K] bf16 bits. B planes: [N][K]. Epilogue: +bias, gelu, +res,
// write fp32 C and/or hi/lo bf16 planes. All dims divide tiles exactly.
// ---------------------------------------------------------------------------
template <int BN>
__global__ __launch_bounds__(256) void gemm_hl(
    const short* __restrict__ Ah, const short* __restrict__ Al,
    const short* __restrict__ Bh, const short* __restrict__ Bl,
    const float* __restrict__ bias, const float* __restrict__ res,
    float* __restrict__ Cf, short* __restrict__ Ch, short* __restrict__ Cl,
    int M, int K, int ldc, int act) {
  constexpr int FN = BN / 32;
  constexpr int BKP = 40;  // padded LDS row stride (bf16 elems)
  __shared__ short As[2][64 * BKP];
  __shared__ short Bs[2][BN * BKP];
  const int t = threadIdx.x;
  const int m0 = blockIdx.y * 64;
  const int n0 = blockIdx.x * BN;
  const int w = t >> 6, lane = t & 63;
  const int wm = (w & 1) * 32, wn = (w >> 1) * (BN / 2);
  const int lr = lane & 15, lk = (lane >> 4) * 8;

  fx4 acc[2][FN];
#pragma unroll
  for (int i = 0; i < 2; i++)
#pragma unroll
    for (int j = 0; j < FN; j++) acc[i][j] = (fx4)0.f;

  const int ar = t >> 2, ak = (t & 3) * 8;

  for (int kt = 0; kt < K; kt += 32) {
    *(uint4*)&As[0][ar * BKP + ak] =
        *(const uint4*)(Ah + (size_t)(m0 + ar) * K + kt + ak);
    *(uint4*)&As[1][ar * BKP + ak] =
        *(const uint4*)(Al + (size_t)(m0 + ar) * K + kt + ak);
#pragma unroll
    for (int q = 0; q < BN / 64; q++) {
      int s = q * 256 + t;
      int br = s >> 2, bk = (s & 3) * 8;
      *(uint4*)&Bs[0][br * BKP + bk] =
          *(const uint4*)(Bh + (size_t)(n0 + br) * K + kt + bk);
      *(uint4*)&Bs[1][br * BKP + bk] =
          *(const uint4*)(Bl + (size_t)(n0 + br) * K + kt + bk);
    }
    __syncthreads();
    s16x8 a0h = *(const s16x8*)&As[0][(wm + lr) * BKP + lk];
    s16x8 a0l = *(const s16x8*)&As[1][(wm + lr) * BKP + lk];
    s16x8 a1h = *(const s16x8*)&As[0][(wm + 16 + lr) * BKP + lk];
    s16x8 a1l = *(const s16x8*)&As[1][(wm + 16 + lr) * BKP + lk];
#pragma unroll
    for (int fn = 0; fn < FN; fn++) {
      s16x8 bh = *(const s16x8*)&Bs[0][(wn + fn * 16 + lr) * BKP + lk];
      s16x8 bl = *(const s16x8*)&Bs[1][(wn + fn * 16 + lr) * BKP + lk];
      acc[0][fn] = __builtin_amdgcn_mfma_f32_16x16x32_bf16(a0h, bh, acc[0][fn], 0, 0, 0);
      acc[0][fn] = __builtin_amdgcn_mfma_f32_16x16x32_bf16(a0h, bl, acc[0][fn], 0, 0, 0);
      acc[0][fn] = __builtin_amdgcn_mfma_f32_16x16x32_bf16(a0l, bh, acc[0][fn], 0, 0, 0);
      acc[1][fn] = __builtin_amdgcn_mfma_f32_16x16x32_bf16(a1h, bh, acc[1][fn], 0, 0, 0);
      acc[1][fn] = __builtin_amdgcn_mfma_f32_16x16x32_bf16(a1h, bl, acc[1][fn], 0, 0, 0);
      acc[1][fn] = __builtin_amdgcn_mfma_f32_16x16x32_bf16(a1l, bh, acc[1][fn], 0, 0, 0);
    }
    __syncthreads();
  }

  const int orow = (lane >> 4) * 4;
#pragma unroll
  for (int fm = 0; fm < 2; fm++) {
#pragma unroll
    for (int fn = 0; fn < FN; fn++) {
      int col = n0 + wn + fn * 16 + lr;
      float bv = bias ? bias[col] : 0.f;
#pragma unroll
      for (int j = 0; j < 4; j++) {
        int row = m0 + wm + fm * 16 + orow + j;
        float v = acc[fm][fn][j] + bv;
        if (act) v = gelu_f(v);
        size_t idx = (size_t)row * ldc + col;
        if (res) v += res[idx];
        if (Cf) Cf[idx] = v;
        if (Ch) {
          unsigned short hb = f2bf_u(v);
          Ch[idx] = (short)hb;
          Cl[idx] = (short)f2bf_u(v - bfu2f(hb));
        }
      }
    }
  }
}

// fp32 GEMM (kept for the small batched classifier GEMM).
template <int BM, int TM>
__global__ __launch_bounds__(256) void gemm_nt(
    const float* __restrict__ A, const float* __restrict__ Bt,
    const float* __restrict__ bias, float* __restrict__ C, int M, int N, int K,
    long sA, long sB, long sBias, long sC) {
  constexpr int BN = 64;
  __shared__ float As[16][BM + 4];
  __shared__ float Bs[16][BN + 4];
  int tid = threadIdx.x;
  int n0 = blockIdx.x * BN;
  int m0 = blockIdx.y * BM;
  int bz = blockIdx.z;
  A += bz * sA;
  Bt += bz * sB;
  C += bz * sC;
  if (bias) bias += bz * sBias;
  int tx = tid & 15, ty = tid >> 4;
  float acc[TM][4];
#pragma unroll
  for (int i = 0; i < TM; i++)
#pragma unroll
    for (int j = 0; j < 4; j++) acc[i][j] = 0.f;

  constexpr int APT = (BM * 4) / 256;
  int brow = tid >> 2, bk4 = (tid & 3) * 4;

  for (int kt = 0; kt < K; kt += 16) {
#pragma unroll
    for (int q = 0; q < APT; q++) {
      int f4 = tid * APT + q;
      int row = f4 >> 2;
      int kk = (f4 & 3) * 4;
      float4 vA = make_float4(0.f, 0.f, 0.f, 0.f);
      if (m0 + row < M) vA = *(const float4*)&A[(long)(m0 + row) * K + kt + kk];
      As[kk + 0][row] = vA.x;
      As[kk + 1][row] = vA.y;
      As[kk + 2][row] = vA.z;
      As[kk + 3][row] = vA.w;
    }
    {
      float4 vB = make_float4(0.f, 0.f, 0.f, 0.f);
      if (n0 + brow < N) vB = *(const float4*)&Bt[(long)(n0 + brow) * K + kt + bk4];
      Bs[bk4 + 0][brow] = vB.x;
      Bs[bk4 + 1][brow] = vB.y;
      Bs[bk4 + 2][brow] = vB.z;
      Bs[bk4 + 3][brow] = vB.w;
    }
    __syncthreads();
#pragma unroll
    for (int kk = 0; kk < 16; kk++) {
      float4 b4 = *(const float4*)&Bs[kk][tx * 4];
      float a[TM];
#pragma unroll
      for (int p = 0; p < TM / 4; p++) {
        float4 a4 = *(const float4*)&As[kk][ty * TM + p * 4];
        a[p * 4 + 0] = a4.x;
        a[p * 4 + 1] = a4.y;
        a[p * 4 + 2] = a4.z;
        a[p * 4 + 3] = a4.w;
      }
#pragma unroll
      for (int i = 0; i < TM; i++) {
        acc[i][0] += a[i] * b4.x;
        acc[i][1] += a[i] * b4.y;
        acc[i][2] += a[i] * b4.z;
        acc[i][3] += a[i] * b4.w;
      }
    }
    __syncthreads();
  }

  int col = n0 + tx * 4;
  float4 bb = make_float4(0.f, 0.f, 0.f, 0.f);
  if (bias && col + 3 < N) bb = *(const float4*)&bias[col];
#pragma unroll
  for (int i = 0; i < TM; i++) {
    int row = m0 + ty * TM + i;
    if (row >= M) continue;
    float4 c;
    c.x = acc[i][0] + bb.x;
    c.y = acc[i][1] + bb.y;
    c.z = acc[i][2] + bb.z;
    c.w = acc[i][3] + bb.w;
    if (col + 3 < N) {
      *(float4*)&C[(long)row * N + col] = c;
    } else {
      float cv[4] = {c.x, c.y, c.z, c.w};
      for (int j = 0; j < 4; j++)
        if (col + j < N) C[(long)row * N + col + j] = cv[j];
    }
  }
}

// Convert up to 4 equal-size fp32 matrices into hi/lo bf16 planes.
__global__ __launch_bounds__(256) void conv4_k(const float* s0, const float* s1,
                                               const float* s2, const float* s3,
                                               short* dh, short* dl, int n) {
  int m = blockIdx.y;
  const float* s = (m == 0) ? s0 : (m == 1) ? s1 : (m == 2) ? s2 : s3;
  int i = (blockIdx.x * 256 + threadIdx.x) * 4;
  if (i >= n) return;
  float4 v = *(const float4*)(s + i);
  short4 hv, lv;
  unsigned short h;
  h = f2bf_u(v.x); hv.x = (short)h; lv.x = (short)f2bf_u(v.x - bfu2f(h));
  h = f2bf_u(v.y); hv.y = (short)h; lv.y = (short)f2bf_u(v.y - bfu2f(h));
  h = f2bf_u(v.z); hv.z = (short)h; lv.z = (short)f2bf_u(v.z - bfu2f(h));
  h = f2bf_u(v.w); hv.w = (short)h; lv.w = (short)f2bf_u(v.w - bfu2f(h));
  *(short4*)(dh + (size_t)m * n + i) = hv;
  *(short4*)(dl + (size_t)m * n + i) = lv;
}

// Convert a 120xK fp32 matrix into padded 128xK hi/lo planes (rows 120..127 = 0).
__global__ __launch_bounds__(256) void convpad_k(const float* __restrict__ s,
                                                 short* __restrict__ dh,
                                                 short* __restrict__ dl, int K) {
  int i = (blockIdx.x * 256 + threadIdx.x) * 4;
  if (i >= 128 * K) return;
  float4 v = make_float4(0.f, 0.f, 0.f, 0.f);
  if (i < 120 * K) v = *(const float4*)(s + i);
  short4 hv, lv;
  unsigned short h;
  h = f2bf_u(v.x); hv.x = (short)h; lv.x = (short)f2bf_u(v.x - bfu2f(h));
  h = f2bf_u(v.y); hv.y = (short)h; lv.y = (short)f2bf_u(v.y - bfu2f(h));
  h = f2bf_u(v.z); hv.z = (short)h; lv.z = (short)f2bf_u(v.z - bfu2f(h));
  h = f2bf_u(v.w); hv.w = (short)h; lv.w = (short)f2bf_u(v.w - bfu2f(h));
  *(short4*)(dh + i) = hv;
  *(short4*)(dl + i) = lv;
}

// h = concat(cls, region_features)
__global__ __launch_bounds__(256) void concat_k(const float* __restrict__ rf,
                                                const float* __restrict__ cls,
                                                float* __restrict__ h) {
  int idx = blockIdx.x * 256 + threadIdx.x;
  if (idx >= kRows * kD) return;
  int d = idx % kD;
  int row = idx / kD;
  int s = row % kS;
  int b = row / kS;
  h[idx] = (s == 0) ? cls[d] : rf[((long)b * kSR + (s - 1)) * kD + d];
}

__global__ void cc_k(const float* __restrict__ mask, float* __restrict__ cc) {
  int d = threadIdx.x;
  if (d < kND) {
    float s = 0.f;
    for (int r = 0; r < kSR; r++) s += mask[r * kND + d];
    cc[d] = s;
  }
}

// M[g][rp][r] = sum_h A_down[g,rp,h] * B_up[g,h,r]
__global__ __launch_bounds__(256) void mmat_k(const float* __restrict__ Adn,
                                              const float* __restrict__ Bup,
                                              float* __restrict__ Mm) {
  int g = blockIdx.x;
  int t = threadIdx.x;
  int pair = t & 63;
  int quarter = t >> 6;
  int rp = pair >> 3, r = pair & 7;
  const float* ad = Adn + (long)(g * 8 + rp) * kH;
  const float* bu = Bup + (long)g * kH * 8 + r;
  float acc = 0.f;
  for (int hh = quarter * 768; hh < quarter * 768 + 768; hh++)
    acc += ad[hh] * bu[hh * 8];
  __shared__ float red[256];
  red[t] = acc;
  __syncthreads();
  if (t < 64) Mm[g * 64 + pair] = red[t] + red[t + 64] + red[t + 128] + red[t + 192];
}

// LN -> fp32 out (final layer)
__global__ __launch_bounds__(256) void ln_row_k(const float* __restrict__ x,
                                                const float* __restrict__ g,
                                                const float* __restrict__ b,
                                                float* __restrict__ y, float eps) {
  int row = blockIdx.x;
  int t = threadIdx.x;
  const float* xr = x + (long)row * kD;
  float v0 = xr[t], v1 = xr[t + 256], v2 = xr[t + 512];
  float m = block_sum(v0 + v1 + v2) * (1.0f / 768.0f);
  float d0 = v0 - m, d1 = v1 - m, d2 = v2 - m;
  float q = block_sum(d0 * d0 + d1 * d1 + d2 * d2);
  float inv = rsqrtf(q * (1.0f / 768.0f) + eps);
  float* yr = y + (long)row * kD;
  yr[t] = d0 * inv * g[t] + b[t];
  yr[t + 256] = d1 * inv * g[t + 256] + b[t + 256];
  yr[t + 512] = d2 * inv * g[t + 512] + b[t + 512];
}

// LN -> hi/lo bf16 planes
__global__ __launch_bounds__(256) void ln_bf_k(const float* __restrict__ x,
                                               const float* __restrict__ g,
                                               const float* __restrict__ b,
                                               short* __restrict__ yh,
                                               short* __restrict__ yl, float eps) {
  int row = blockIdx.x;
  int t = threadIdx.x;
  const float* xr = x + (long)row * kD;
  float v0 = xr[t], v1 = xr[t + 256], v2 = xr[t + 512];
  float m = block_sum(v0 + v1 + v2) * (1.0f / 768.0f);
  float d0 = v0 - m, d1 = v1 - m, d2 = v2 - m;
  float q = block_sum(d0 * d0 + d1 * d1 + d2 * d2);
  float inv = rsqrtf(q * (1.0f / 768.0f) + eps);
  long rb = (long)row * kD;
#pragma unroll
  for (int c = 0; c < 3; c++) {
    int tt = t + c * 256;
    float dd = (c == 0 ? d0 : c == 1 ? d1 : d2);
    float val = dd * inv * g[tt] + b[tt];
    unsigned short hb = f2bf_u(val);
    yh[rb + tt] = (short)hb;
    yl[rb + tt] = (short)f2bf_u(val - bfu2f(hb));
  }
}

// res1 = a + h ; n2 = LN(res1) -> hi/lo planes
__global__ __launch_bounds__(256) void addln_bf_k(
    const float* __restrict__ a, const float* __restrict__ hh,
    const float* __restrict__ g, const float* __restrict__ b,
    float* __restrict__ r1, short* __restrict__ n2h, short* __restrict__ n2l,
    float eps) {
  int row = blockIdx.x;
  int t = threadIdx.x;
  long rb = (long)row * kD;
  float v0 = a[rb + t] + hh[rb + t];
  float v1 = a[rb + t + 256] + hh[rb + t + 256];
  float v2 = a[rb + t + 512] + hh[rb + t + 512];
  r1[rb + t] = v0;
  r1[rb + t + 256] = v1;
  r1[rb + t + 512] = v2;
  float m = block_sum(v0 + v1 + v2) * (1.0f / 768.0f);
  float d0 = v0 - m, d1 = v1 - m, d2 = v2 - m;
  float q = block_sum(d0 * d0 + d1 * d1 + d2 * d2);
  float inv = rsqrtf(q * (1.0f / 768.0f) + eps);
#pragma unroll
  for (int c = 0; c < 3; c++) {
    int tt = t + c * 256;
    float dd = (c == 0 ? d0 : c == 1 ? d1 : d2);
    float val = dd * inv * g[tt] + b[tt];
    unsigned short hb = f2bf_u(val);
    n2h[rb + tt] = (short)hb;
    n2l[rb + tt] = (short)f2bf_u(val - bfu2f(hb));
  }
}

// One block per (b, head). S=30, dh=64. Output -> hi/lo bf16 planes.
__global__ __launch_bounds__(256) void attn_k(const float* __restrict__ q,
                                              const float* __restrict__ k,
                                              const float* __restrict__ v,
                                              short* __restrict__ oh,
                                              short* __restrict__ ol) {
  int blk = blockIdx.x;
  int b = blk / kNH, hh = blk % kNH;
  __shared__ float qs[30][65], ks[30][65], vs[30][65], ps[30][32];
  int t = threadIdx.x;
  long base = (long)b * kS * kD + hh * 64;
  for (int idx = t; idx < 1920; idx += 256) {
    int s = idx >> 6, d = idx & 63;
    long a = base + (long)s * kD + d;
    qs[s][d] = q[a];
    ks[s][d] = k[a];
    vs[s][d] = v[a];
  }
  __syncthreads();
  for (int idx = t; idx < 900; idx += 256) {
    int r = idx / 30, c = idx % 30;
    float acc = 0.f;
#pragma unroll
    for (int d = 0; d < 64; d++) acc += qs[r][d] * ks[c][d];
    ps[r][c] = acc * 0.125f;
  }
  __syncthreads();
  if (t < 30) {
    float mx = -1e30f;
#pragma unroll
    for (int c = 0; c < 30; c++) mx = fmaxf(mx, ps[t][c]);
    float sm = 0.f;
#pragma unroll
    for (int c = 0; c < 30; c++) sm += expf(ps[t][c] - mx);
    float inv = 1.0f / sm;
#pragma unroll
    for (int c = 0; c < 30; c++) ps[t][c] = expf(ps[t][c] - mx) * inv;
  }
  __syncthreads();
  for (int idx = t; idx < 1920; idx += 256) {
    int r = idx >> 6, d = idx & 63;
    float acc = 0.f;
#pragma unroll
    for (int c = 0; c < 30; c++) acc += ps[r][c] * vs[c][d];
    long a = base + (long)r * kD + d;
    unsigned short hb = f2bf_u(acc);
    oh[a] = (short)hb;
    ol[a] = (short)f2bf_u(acc - bfu2f(hb));
  }
}

// pooled[(d*64+b)*768+hd]
__global__ __launch_bounds__(256) void pool_k(const float* __restrict__ ao,
                                              const float* __restrict__ mask,
                                              const float* __restrict__ cc,
                                              float* __restrict__ pooled) {
  int blk = blockIdx.x;
  int d = blk >> 6, b = blk & 63;
  __shared__ float mr[32];
  int t = threadIdx.x;
  if (t < kSR) mr[t] = mask[t * kND + d];
  __syncthreads();
  float inv = 1.0f / cc[d];
  for (int hd = t; hd < kD; hd += 256) {
    float acc = 0.f;
    for (int r = 0; r < kSR; r++) acc += mr[r] * ao[((long)b * kS + 1 + r) * kD + hd];
    pooled[(long)blk * kD + hd] = acc * inv;
  }
}

// Per (d,b): LN(z) -> gelu -> dot cW2 -> +cb2 -> sigmoid>0.5 -> da[b,d]
__global__ __launch_bounds__(256) void cls2_k(const float* __restrict__ z,
                                              const float* __restrict__ lng,
                                              const float* __restrict__ lnb,
                                              const float* __restrict__ w2,
                                              const float* __restrict__ b2,
                                              float* __restrict__ da) {
  int blk = blockIdx.x;
  int d = blk >> 6, b = blk & 63;
  int t = threadIdx.x;
  const float* zr = z + (long)blk * 384;
  float v0 = zr[t];
  float v1 = (t < 128) ? zr[256 + t] : 0.f;
  float m = block_sum(v0 + v1) * (1.0f / 384.0f);
  float d0 = v0 - m;
  float d1 = (t < 128) ? v1 - m : 0.f;
  float q = block_sum(d0 * d0 + d1 * d1);
  float inv = rsqrtf(q * (1.0f / 384.0f) + 1e-5f);
  const float* lg = lng + (long)d * 384;
  const float* lb = lnb + (long)d * 384;
  const float* wd = w2 + (long)d * 384;
  float p = gelu_f(d0 * inv * lg[t] + lb[t]) * wd[t];
  if (t < 128) p += gelu_f(d1 * inv * lg[256 + t] + lb[256 + t]) * wd[256 + t];
  float ps = block_sum(p);
  if (t == 0) da[b * kND + d] = (ps + b2[d] > 0.f) ? 1.f : 0.f;
}

// vv = IA + SCALE * M_e @ u   (stride 128 buffers, 120 live cols)
__global__ __launch_bounds__(256) void vcomb_k(const float* __restrict__ u,
                                               const float* __restrict__ ia,
                                               const float* __restrict__ Mm,
                                               float* __restrict__ vv) {
  int idx = blockIdx.x * 256 + threadIdx.x;
  if (idx >= kRows * 120) return;
  int row = idx / 120, c = idx % 120;
  int e = c >> 3, rp = c & 7;
  const float* Me = Mm + e * 64 + rp * 8;
  const float* ur = u + (long)row * 128 + e * 8;
  float acc = ia[(long)row * 128 + c];
#pragma unroll
  for (int r = 0; r < 8; r++) acc += 2.0f * Me[r] * ur[r];
  vv[(long)row * 128 + c] = acc;
}

// Per (b,s): expert loop with plain-LN + weighted sum; h = acc + res1.
__global__ __launch_bounds__(256) void finaleven_k(
    const float* __restrict__ base, const float* __restrict__ res1,
    const float* __restrict__ vv, const float* __restrict__ Bd,
    const float* __restrict__ da, const float* __restrict__ mask,
    float* __restrict__ h) {
  int row = blockIdx.x;
  int b = row / kS, s = row % kS;
  int t = threadIdx.x;
  __shared__ float w[16];
  __shared__ float vvs[120];
  if (t < 120) vvs[t] = vv[(long)row * 128 + t];
  if (t < kND) w[t] = (s >= 1) ? da[b * kND + t] * mask[(s - 1) * kND + t] : 0.f;
  if (t == kND) w[kND] = 1.f;
  __syncthreads();
  float wsum = 0.f;
#pragma unroll
  for (int e = 0; e < kE; e++) wsum += w[e];
  float winv = 1.0f / wsum;
  long rb = (long)row * kD;
  float b0 = base[rb + t], b1 = base[rb + t + 256], b2v = base[rb + t + 512];
  float a0 = 0.f, a1 = 0.f, a2 = 0.f;
  for (int e = 0; e < kE; e++) {
    float we = w[e];
    if (we == 0.f) continue;
    const float* vr = vvs + e * 8;
    float y0 = b0 + 2.0f * dot8(Bd + ((long)(e * kD + t)) * 8, vr);
    float y1 = b1 + 2.0f * dot8(Bd + ((long)(e * kD + t + 256)) * 8, vr);
    float y2 = b2v + 2.0f * dot8(Bd + ((long)(e * kD + t + 512)) * 8, vr);
    float m = block_sum(y0 + y1 + y2) * (1.0f / 768.0f);
    float d0 = y0 - m, d1 = y1 - m, d2 = y2 - m;
    float q = block_sum(d0 * d0 + d1 * d1 + d2 * d2);
    float inv = rsqrtf(q * (1.0f / 768.0f) + 1e-5f);
    float sc = we * winv * inv;
    a0 += sc * d0;
    a1 += sc * d1;
    a2 += sc * d2;
  }
  h[rb + t] = a0 + res1[rb + t];
  h[rb + t + 256] = a1 + res1[rb + t + 256];
  h[rb + t + 512] = a2 + res1[rb + t + 512];
}

}  // namespace

extern "C" void kernel_launch(void* const* d_in, const int* in_sizes, int n_in,
                              void* d_out, int out_size, void* d_ws, size_t ws_size,
                              hipStream_t stream) {
  const float* region = (const float*)d_in[0];
  const float* mask = (const float*)d_in[1];
  const float* cls = (const float*)d_in[2];
  const float* ln1g = (const float*)d_in[3];
  const float* ln1b = (const float*)d_in[4];
  const float* ln2g = (const float*)d_in[5];
  const float* ln2b = (const float*)d_in[6];
  const float* Wq = (const float*)d_in[7];
  const float* bq = (const float*)d_in[8];
  const float* Wk = (const float*)d_in[9];
  const float* bk = (const float*)d_in[10];
  const float* Wv = (const float*)d_in[11];
  const float* bv = (const float*)d_in[12];
  const float* Wao = (const float*)d_in[13];
  const float* bao = (const float*)d_in[14];
  const float* Wi = (const float*)d_in[15];
  const float* bi = (const float*)d_in[16];
  const float* Wo = (const float*)d_in[17];
  const float* bo = (const float*)d_in[18];
  const float* fg = (const float*)d_in[19];
  const float* fb = (const float*)d_in[20];
  const float* cW1 = (const float*)d_in[21];
  const float* cb1 = (const float*)d_in[22];
  const float* clng = (const float*)d_in[23];
  const float* clnb = (const float*)d_in[24];
  const float* cW2 = (const float*)d_in[25];
  const float* cb2 = (const float*)d_in[26];
  const float* Aup = (const float*)d_in[27];
  const float* Bup = (const float*)d_in[28];
  const float* Adn = (const float*)d_in[29];
  const float* Bdn = (const float*)d_in[30];
  float* out = (float*)d_out;

  char* wsb = (char*)d_ws;
  size_t off = 0;
  auto alloc = [&](size_t bytes) {
    char* p = wsb + off;
    off = (off + bytes + 255) & ~(size_t)255;
    return (void*)p;
  };
  float* h = (float*)alloc((size_t)kRows * kD * 4);
  float* qb = (float*)alloc((size_t)kRows * kD * 4);
  float* kb = (float*)alloc((size_t)kRows * kD * 4);
  float* vb = (float*)alloc((size_t)kRows * kD * 4);
  float* ao = (float*)alloc((size_t)kRows * kD * 4);
  float* res1 = (float*)alloc((size_t)kRows * kD * 4);
  float* baseb = (float*)alloc((size_t)kRows * kD * 4);
  float* pooled = (float*)alloc((size_t)kND * kB * kD * 4);
  float* zb = (float*)alloc((size_t)kND * kB * 384 * 4);
  float* da = (float*)alloc((size_t)kB * kND * 4);
  float* ub = (float*)alloc((size_t)kRows * 128 * 4);
  float* ia = (float*)alloc((size_t)kRows * 128 * 4);
  float* vvb = (float*)alloc((size_t)kRows * 128 * 4);
  float* Mm = (float*)alloc((size_t)kNE * kE * 64 * 4);
  float* cc = (float*)alloc(64);
  short* n1h = (short*)alloc((size_t)kRows * kD * 2);
  short* n1l = (short*)alloc((size_t)kRows * kD * 2);
  short* n2h = (short*)alloc((size_t)kRows * kD * 2);
  short* n2l = (short*)alloc((size_t)kRows * kD * 2);
  short* inth = (short*)alloc((size_t)kRows * kH * 2);
  short* intl = (short*)alloc((size_t)kRows * kH * 2);
  short* wqkh = (short*)alloc((size_t)4 * kD * kD * 2);
  short* wqkl = (short*)alloc((size_t)4 * kD * kD * 2);
  short* wioh = (short*)alloc((size_t)2 * kD * kH * 2);
  short* wiol = (short*)alloc((size_t)2 * kD * kH * 2);
  short* luh = (short*)alloc((size_t)128 * kD * 2);
  short* lul = (short*)alloc((size_t)128 * kD * 2);
  short* ldh = (short*)alloc((size_t)128 * kH * 2);
  short* ldl = (short*)alloc((size_t)128 * kH * 2);

  concat_k<<<(kRows * kD + 255) / 256, 256, 0, stream>>>(region, cls, h);
  cc_k<<<1, 32, 0, stream>>>(mask, cc);
  mmat_k<<<kNE * kE, 256, 0, stream>>>(Adn, Bup, Mm);

  const int nDD = kD * kD;       // 589824
  const int nDH = kD * kH;       // 2359296
  dim3 gqkv(12, 30);             // N=768
  dim3 gwi(24, 30);              // N=3072
  dim3 glora(1, 30);             // N=128

  for (int i = 0; i < kL; i++) {
    int le = i >> 1;
    bool even = (i % 2) == 0;
    conv4_k<<<dim3(nDD / 1024, 4), 256, 0, stream>>>(
        Wq + (long)i * nDD, Wk + (long)i * nDD, Wv + (long)i * nDD,
        Wao + (long)i * nDD, wqkh, wqkl, nDD);
    conv4_k<<<dim3(nDH / 1024, 2), 256, 0, stream>>>(
        Wi + (long)i * nDH, Wo + (long)i * nDH, Wi, Wi, wioh, wiol, nDH);

    ln_bf_k<<<kRows, 256, 0, stream>>>(h, ln1g + i * kD, ln1b + i * kD, n1h, n1l,
                                       1e-12f);
    gemm_hl<64><<<gqkv, 256, 0, stream>>>(n1h, n1l, wqkh + 0L * nDD, wqkl + 0L * nDD,
                                          bq + i * kD, nullptr, qb, nullptr, nullptr,
                                          kRows, kD, kD, 0);
    gemm_hl<64><<<gqkv, 256, 0, stream>>>(n1h, n1l, wqkh + 1L * nDD, wqkl + 1L * nDD,
                                          bk + i * kD, nullptr, kb, nullptr, nullptr,
                                          kRows, kD, kD, 0);
    gemm_hl<64><<<gqkv, 256, 0, stream>>>(n1h, n1l, wqkh + 2L * nDD, wqkl + 2L * nDD,
                                          bv + i * kD, nullptr, vb, nullptr, nullptr,
                                          kRows, kD, kD, 0);
    attn_k<<<kB * kNH, 256, 0, stream>>>(qb, kb, vb, n1h, n1l);
    gemm_hl<64><<<gqkv, 256, 0, stream>>>(n1h, n1l, wqkh + 3L * nDD, wqkl + 3L * nDD,
                                          bao + i * kD, nullptr, ao, nullptr, nullptr,
                                          kRows, kD, kD, 0);
    addln_bf_k<<<kRows, 256, 0, stream>>>(ao, h, ln2g + i * kD, ln2b + i * kD, res1,
                                          n2h, n2l, 1e-12f);
    gemm_hl<128><<<gwi, 256, 0, stream>>>(n2h, n2l, wioh + 0L * nDH, wiol + 0L * nDH,
                                          bi + i * kH, nullptr, nullptr, inth, intl,
                                          kRows, kD, kH, 1);
    gemm_hl<64><<<gqkv, 256, 0, stream>>>(inth, intl, wioh + 1L * nDH, wiol + 1L * nDH,
                                          bo + i * kD, even ? nullptr : res1,
                                          even ? baseb : h, nullptr, nullptr, kRows,
                                          kH, kD, 0);
    if (even) {
      convpad_k<<<(128 * kD) / 1024, 256, 0, stream>>>(
          Aup + (long)le * kE * 8 * kD, luh, lul, kD);
      convpad_k<<<(128 * kH) / 1024, 256, 0, stream>>>(
          Adn + (long)le * kE * 8 * kH, ldh, ldl, kH);
      gemm_hl<128><<<glora, 256, 0, stream>>>(n2h, n2l, luh, lul, nullptr, nullptr,
                                              ub, nullptr, nullptr, kRows, kD, 128, 0);
      gemm_hl<128><<<glora, 256, 0, stream>>>(inth, intl, ldh, ldl, nullptr, nullptr,
                                              ia, nullptr, nullptr, kRows, kH, 128, 0);
      pool_k<<<kND * kB, 256, 0, stream>>>(ao, mask, cc, pooled);
      gemm_nt<64, 4><<<dim3(6, 1, kND), 256, 0, stream>>>(
          pooled, cW1 + (long)le * kND * 384 * kD, cb1 + (long)le * kND * 384, zb,
          64, 384, kD, (long)64 * kD, (long)384 * kD, 384, (long)64 * 384);
      cls2_k<<<kND * kB, 256, 0, stream>>>(zb, clng + (long)le * kND * 384,
                                           clnb + (long)le * kND * 384,
                                           cW2 + (long)le * kND * 384, cb2 + le * kND,
                                           da);
      vcomb_k<<<(kRows * 120 + 255) / 256, 256, 0, stream>>>(ub, ia, Mm + le * kE * 64,
                                                             vvb);
      finaleven_k<<<kRows, 256, 0, stream>>>(baseb, res1, vvb,
                                             Bdn + (long)le * kE * kD * 8, da, mask, h);
    }
  }
  ln_row_k<<<kRows, 256, 0, stream>>>(h, fg, fb, out, 1e-12f);
}

// Round 3
// 4105.492 us; speedup vs baseline: 2.0089x; 1.0763x over previous
//
#include <hip/hip_runtime.h>

namespace {

constexpr int kB = 64, kSR = 29, kS = 30, kD = 768, kH = 3072, kL = 12;
constexpr int kNH = 12, kND = 14, kE = 15, kNE = 6;
constexpr int kRows = kB * kS;  // 1920
constexpr int kQKV = 2304;

typedef __attribute__((ext_vector_type(8))) short s16x8;
typedef __attribute__((ext_vector_type(4))) float fx4;

__device__ __forceinline__ float gelu_f(float x) {
  return 0.5f * x * (1.0f + erff(x * 0.70710678118654752f));
}

__device__ __forceinline__ unsigned short f2bf_u(float x) {
  union { float f; unsigned u; } v;
  v.f = x;
  unsigned r = v.u + 0x7fffu + ((v.u >> 16) & 1u);
  return (unsigned short)(r >> 16);
}
__device__ __forceinline__ float bfu2f(unsigned short h) {
  union { unsigned u; float f; } v;
  v.u = ((unsigned)h) << 16;
  return v.f;
}

// async global->LDS, 16B per lane. LDS dest = uniform base + lane*16.
__device__ __forceinline__ void g2l16(const short* g, short* l) {
  __builtin_amdgcn_global_load_lds(
      (const __attribute__((address_space(1))) unsigned int*)g,
      (__attribute__((address_space(3))) unsigned int*)l, 16, 0, 0);
}

__device__ __forceinline__ float block_sum(float v) {
  __shared__ float sb[4];
#pragma unroll
  for (int o = 32; o > 0; o >>= 1) v += __shfl_down(v, o, 64);
  int w = threadIdx.x >> 6;
  __syncthreads();
  if ((threadIdx.x & 63) == 0) sb[w] = v;
  __syncthreads();
  return sb[0] + sb[1] + sb[2] + sb[3];
}

__device__ __forceinline__ float dot8(const float* __restrict__ p,
                                      const float* __restrict__ q) {
  float4 x = *(const float4*)p;
  float4 y = *(const float4*)(p + 4);
  return x.x * q[0] + x.y * q[1] + x.z * q[2] + x.w * q[3] +
         y.x * q[4] + y.y * q[5] + y.z * q[6] + y.w * q[7];
}

// ---------------------------------------------------------------------------
// MFMA GEMM, C = A @ B^T, hi/lo bf16 planes, 3-pass (hh+hl+lh ~ fp32).
// Tile 64 x BN, BK=32, 4 waves (2x2), wave tile 32 x BN/2.
// LDS is fragment-contiguous (1KB per 16x32 frag, lane-linear) staged via
// global_load_lds with per-lane gathered global addresses -> conflict-free
// ds_read_b128 on both sides. All dims divide tiles exactly; no bounds checks.
// KSPLIT: blockIdx.z k-chunk + fp32 atomicAdd into pre-zeroed Cf.
// ---------------------------------------------------------------------------
template <int BN, bool KSPLIT>
__global__ __launch_bounds__(256) void gemm_hl(
    const short* __restrict__ Ah, const short* __restrict__ Al,
    const short* __restrict__ Bh, const short* __restrict__ Bl,
    const float* __restrict__ bias, const float* __restrict__ res,
    float* __restrict__ Cf, short* __restrict__ Ch, short* __restrict__ Cl,
    int K, int ldc, int act, int kchunk) {
  constexpr int NFRAG = BN / 16;        // 4 or 8
  constexpr int NF_W = NFRAG / 2;       // n-frags per wave
  constexpr int LPW = (8 + 2 * NFRAG) / 4;
  __shared__ __align__(16) short As[2][4][512];
  __shared__ __align__(16) short Bs[2][NFRAG][512];
  const int t = threadIdx.x, w = t >> 6, lane = t & 63;
  const int lr = lane & 15, lg = lane >> 4;
  const int m0 = blockIdx.y * 64, n0 = blockIdx.x * BN;
  const int k0 = KSPLIT ? blockIdx.z * kchunk : 0;
  const int nsteps = (KSPLIT ? kchunk : K) / 32;
  const int wm = (w & 1) * 32;
  const int mf0 = (w & 1) * 2;
  const int wnf = (w >> 1) * NF_W;

  const short* gp[LPW];
  short* lp[LPW];
#pragma unroll
  for (int q = 0; q < LPW; q++) {
    int f = w * LPW + q;
    if (f < 8) {
      int p = f & 1, mf = f >> 1;
      gp[q] = (p ? Al : Ah) + (size_t)(m0 + mf * 16 + lr) * K + k0 + lg * 8;
      lp[q] = &As[p][mf][0];
    } else {
      int fb = f - 8, p = fb & 1, nf = fb >> 1;
      gp[q] = (p ? Bl : Bh) + (size_t)(n0 + nf * 16 + lr) * K + k0 + lg * 8;
      lp[q] = &Bs[p][nf][0];
    }
  }

  fx4 acc[2][NF_W];
#pragma unroll
  for (int i = 0; i < 2; i++)
#pragma unroll
    for (int j = 0; j < NF_W; j++) acc[i][j] = (fx4)0.f;

  for (int s = 0; s < nsteps; s++) {
#pragma unroll
    for (int q = 0; q < LPW; q++) {
      g2l16(gp[q], lp[q]);
      gp[q] += 32;
    }
    __syncthreads();
    s16x8 af[2][2], bf[NF_W][2];
#pragma unroll
    for (int fm = 0; fm < 2; fm++) {
      af[fm][0] = *(const s16x8*)&As[0][mf0 + fm][lane * 8];
      af[fm][1] = *(const s16x8*)&As[1][mf0 + fm][lane * 8];
    }
#pragma unroll
    for (int fn = 0; fn < NF_W; fn++) {
      bf[fn][0] = *(const s16x8*)&Bs[0][wnf + fn][lane * 8];
      bf[fn][1] = *(const s16x8*)&Bs[1][wnf + fn][lane * 8];
    }
#pragma unroll
    for (int fm = 0; fm < 2; fm++)
#pragma unroll
      for (int fn = 0; fn < NF_W; fn++) {
        acc[fm][fn] = __builtin_amdgcn_mfma_f32_16x16x32_bf16(af[fm][0], bf[fn][0], acc[fm][fn], 0, 0, 0);
        acc[fm][fn] = __builtin_amdgcn_mfma_f32_16x16x32_bf16(af[fm][0], bf[fn][1], acc[fm][fn], 0, 0, 0);
        acc[fm][fn] = __builtin_amdgcn_mfma_f32_16x16x32_bf16(af[fm][1], bf[fn][0], acc[fm][fn], 0, 0, 0);
      }
    __syncthreads();
  }

  const int orow = (lane >> 4) * 4;
#pragma unroll
  for (int fm = 0; fm < 2; fm++) {
#pragma unroll
    for (int fn = 0; fn < NF_W; fn++) {
      int col = n0 + (wnf + fn) * 16 + lr;
      if (KSPLIT) {
#pragma unroll
        for (int j = 0; j < 4; j++) {
          int row = m0 + wm + fm * 16 + orow + j;
          atomicAdd(&Cf[(size_t)row * ldc + col], acc[fm][fn][j]);
        }
      } else {
        float bv = bias ? bias[col] : 0.f;
#pragma unroll
        for (int j = 0; j < 4; j++) {
          int row = m0 + wm + fm * 16 + orow + j;
          float v = acc[fm][fn][j] + bv;
          if (act) v = gelu_f(v);
          size_t idx = (size_t)row * ldc + col;
          if (res) v += res[idx];
          if (Cf) Cf[idx] = v;
          if (Ch) {
            unsigned short hb = f2bf_u(v);
            Ch[idx] = (short)hb;
            Cl[idx] = (short)f2bf_u(v - bfu2f(hb));
          }
        }
      }
    }
  }
}

// fp32 GEMM (small batched classifier GEMM only).
template <int BM, int TM>
__global__ __launch_bounds__(256) void gemm_nt(
    const float* __restrict__ A, const float* __restrict__ Bt,
    const float* __restrict__ bias, float* __restrict__ C, int M, int N, int K,
    long sA, long sB, long sBias, long sC) {
  constexpr int BN = 64;
  __shared__ float As[16][BM + 4];
  __shared__ float Bs[16][BN + 4];
  int tid = threadIdx.x;
  int n0 = blockIdx.x * BN;
  int m0 = blockIdx.y * BM;
  int bz = blockIdx.z;
  A += bz * sA;
  Bt += bz * sB;
  C += bz * sC;
  if (bias) bias += bz * sBias;
  int tx = tid & 15, ty = tid >> 4;
  float acc[TM][4];
#pragma unroll
  for (int i = 0; i < TM; i++)
#pragma unroll
    for (int j = 0; j < 4; j++) acc[i][j] = 0.f;

  constexpr int APT = (BM * 4) / 256;
  int brow = tid >> 2, bk4 = (tid & 3) * 4;

  for (int kt = 0; kt < K; kt += 16) {
#pragma unroll
    for (int q = 0; q < APT; q++) {
      int f4 = tid * APT + q;
      int row = f4 >> 2;
      int kk = (f4 & 3) * 4;
      float4 vA = make_float4(0.f, 0.f, 0.f, 0.f);
      if (m0 + row < M) vA = *(const float4*)&A[(long)(m0 + row) * K + kt + kk];
      As[kk + 0][row] = vA.x;
      As[kk + 1][row] = vA.y;
      As[kk + 2][row] = vA.z;
      As[kk + 3][row] = vA.w;
    }
    {
      float4 vB = make_float4(0.f, 0.f, 0.f, 0.f);
      if (n0 + brow < N) vB = *(const float4*)&Bt[(long)(n0 + brow) * K + kt + bk4];
      Bs[bk4 + 0][brow] = vB.x;
      Bs[bk4 + 1][brow] = vB.y;
      Bs[bk4 + 2][brow] = vB.z;
      Bs[bk4 + 3][brow] = vB.w;
    }
    __syncthreads();
#pragma unroll
    for (int kk = 0; kk < 16; kk++) {
      float4 b4 = *(const float4*)&Bs[kk][tx * 4];
      float a[TM];
#pragma unroll
      for (int p = 0; p < TM / 4; p++) {
        float4 a4 = *(const float4*)&As[kk][ty * TM + p * 4];
        a[p * 4 + 0] = a4.x;
        a[p * 4 + 1] = a4.y;
        a[p * 4 + 2] = a4.z;
        a[p * 4 + 3] = a4.w;
      }
#pragma unroll
      for (int i = 0; i < TM; i++) {
        acc[i][0] += a[i] * b4.x;
        acc[i][1] += a[i] * b4.y;
        acc[i][2] += a[i] * b4.z;
        acc[i][3] += a[i] * b4.w;
      }
    }
    __syncthreads();
  }

  int col = n0 + tx * 4;
  float4 bb = make_float4(0.f, 0.f, 0.f, 0.f);
  if (bias && col + 3 < N) bb = *(const float4*)&bias[col];
#pragma unroll
  for (int i = 0; i < TM; i++) {
    int row = m0 + ty * TM + i;
    if (row >= M) continue;
    float4 c;
    c.x = acc[i][0] + bb.x;
    c.y = acc[i][1] + bb.y;
    c.z = acc[i][2] + bb.z;
    c.w = acc[i][3] + bb.w;
    if (col + 3 < N) {
      *(float4*)&C[(long)row * N + col] = c;
    } else {
      float cv[4] = {c.x, c.y, c.z, c.w};
      for (int j = 0; j < 4; j++)
        if (col + j < N) C[(long)row * N + col + j] = cv[j];
    }
  }
}

__global__ __launch_bounds__(256) void conv4_k(const float* s0, const float* s1,
                                               const float* s2, const float* s3,
                                               short* dh, short* dl, int n) {
  int m = blockIdx.y;
  const float* s = (m == 0) ? s0 : (m == 1) ? s1 : (m == 2) ? s2 : s3;
  int i = (blockIdx.x * 256 + threadIdx.x) * 4;
  if (i >= n) return;
  float4 v = *(const float4*)(s + i);
  short4 hv, lv;
  unsigned short h;
  h = f2bf_u(v.x); hv.x = (short)h; lv.x = (short)f2bf_u(v.x - bfu2f(h));
  h = f2bf_u(v.y); hv.y = (short)h; lv.y = (short)f2bf_u(v.y - bfu2f(h));
  h = f2bf_u(v.z); hv.z = (short)h; lv.z = (short)f2bf_u(v.z - bfu2f(h));
  h = f2bf_u(v.w); hv.w = (short)h; lv.w = (short)f2bf_u(v.w - bfu2f(h));
  *(short4*)(dh + (size_t)m * n + i) = hv;
  *(short4*)(dl + (size_t)m * n + i) = lv;
}

__global__ __launch_bounds__(256) void convpad_k(const float* __restrict__ s,
                                                 short* __restrict__ dh,
                                                 short* __restrict__ dl, int K) {
  int i = (blockIdx.x * 256 + threadIdx.x) * 4;
  if (i >= 128 * K) return;
  float4 v = make_float4(0.f, 0.f, 0.f, 0.f);
  if (i < 120 * K) v = *(const float4*)(s + i);
  short4 hv, lv;
  unsigned short h;
  h = f2bf_u(v.x); hv.x = (short)h; lv.x = (short)f2bf_u(v.x - bfu2f(h));
  h = f2bf_u(v.y); hv.y = (short)h; lv.y = (short)f2bf_u(v.y - bfu2f(h));
  h = f2bf_u(v.z); hv.z = (short)h; lv.z = (short)f2bf_u(v.z - bfu2f(h));
  h = f2bf_u(v.w); hv.w = (short)h; lv.w = (short)f2bf_u(v.w - bfu2f(h));
  *(short4*)(dh + i) = hv;
  *(short4*)(dl + i) = lv;
}

__global__ __launch_bounds__(256) void concat_k(const float* __restrict__ rf,
                                                const float* __restrict__ cls,
                                                float* __restrict__ h) {
  int idx = blockIdx.x * 256 + threadIdx.x;
  if (idx >= kRows * kD) return;
  int d = idx % kD;
  int row = idx / kD;
  int s = row % kS;
  int b = row / kS;
  h[idx] = (s == 0) ? cls[d] : rf[((long)b * kSR + (s - 1)) * kD + d];
}

__global__ void cc_k(const float* __restrict__ mask, float* __restrict__ cc) {
  int d = threadIdx.x;
  if (d < kND) {
    float s = 0.f;
    for (int r = 0; r < kSR; r++) s += mask[r * kND + d];
    cc[d] = s;
  }
}

__global__ __launch_bounds__(256) void mmat_k(const float* __restrict__ Adn,
                                              const float* __restrict__ Bup,
                                              float* __restrict__ Mm) {
  int g = blockIdx.x;
  int t = threadIdx.x;
  int pair = t & 63;
  int quarter = t >> 6;
  int rp = pair >> 3, r = pair & 7;
  const float* ad = Adn + (long)(g * 8 + rp) * kH;
  const float* bu = Bup + (long)g * kH * 8 + r;
  float acc = 0.f;
  for (int hh = quarter * 768; hh < quarter * 768 + 768; hh++)
    acc += ad[hh] * bu[hh * 8];
  __shared__ float red[256];
  red[t] = acc;
  __syncthreads();
  if (t < 64) Mm[g * 64 + pair] = red[t] + red[t + 64] + red[t + 128] + red[t + 192];
}

// LN -> hi/lo bf16 planes. Optional fused pre-add: x = c2 + b2 + r2 (written
// to hout) when c2 != null, else x read directly.
__global__ __launch_bounds__(256) void ln_bf_k(
    const float* __restrict__ x, const float* __restrict__ c2,
    const float* __restrict__ b2, const float* __restrict__ r2,
    float* __restrict__ hout, const float* __restrict__ g,
    const float* __restrict__ b, short* __restrict__ yh,
    short* __restrict__ yl, float eps) {
  int row = blockIdx.x;
  int t = threadIdx.x;
  long rb = (long)row * kD;
  float v0, v1, v2;
  if (c2) {
    v0 = c2[rb + t] + b2[t] + r2[rb + t];
    v1 = c2[rb + t + 256] + b2[t + 256] + r2[rb + t + 256];
    v2 = c2[rb + t + 512] + b2[t + 512] + r2[rb + t + 512];
    hout[rb + t] = v0;
    hout[rb + t + 256] = v1;
    hout[rb + t + 512] = v2;
  } else {
    v0 = x[rb + t];
    v1 = x[rb + t + 256];
    v2 = x[rb + t + 512];
  }
  float m = block_sum(v0 + v1 + v2) * (1.0f / 768.0f);
  float d0 = v0 - m, d1 = v1 - m, d2 = v2 - m;
  float q = block_sum(d0 * d0 + d1 * d1 + d2 * d2);
  float inv = rsqrtf(q * (1.0f / 768.0f) + eps);
#pragma unroll
  for (int c = 0; c < 3; c++) {
    int tt = t + c * 256;
    float dd = (c == 0 ? d0 : c == 1 ? d1 : d2);
    float val = dd * inv * g[tt] + b[tt];
    unsigned short hb = f2bf_u(val);
    yh[rb + tt] = (short)hb;
    yl[rb + tt] = (short)f2bf_u(val - bfu2f(hb));
  }
}

// Final LN -> fp32 out, fused h = c2 + b2 + r2.
__global__ __launch_bounds__(256) void ln_row_k(
    const float* __restrict__ c2, const float* __restrict__ b2,
    const float* __restrict__ r2, const float* __restrict__ g,
    const float* __restrict__ b, float* __restrict__ y, float eps) {
  int row = blockIdx.x;
  int t = threadIdx.x;
  long rb = (long)row * kD;
  float v0 = c2[rb + t] + b2[t] + r2[rb + t];
  float v1 = c2[rb + t + 256] + b2[t + 256] + r2[rb + t + 256];
  float v2 = c2[rb + t + 512] + b2[t + 512] + r2[rb + t + 512];
  float m = block_sum(v0 + v1 + v2) * (1.0f / 768.0f);
  float d0 = v0 - m, d1 = v1 - m, d2 = v2 - m;
  float q = block_sum(d0 * d0 + d1 * d1 + d2 * d2);
  float inv = rsqrtf(q * (1.0f / 768.0f) + eps);
  y[rb + t] = d0 * inv * g[t] + b[t];
  y[rb + t + 256] = d1 * inv * g[t + 256] + b[t + 256];
  y[rb + t + 512] = d2 * inv * g[t + 512] + b[t + 512];
}

// res1 = a + h ; n2 = LN(res1) -> hi/lo planes
__global__ __launch_bounds__(256) void addln_bf_k(
    const float* __restrict__ a, const float* __restrict__ hh,
    const float* __restrict__ g, const float* __restrict__ b,
    float* __restrict__ r1, short* __restrict__ n2h, short* __restrict__ n2l,
    float eps) {
  int row = blockIdx.x;
  int t = threadIdx.x;
  long rb = (long)row * kD;
  float v0 = a[rb + t] + hh[rb + t];
  float v1 = a[rb + t + 256] + hh[rb + t + 256];
  float v2 = a[rb + t + 512] + hh[rb + t + 512];
  r1[rb + t] = v0;
  r1[rb + t + 256] = v1;
  r1[rb + t + 512] = v2;
  float m = block_sum(v0 + v1 + v2) * (1.0f / 768.0f);
  float d0 = v0 - m, d1 = v1 - m, d2 = v2 - m;
  float q = block_sum(d0 * d0 + d1 * d1 + d2 * d2);
  float inv = rsqrtf(q * (1.0f / 768.0f) + eps);
#pragma unroll
  for (int c = 0; c < 3; c++) {
    int tt = t + c * 256;
    float dd = (c == 0 ? d0 : c == 1 ? d1 : d2);
    float val = dd * inv * g[tt] + b[tt];
    unsigned short hb = f2bf_u(val);
    n2h[rb + tt] = (short)hb;
    n2l[rb + tt] = (short)f2bf_u(val - bfu2f(hb));
  }
}

// One block per (b, head). Reads packed qkv [1920][2304], adds biases inline.
__global__ __launch_bounds__(256) void attn_k(const float* __restrict__ qkv,
                                              const float* __restrict__ bq,
                                              const float* __restrict__ bk,
                                              const float* __restrict__ bv,
                                              short* __restrict__ oh,
                                              short* __restrict__ ol) {
  int blk = blockIdx.x;
  int b = blk / kNH, hh = blk % kNH;
  __shared__ float qs[30][65], ks[30][65], vs[30][65], ps[30][32];
  int t = threadIdx.x;
  long ibase = (long)b * kS * kQKV + hh * 64;
  long obase = (long)b * kS * kD + hh * 64;
  for (int idx = t; idx < 1920; idx += 256) {
    int s = idx >> 6, d = idx & 63;
    long a = ibase + (long)s * kQKV + d;
    int bcol = hh * 64 + d;
    qs[s][d] = qkv[a] + bq[bcol];
    ks[s][d] = qkv[a + 768] + bk[bcol];
    vs[s][d] = qkv[a + 1536] + bv[bcol];
  }
  __syncthreads();
  for (int idx = t; idx < 900; idx += 256) {
    int r = idx / 30, c = idx % 30;
    float acc = 0.f;
#pragma unroll
    for (int d = 0; d < 64; d++) acc += qs[r][d] * ks[c][d];
    ps[r][c] = acc * 0.125f;
  }
  __syncthreads();
  if (t < 30) {
    float mx = -1e30f;
#pragma unroll
    for (int c = 0; c < 30; c++) mx = fmaxf(mx, ps[t][c]);
    float sm = 0.f;
#pragma unroll
    for (int c = 0; c < 30; c++) sm += expf(ps[t][c] - mx);
    float inv = 1.0f / sm;
#pragma unroll
    for (int c = 0; c < 30; c++) ps[t][c] = expf(ps[t][c] - mx) * inv;
  }
  __syncthreads();
  for (int idx = t; idx < 1920; idx += 256) {
    int r = idx >> 6, d = idx & 63;
    float acc = 0.f;
#pragma unroll
    for (int c = 0; c < 30; c++) acc += ps[r][c] * vs[c][d];
    long a = obase + (long)r * kD + d;
    unsigned short hb = f2bf_u(acc);
    oh[a] = (short)hb;
    ol[a] = (short)f2bf_u(acc - bfu2f(hb));
  }
}

__global__ __launch_bounds__(256) void pool_k(const float* __restrict__ ao,
                                              const float* __restrict__ mask,
                                              const float* __restrict__ cc,
                                              float* __restrict__ pooled) {
  int blk = blockIdx.x;
  int d = blk >> 6, b = blk & 63;
  __shared__ float mr[32];
  int t = threadIdx.x;
  if (t < kSR) mr[t] = mask[t * kND + d];
  __syncthreads();
  float inv = 1.0f / cc[d];
  for (int hd = t; hd < kD; hd += 256) {
    float acc = 0.f;
    for (int r = 0; r < kSR; r++) acc += mr[r] * ao[((long)b * kS + 1 + r) * kD + hd];
    pooled[(long)blk * kD + hd] = acc * inv;
  }
}

__global__ __launch_bounds__(256) void cls2_k(const float* __restrict__ z,
                                              const float* __restrict__ lng,
                                              const float* __restrict__ lnb,
                                              const float* __restrict__ w2,
                                              const float* __restrict__ b2,
                                              float* __restrict__ da) {
  int blk = blockIdx.x;
  int d = blk >> 6, b = blk & 63;
  int t = threadIdx.x;
  const float* zr = z + (long)blk * 384;
  float v0 = zr[t];
  float v1 = (t < 128) ? zr[256 + t] : 0.f;
  float m = block_sum(v0 + v1) * (1.0f / 384.0f);
  float d0 = v0 - m;
  float d1 = (t < 128) ? v1 - m : 0.f;
  float q = block_sum(d0 * d0 + d1 * d1);
  float inv = rsqrtf(q * (1.0f / 384.0f) + 1e-5f);
  const float* lg = lng + (long)d * 384;
  const float* lb = lnb + (long)d * 384;
  const float* wd = w2 + (long)d * 384;
  float p = gelu_f(d0 * inv * lg[t] + lb[t]) * wd[t];
  if (t < 128) p += gelu_f(d1 * inv * lg[256 + t] + lb[256 + t]) * wd[256 + t];
  float ps = block_sum(p);
  if (t == 0) da[b * kND + d] = (ps + b2[d] > 0.f) ? 1.f : 0.f;
}

__global__ __launch_bounds__(256) void vcomb_k(const float* __restrict__ u,
                                               const float* __restrict__ ia,
                                               const float* __restrict__ Mm,
                                               float* __restrict__ vv) {
  int idx = blockIdx.x * 256 + threadIdx.x;
  if (idx >= kRows * 120) return;
  int row = idx / 120, c = idx % 120;
  int e = c >> 3, rp = c & 7;
  const float* Me = Mm + e * 64 + rp * 8;
  const float* ur = u + (long)row * 128 + e * 8;
  float acc = ia[(long)row * 128 + c];
#pragma unroll
  for (int r = 0; r < 8; r++) acc += 2.0f * Me[r] * ur[r];
  vv[(long)row * 128 + c] = acc;
}

// Per (b,s): base = cwo + bo; expert loop LN_plain + weighted sum; h = acc+res1.
__global__ __launch_bounds__(256) void finaleven_k(
    const float* __restrict__ cwo, const float* __restrict__ bo,
    const float* __restrict__ res1, const float* __restrict__ vv,
    const float* __restrict__ Bd, const float* __restrict__ da,
    const float* __restrict__ mask, float* __restrict__ h) {
  int row = blockIdx.x;
  int b = row / kS, s = row % kS;
  int t = threadIdx.x;
  __shared__ float w[16];
  __shared__ float vvs[120];
  if (t < 120) vvs[t] = vv[(long)row * 128 + t];
  if (t < kND) w[t] = (s >= 1) ? da[b * kND + t] * mask[(s - 1) * kND + t] : 0.f;
  if (t == kND) w[kND] = 1.f;
  __syncthreads();
  float wsum = 0.f;
#pragma unroll
  for (int e = 0; e < kE; e++) wsum += w[e];
  float winv = 1.0f / wsum;
  long rb = (long)row * kD;
  float b0 = cwo[rb + t] + bo[t];
  float b1 = cwo[rb + t + 256] + bo[t + 256];
  float b2v = cwo[rb + t + 512] + bo[t + 512];
  float a0 = 0.f, a1 = 0.f, a2 = 0.f;
  for (int e = 0; e < kE; e++) {
    float we = w[e];
    if (we == 0.f) continue;
    const float* vr = vvs + e * 8;
    float y0 = b0 + 2.0f * dot8(Bd + ((long)(e * kD + t)) * 8, vr);
    float y1 = b1 + 2.0f * dot8(Bd + ((long)(e * kD + t + 256)) * 8, vr);
    float y2 = b2v + 2.0f * dot8(Bd + ((long)(e * kD + t + 512)) * 8, vr);
    float m = block_sum(y0 + y1 + y2) * (1.0f / 768.0f);
    float d0 = y0 - m, d1 = y1 - m, d2 = y2 - m;
    float q = block_sum(d0 * d0 + d1 * d1 + d2 * d2);
    float inv = rsqrtf(q * (1.0f / 768.0f) + 1e-5f);
    float sc = we * winv * inv;
    a0 += sc * d0;
    a1 += sc * d1;
    a2 += sc * d2;
  }
  h[rb + t] = a0 + res1[rb + t];
  h[rb + t + 256] = a1 + res1[rb + t + 256];
  h[rb + t + 512] = a2 + res1[rb + t + 512];
}

}  // namespace

extern "C" void kernel_launch(void* const* d_in, const int* in_sizes, int n_in,
                              void* d_out, int out_size, void* d_ws, size_t ws_size,
                              hipStream_t stream) {
  const float* region = (const float*)d_in[0];
  const float* mask = (const float*)d_in[1];
  const float* cls = (const float*)d_in[2];
  const float* ln1g = (const float*)d_in[3];
  const float* ln1b = (const float*)d_in[4];
  const float* ln2g = (const float*)d_in[5];
  const float* ln2b = (const float*)d_in[6];
  const float* Wq = (const float*)d_in[7];
  const float* bq = (const float*)d_in[8];
  const float* Wk = (const float*)d_in[9];
  const float* bk = (const float*)d_in[10];
  const float* Wv = (const float*)d_in[11];
  const float* bv = (const float*)d_in[12];
  const float* Wao = (const float*)d_in[13];
  const float* bao = (const float*)d_in[14];
  const float* Wi = (const float*)d_in[15];
  const float* bi = (const float*)d_in[16];
  const float* Wo = (const float*)d_in[17];
  const float* bo = (const float*)d_in[18];
  const float* fg = (const float*)d_in[19];
  const float* fb = (const float*)d_in[20];
  const float* cW1 = (const float*)d_in[21];
  const float* cb1 = (const float*)d_in[22];
  const float* clng = (const float*)d_in[23];
  const float* clnb = (const float*)d_in[24];
  const float* cW2 = (const float*)d_in[25];
  const float* cb2 = (const float*)d_in[26];
  const float* Aup = (const float*)d_in[27];
  const float* Bup = (const float*)d_in[28];
  const float* Adn = (const float*)d_in[29];
  const float* Bdn = (const float*)d_in[30];
  float* out = (float*)d_out;

  char* wsb = (char*)d_ws;
  size_t off = 0;
  auto alloc = [&](size_t bytes) {
    char* p = wsb + off;
    off = (off + bytes + 255) & ~(size_t)255;
    return (void*)p;
  };
  float* h = (float*)alloc((size_t)kRows * kD * 4);
  float* qkv = (float*)alloc((size_t)kRows * kQKV * 4);
  float* ao = (float*)alloc((size_t)kRows * kD * 4);
  float* res1 = (float*)alloc((size_t)kRows * kD * 4);
  float* cwo = (float*)alloc((size_t)kRows * kD * 4);
  float* pooled = (float*)alloc((size_t)kND * kB * kD * 4);
  float* zb = (float*)alloc((size_t)kND * kB * 384 * 4);
  float* da = (float*)alloc((size_t)kB * kND * 4);
  float* ub = (float*)alloc((size_t)kRows * 128 * 4);
  float* ia = (float*)alloc((size_t)kRows * 128 * 4);
  float* vvb = (float*)alloc((size_t)kRows * 128 * 4);
  float* Mm = (float*)alloc((size_t)kNE * kE * 64 * 4);
  float* cc = (float*)alloc(64);
  short* n1h = (short*)alloc((size_t)kRows * kD * 2);
  short* n1l = (short*)alloc((size_t)kRows * kD * 2);
  short* n2h = (short*)alloc((size_t)kRows * kD * 2);
  short* n2l = (short*)alloc((size_t)kRows * kD * 2);
  short* inth = (short*)alloc((size_t)kRows * kH * 2);
  short* intl = (short*)alloc((size_t)kRows * kH * 2);
  short* wqkh = (short*)alloc((size_t)4 * kD * kD * 2);
  short* wqkl = (short*)alloc((size_t)4 * kD * kD * 2);
  short* wioh = (short*)alloc((size_t)2 * kD * kH * 2);
  short* wiol = (short*)alloc((size_t)2 * kD * kH * 2);
  short* luh = (short*)alloc((size_t)128 * kD * 2);
  short* lul = (short*)alloc((size_t)128 * kD * 2);
  short* ldh = (short*)alloc((size_t)128 * kH * 2);
  short* ldl = (short*)alloc((size_t)128 * kH * 2);

  concat_k<<<(kRows * kD + 255) / 256, 256, 0, stream>>>(region, cls, h);
  cc_k<<<1, 32, 0, stream>>>(mask, cc);
  mmat_k<<<kNE * kE, 256, 0, stream>>>(Adn, Bup, Mm);

  const int nDD = kD * kD;
  const int nDH = kD * kH;

  // n1 planes for layer 0
  ln_bf_k<<<kRows, 256, 0, stream>>>(h, nullptr, nullptr, nullptr, nullptr, ln1g,
                                     ln1b, n1h, n1l, 1e-12f);

  for (int i = 0; i < kL; i++) {
    int le = i >> 1;
    bool even = (i % 2) == 0;
    conv4_k<<<dim3(nDD / 1024, 4), 256, 0, stream>>>(
        Wq + (long)i * nDD, Wk + (long)i * nDD, Wv + (long)i * nDD,
        Wao + (long)i * nDD, wqkh, wqkl, nDD);
    conv4_k<<<dim3(nDH / 1024, 2), 256, 0, stream>>>(
        Wi + (long)i * nDH, Wo + (long)i * nDH, Wi, Wi, wioh, wiol, nDH);

    // QKV fused: B = [Wq;Wk;Wv] rows 0..2303, biases folded into attn_k.
    gemm_hl<128, false><<<dim3(kQKV / 128, 30), 256, 0, stream>>>(
        n1h, n1l, wqkh, wqkl, nullptr, nullptr, qkv, nullptr, nullptr, kD, kQKV,
        0, 0);
    attn_k<<<kB * kNH, 256, 0, stream>>>(qkv, bq + i * kD, bk + i * kD,
                                         bv + i * kD, n1h, n1l);
    gemm_hl<64, false><<<dim3(12, 30), 256, 0, stream>>>(
        n1h, n1l, wqkh + 3L * nDD, wqkl + 3L * nDD, bao + i * kD, nullptr, ao,
        nullptr, nullptr, kD, kD, 0, 0);
    addln_bf_k<<<kRows, 256, 0, stream>>>(ao, h, ln2g + i * kD, ln2b + i * kD,
                                          res1, n2h, n2l, 1e-12f);
    gemm_hl<128, false><<<dim3(24, 30), 256, 0, stream>>>(
        n2h, n2l, wioh, wiol, bi + i * kH, nullptr, nullptr, inth, intl, kD, kH,
        1, 0);
    hipMemsetAsync(cwo, 0, (size_t)kRows * kD * 4, stream);
    gemm_hl<64, true><<<dim3(12, 30, 2), 256, 0, stream>>>(
        inth, intl, wioh + (long)nDH, wiol + (long)nDH, nullptr, nullptr, cwo,
        nullptr, nullptr, kH, kD, 0, 1536);
    if (even) {
      convpad_k<<<(128 * kD) / 1024, 256, 0, stream>>>(
          Aup + (long)le * kE * 8 * kD, luh, lul, kD);
      convpad_k<<<(128 * kH) / 1024, 256, 0, stream>>>(
          Adn + (long)le * kE * 8 * kH, ldh, ldl, kH);
      hipMemsetAsync(ub, 0, (size_t)kRows * 128 * 4, stream);
      hipMemsetAsync(ia, 0, (size_t)kRows * 128 * 4, stream);
      gemm_hl<128, true><<<dim3(1, 30, 8), 256, 0, stream>>>(
          n2h, n2l, luh, lul, nullptr, nullptr, ub, nullptr, nullptr, kD, 128, 0,
          96);
      gemm_hl<128, true><<<dim3(1, 30, 8), 256, 0, stream>>>(
          inth, intl, ldh, ldl, nullptr, nullptr, ia, nullptr, nullptr, kH, 128,
          0, 384);
      pool_k<<<kND * kB, 256, 0, stream>>>(ao, mask, cc, pooled);
      gemm_nt<64, 4><<<dim3(6, 1, kND), 256, 0, stream>>>(
          pooled, cW1 + (long)le * kND * 384 * kD, cb1 + (long)le * kND * 384, zb,
          64, 384, kD, (long)64 * kD, (long)384 * kD, 384, (long)64 * 384);
      cls2_k<<<kND * kB, 256, 0, stream>>>(zb, clng + (long)le * kND * 384,
                                           clnb + (long)le * kND * 384,
                                           cW2 + (long)le * kND * 384,
                                           cb2 + le * kND, da);
      vcomb_k<<<(kRows * 120 + 255) / 256, 256, 0, stream>>>(
          ub, ia, Mm + le * kE * 64, vvb);
      finaleven_k<<<kRows, 256, 0, stream>>>(cwo, bo + i * kD, res1, vvb,
                                             Bdn + (long)le * kE * kD * 8, da,
                                             mask, h);
      // n1 planes for layer i+1
      ln_bf_k<<<kRows, 256, 0, stream>>>(h, nullptr, nullptr, nullptr, nullptr,
                                         ln1g + (i + 1) * kD, ln1b + (i + 1) * kD,
                                         n1h, n1l, 1e-12f);
    } else if (i < kL - 1) {
      // h = cwo + bo + res1, then LN -> n1 planes for layer i+1
      ln_bf_k<<<kRows, 256, 0, stream>>>(nullptr, cwo, bo + i * kD, res1, h,
                                         ln1g + (i + 1) * kD, ln1b + (i + 1) * kD,
                                         n1h, n1l, 1e-12f);
    } else {
      ln_row_k<<<kRows, 256, 0, stream>>>(cwo, bo + i * kD, res1, fg, fb, out,
                                          1e-12f);
    }
  }
}

// Round 4
// 3863.265 us; speedup vs baseline: 2.1348x; 1.0627x over previous
//
#include <hip/hip_runtime.h>

namespace {

constexpr int kB = 64, kSR = 29, kS = 30, kD = 768, kH = 3072, kL = 12;
constexpr int kNH = 12, kND = 14, kE = 15, kNE = 6;
constexpr int kRows = kB * kS;  // 1920
constexpr int kQKV = 2304;

typedef __attribute__((ext_vector_type(8))) short s16x8;
typedef __attribute__((ext_vector_type(4))) float fx4;

__device__ __forceinline__ float gelu_f(float x) {
  return 0.5f * x * (1.0f + erff(x * 0.70710678118654752f));
}

__device__ __forceinline__ unsigned short f2bf_u(float x) {
  union { float f; unsigned u; } v;
  v.f = x;
  unsigned r = v.u + 0x7fffu + ((v.u >> 16) & 1u);
  return (unsigned short)(r >> 16);
}
__device__ __forceinline__ float bfu2f(unsigned short h) {
  union { unsigned u; float f; } v;
  v.u = ((unsigned)h) << 16;
  return v.f;
}

// async global->LDS, 16B per lane. LDS dest = uniform base + lane*16.
__device__ __forceinline__ void g2l16(const short* g, short* l) {
  __builtin_amdgcn_global_load_lds(
      (const __attribute__((address_space(1))) unsigned int*)g,
      (__attribute__((address_space(3))) unsigned int*)l, 16, 0, 0);
}

__device__ __forceinline__ float block_sum(float v) {
  __shared__ float sb[4];
#pragma unroll
  for (int o = 32; o > 0; o >>= 1) v += __shfl_down(v, o, 64);
  int w = threadIdx.x >> 6;
  __syncthreads();
  if ((threadIdx.x & 63) == 0) sb[w] = v;
  __syncthreads();
  return sb[0] + sb[1] + sb[2] + sb[3];
}

__device__ __forceinline__ float dot8(const float* __restrict__ p,
                                      const float* __restrict__ q) {
  float4 x = *(const float4*)p;
  float4 y = *(const float4*)(p + 4);
  return x.x * q[0] + x.y * q[1] + x.z * q[2] + x.w * q[3] +
         y.x * q[4] + y.y * q[5] + y.z * q[6] + y.w * q[7];
}

// ---------------------------------------------------------------------------
// MFMA GEMM, C = A @ B^T, hi/lo bf16 planes, 3-pass (hh+hl+lh ~ fp32).
// Tile 128x128, BK=32, 4 waves (2x2), wave tile 64x64 (4x4 16x16 frags).
// Double-buffered fragment-contiguous LDS staged via global_load_lds with
// per-lane gathered global addresses; ONE __syncthreads per K-step: stage of
// step s+1 is issued before compute of step s, so load latency hides under
// the 48 MFMA. All dims divide tiles exactly.
// KSPLIT: blockIdx.z k-chunk + fp32 atomicAdd into pre-zeroed Cf.
// ---------------------------------------------------------------------------
template <bool KSPLIT>
__global__ __launch_bounds__(256, 2) void gemm_hl(
    const short* __restrict__ Ah, const short* __restrict__ Al,
    const short* __restrict__ Bh, const short* __restrict__ Bl,
    const float* __restrict__ bias, const float* __restrict__ res,
    float* __restrict__ Cf, short* __restrict__ Ch, short* __restrict__ Cl,
    int K, int ldc, int act, int kchunk) {
  // [buf][plane][frag][512]
  __shared__ __align__(16) short As[2][2][8][512];
  __shared__ __align__(16) short Bs[2][2][8][512];
  const int t = threadIdx.x, w = t >> 6, lane = t & 63;
  const int lr = lane & 15, lg = lane >> 4;
  const int m0 = blockIdx.y * 128, n0 = blockIdx.x * 128;
  const int k0 = KSPLIT ? blockIdx.z * kchunk : 0;
  const int nsteps = (KSPLIT ? kchunk : K) / 32;
  const int wmf = (w & 1) * 4;   // wave m-frag base
  const int wnf = (w >> 1) * 4;  // wave n-frag base

  // 8 staging fragments per wave: f = w*8+q. f<16: A (plane f&1, mfrag f>>1),
  // else B.
  const short* gp[8];
  short* lp[8];
#pragma unroll
  for (int q = 0; q < 8; q++) {
    int f = w * 8 + q;
    if (f < 16) {
      int p = f & 1, mf = f >> 1;
      gp[q] = (p ? Al : Ah) + (size_t)(m0 + mf * 16 + lr) * K + k0 + lg * 8;
      lp[q] = &As[0][p][mf][0];
    } else {
      int fb = f - 16, p = fb & 1, nf = fb >> 1;
      gp[q] = (p ? Bl : Bh) + (size_t)(n0 + nf * 16 + lr) * K + k0 + lg * 8;
      lp[q] = &Bs[0][p][nf][0];
    }
  }
  // buf1 is +8192 shorts from buf0 for both As and Bs frags.

  fx4 acc[4][4];
#pragma unroll
  for (int i = 0; i < 4; i++)
#pragma unroll
    for (int j = 0; j < 4; j++) acc[i][j] = (fx4)0.f;

  // prologue: stage step 0 into buf0
#pragma unroll
  for (int q = 0; q < 8; q++) {
    g2l16(gp[q], lp[q]);
    gp[q] += 32;
  }
  __syncthreads();

  int cur = 0;
  for (int s = 0; s < nsteps; s++) {
    if (s + 1 < nsteps) {
      int boff = (cur ^ 1) * 8192;
#pragma unroll
      for (int q = 0; q < 8; q++) {
        g2l16(gp[q], lp[q] + boff);
        gp[q] += 32;
      }
    }
    s16x8 af[4][2], bf[4][2];
#pragma unroll
    for (int fm = 0; fm < 4; fm++) {
      af[fm][0] = *(const s16x8*)&As[cur][0][wmf + fm][lane * 8];
      af[fm][1] = *(const s16x8*)&As[cur][1][wmf + fm][lane * 8];
    }
#pragma unroll
    for (int fn = 0; fn < 4; fn++) {
      bf[fn][0] = *(const s16x8*)&Bs[cur][0][wnf + fn][lane * 8];
      bf[fn][1] = *(const s16x8*)&Bs[cur][1][wnf + fn][lane * 8];
    }
#pragma unroll
    for (int fm = 0; fm < 4; fm++)
#pragma unroll
      for (int fn = 0; fn < 4; fn++) {
        acc[fm][fn] = __builtin_amdgcn_mfma_f32_16x16x32_bf16(af[fm][0], bf[fn][0], acc[fm][fn], 0, 0, 0);
        acc[fm][fn] = __builtin_amdgcn_mfma_f32_16x16x32_bf16(af[fm][0], bf[fn][1], acc[fm][fn], 0, 0, 0);
        acc[fm][fn] = __builtin_amdgcn_mfma_f32_16x16x32_bf16(af[fm][1], bf[fn][0], acc[fm][fn], 0, 0, 0);
      }
    __syncthreads();
    cur ^= 1;
  }

  const int orow = (lane >> 4) * 4;
#pragma unroll
  for (int fm = 0; fm < 4; fm++) {
#pragma unroll
    for (int fn = 0; fn < 4; fn++) {
      int col = n0 + (wnf + fn) * 16 + lr;
      if (KSPLIT) {
#pragma unroll
        for (int j = 0; j < 4; j++) {
          int row = m0 + (wmf + fm) * 16 + orow + j;
          atomicAdd(&Cf[(size_t)row * ldc + col], acc[fm][fn][j]);
        }
      } else {
        float bv = bias ? bias[col] : 0.f;
#pragma unroll
        for (int j = 0; j < 4; j++) {
          int row = m0 + (wmf + fm) * 16 + orow + j;
          float v = acc[fm][fn][j] + bv;
          if (act) v = gelu_f(v);
          size_t idx = (size_t)row * ldc + col;
          if (res) v += res[idx];
          if (Cf) Cf[idx] = v;
          if (Ch) {
            unsigned short hb = f2bf_u(v);
            Ch[idx] = (short)hb;
            Cl[idx] = (short)f2bf_u(v - bfu2f(hb));
          }
        }
      }
    }
  }
}

// fp32 GEMM (small batched classifier GEMM only).
template <int BM, int TM>
__global__ __launch_bounds__(256) void gemm_nt(
    const float* __restrict__ A, const float* __restrict__ Bt,
    const float* __restrict__ bias, float* __restrict__ C, int M, int N, int K,
    long sA, long sB, long sBias, long sC) {
  constexpr int BN = 64;
  __shared__ float As[16][BM + 4];
  __shared__ float Bs[16][BN + 4];
  int tid = threadIdx.x;
  int n0 = blockIdx.x * BN;
  int m0 = blockIdx.y * BM;
  int bz = blockIdx.z;
  A += bz * sA;
  Bt += bz * sB;
  C += bz * sC;
  if (bias) bias += bz * sBias;
  int tx = tid & 15, ty = tid >> 4;
  float acc[TM][4];
#pragma unroll
  for (int i = 0; i < TM; i++)
#pragma unroll
    for (int j = 0; j < 4; j++) acc[i][j] = 0.f;

  constexpr int APT = (BM * 4) / 256;
  int brow = tid >> 2, bk4 = (tid & 3) * 4;

  for (int kt = 0; kt < K; kt += 16) {
#pragma unroll
    for (int q = 0; q < APT; q++) {
      int f4 = tid * APT + q;
      int row = f4 >> 2;
      int kk = (f4 & 3) * 4;
      float4 vA = make_float4(0.f, 0.f, 0.f, 0.f);
      if (m0 + row < M) vA = *(const float4*)&A[(long)(m0 + row) * K + kt + kk];
      As[kk + 0][row] = vA.x;
      As[kk + 1][row] = vA.y;
      As[kk + 2][row] = vA.z;
      As[kk + 3][row] = vA.w;
    }
    {
      float4 vB = make_float4(0.f, 0.f, 0.f, 0.f);
      if (n0 + brow < N) vB = *(const float4*)&Bt[(long)(n0 + brow) * K + kt + bk4];
      Bs[bk4 + 0][brow] = vB.x;
      Bs[bk4 + 1][brow] = vB.y;
      Bs[bk4 + 2][brow] = vB.z;
      Bs[bk4 + 3][brow] = vB.w;
    }
    __syncthreads();
#pragma unroll
    for (int kk = 0; kk < 16; kk++) {
      float4 b4 = *(const float4*)&Bs[kk][tx * 4];
      float a[TM];
#pragma unroll
      for (int p = 0; p < TM / 4; p++) {
        float4 a4 = *(const float4*)&As[kk][ty * TM + p * 4];
        a[p * 4 + 0] = a4.x;
        a[p * 4 + 1] = a4.y;
        a[p * 4 + 2] = a4.z;
        a[p * 4 + 3] = a4.w;
      }
#pragma unroll
      for (int i = 0; i < TM; i++) {
        acc[i][0] += a[i] * b4.x;
        acc[i][1] += a[i] * b4.y;
        acc[i][2] += a[i] * b4.z;
        acc[i][3] += a[i] * b4.w;
      }
    }
    __syncthreads();
  }

  int col = n0 + tx * 4;
  float4 bb = make_float4(0.f, 0.f, 0.f, 0.f);
  if (bias && col + 3 < N) bb = *(const float4*)&bias[col];
#pragma unroll
  for (int i = 0; i < TM; i++) {
    int row = m0 + ty * TM + i;
    if (row >= M) continue;
    float4 c;
    c.x = acc[i][0] + bb.x;
    c.y = acc[i][1] + bb.y;
    c.z = acc[i][2] + bb.z;
    c.w = acc[i][3] + bb.w;
    if (col + 3 < N) {
      *(float4*)&C[(long)row * N + col] = c;
    } else {
      float cv[4] = {c.x, c.y, c.z, c.w};
      for (int j = 0; j < 4; j++)
        if (col + j < N) C[(long)row * N + col + j] = cv[j];
    }
  }
}

__global__ __launch_bounds__(256) void conv4_k(const float* s0, const float* s1,
                                               const float* s2, const float* s3,
                                               short* dh, short* dl, int n) {
  int m = blockIdx.y;
  const float* s = (m == 0) ? s0 : (m == 1) ? s1 : (m == 2) ? s2 : s3;
  int i = (blockIdx.x * 256 + threadIdx.x) * 4;
  if (i >= n) return;
  float4 v = *(const float4*)(s + i);
  short4 hv, lv;
  unsigned short h;
  h = f2bf_u(v.x); hv.x = (short)h; lv.x = (short)f2bf_u(v.x - bfu2f(h));
  h = f2bf_u(v.y); hv.y = (short)h; lv.y = (short)f2bf_u(v.y - bfu2f(h));
  h = f2bf_u(v.z); hv.z = (short)h; lv.z = (short)f2bf_u(v.z - bfu2f(h));
  h = f2bf_u(v.w); hv.w = (short)h; lv.w = (short)f2bf_u(v.w - bfu2f(h));
  *(short4*)(dh + (size_t)m * n + i) = hv;
  *(short4*)(dl + (size_t)m * n + i) = lv;
}

__global__ __launch_bounds__(256) void convpad_k(const float* __restrict__ s,
                                                 short* __restrict__ dh,
                                                 short* __restrict__ dl, int K) {
  int i = (blockIdx.x * 256 + threadIdx.x) * 4;
  if (i >= 128 * K) return;
  float4 v = make_float4(0.f, 0.f, 0.f, 0.f);
  if (i < 120 * K) v = *(const float4*)(s + i);
  short4 hv, lv;
  unsigned short h;
  h = f2bf_u(v.x); hv.x = (short)h; lv.x = (short)f2bf_u(v.x - bfu2f(h));
  h = f2bf_u(v.y); hv.y = (short)h; lv.y = (short)f2bf_u(v.y - bfu2f(h));
  h = f2bf_u(v.z); hv.z = (short)h; lv.z = (short)f2bf_u(v.z - bfu2f(h));
  h = f2bf_u(v.w); hv.w = (short)h; lv.w = (short)f2bf_u(v.w - bfu2f(h));
  *(short4*)(dh + i) = hv;
  *(short4*)(dl + i) = lv;
}

__global__ __launch_bounds__(256) void concat_k(const float* __restrict__ rf,
                                                const float* __restrict__ cls,
                                                float* __restrict__ h) {
  int idx = blockIdx.x * 256 + threadIdx.x;
  if (idx >= kRows * kD) return;
  int d = idx % kD;
  int row = idx / kD;
  int s = row % kS;
  int b = row / kS;
  h[idx] = (s == 0) ? cls[d] : rf[((long)b * kSR + (s - 1)) * kD + d];
}

__global__ void cc_k(const float* __restrict__ mask, float* __restrict__ cc) {
  int d = threadIdx.x;
  if (d < kND) {
    float s = 0.f;
    for (int r = 0; r < kSR; r++) s += mask[r * kND + d];
    cc[d] = s;
  }
}

__global__ __launch_bounds__(256) void mmat_k(const float* __restrict__ Adn,
                                              const float* __restrict__ Bup,
                                              float* __restrict__ Mm) {
  int g = blockIdx.x;
  int t = threadIdx.x;
  int pair = t & 63;
  int quarter = t >> 6;
  int rp = pair >> 3, r = pair & 7;
  const float* ad = Adn + (long)(g * 8 + rp) * kH;
  const float* bu = Bup + (long)g * kH * 8 + r;
  float acc = 0.f;
  for (int hh = quarter * 768; hh < quarter * 768 + 768; hh++)
    acc += ad[hh] * bu[hh * 8];
  __shared__ float red[256];
  red[t] = acc;
  __syncthreads();
  if (t < 64) Mm[g * 64 + pair] = red[t] + red[t + 64] + red[t + 128] + red[t + 192];
}

// LN -> hi/lo bf16 planes. Optional fused pre-add: x = c2 + b2 + r2 (written
// to hout) when c2 != null, else x read directly.
__global__ __launch_bounds__(256) void ln_bf_k(
    const float* __restrict__ x, const float* __restrict__ c2,
    const float* __restrict__ b2, const float* __restrict__ r2,
    float* __restrict__ hout, const float* __restrict__ g,
    const float* __restrict__ b, short* __restrict__ yh,
    short* __restrict__ yl, float eps) {
  int row = blockIdx.x;
  int t = threadIdx.x;
  long rb = (long)row * kD;
  float v0, v1, v2;
  if (c2) {
    v0 = c2[rb + t] + b2[t] + r2[rb + t];
    v1 = c2[rb + t + 256] + b2[t + 256] + r2[rb + t + 256];
    v2 = c2[rb + t + 512] + b2[t + 512] + r2[rb + t + 512];
    hout[rb + t] = v0;
    hout[rb + t + 256] = v1;
    hout[rb + t + 512] = v2;
  } else {
    v0 = x[rb + t];
    v1 = x[rb + t + 256];
    v2 = x[rb + t + 512];
  }
  float m = block_sum(v0 + v1 + v2) * (1.0f / 768.0f);
  float d0 = v0 - m, d1 = v1 - m, d2 = v2 - m;
  float q = block_sum(d0 * d0 + d1 * d1 + d2 * d2);
  float inv = rsqrtf(q * (1.0f / 768.0f) + eps);
#pragma unroll
  for (int c = 0; c < 3; c++) {
    int tt = t + c * 256;
    float dd = (c == 0 ? d0 : c == 1 ? d1 : d2);
    float val = dd * inv * g[tt] + b[tt];
    unsigned short hb = f2bf_u(val);
    yh[rb + tt] = (short)hb;
    yl[rb + tt] = (short)f2bf_u(val - bfu2f(hb));
  }
}

// Final LN -> fp32 out, fused h = c2 + b2 + r2.
__global__ __launch_bounds__(256) void ln_row_k(
    const float* __restrict__ c2, const float* __restrict__ b2,
    const float* __restrict__ r2, const float* __restrict__ g,
    const float* __restrict__ b, float* __restrict__ y, float eps) {
  int row = blockIdx.x;
  int t = threadIdx.x;
  long rb = (long)row * kD;
  float v0 = c2[rb + t] + b2[t] + r2[rb + t];
  float v1 = c2[rb + t + 256] + b2[t + 256] + r2[rb + t + 256];
  float v2 = c2[rb + t + 512] + b2[t + 512] + r2[rb + t + 512];
  float m = block_sum(v0 + v1 + v2) * (1.0f / 768.0f);
  float d0 = v0 - m, d1 = v1 - m, d2 = v2 - m;
  float q = block_sum(d0 * d0 + d1 * d1 + d2 * d2);
  float inv = rsqrtf(q * (1.0f / 768.0f) + eps);
  y[rb + t] = d0 * inv * g[t] + b[t];
  y[rb + t + 256] = d1 * inv * g[t + 256] + b[t + 256];
  y[rb + t + 512] = d2 * inv * g[t + 512] + b[t + 512];
}

// res1 = a + abias + h ; n2 = LN(res1) -> hi/lo planes
__global__ __launch_bounds__(256) void addln_bf_k(
    const float* __restrict__ a, const float* __restrict__ abias,
    const float* __restrict__ hh, const float* __restrict__ g,
    const float* __restrict__ b, float* __restrict__ r1,
    short* __restrict__ n2h, short* __restrict__ n2l, float eps) {
  int row = blockIdx.x;
  int t = threadIdx.x;
  long rb = (long)row * kD;
  float v0 = a[rb + t] + abias[t] + hh[rb + t];
  float v1 = a[rb + t + 256] + abias[t + 256] + hh[rb + t + 256];
  float v2 = a[rb + t + 512] + abias[t + 512] + hh[rb + t + 512];
  r1[rb + t] = v0;
  r1[rb + t + 256] = v1;
  r1[rb + t + 512] = v2;
  float m = block_sum(v0 + v1 + v2) * (1.0f / 768.0f);
  float d0 = v0 - m, d1 = v1 - m, d2 = v2 - m;
  float q = block_sum(d0 * d0 + d1 * d1 + d2 * d2);
  float inv = rsqrtf(q * (1.0f / 768.0f) + eps);
#pragma unroll
  for (int c = 0; c < 3; c++) {
    int tt = t + c * 256;
    float dd = (c == 0 ? d0 : c == 1 ? d1 : d2);
    float val = dd * inv * g[tt] + b[tt];
    unsigned short hb = f2bf_u(val);
    n2h[rb + tt] = (short)hb;
    n2l[rb + tt] = (short)f2bf_u(val - bfu2f(hb));
  }
}

// One block per (b, head). Reads packed qkv [1920][2304], adds biases inline.
__global__ __launch_bounds__(256) void attn_k(const float* __restrict__ qkv,
                                              const float* __restrict__ bq,
                                              const float* __restrict__ bk,
                                              const float* __restrict__ bv,
                                              short* __restrict__ oh,
                                              short* __restrict__ ol) {
  int blk = blockIdx.x;
  int b = blk / kNH, hh = blk % kNH;
  __shared__ float qs[30][65], ks[30][65], vs[30][65], ps[30][32];
  int t = threadIdx.x;
  long ibase = (long)b * kS * kQKV + hh * 64;
  long obase = (long)b * kS * kD + hh * 64;
  for (int idx = t; idx < 1920; idx += 256) {
    int s = idx >> 6, d = idx & 63;
    long a = ibase + (long)s * kQKV + d;
    int bcol = hh * 64 + d;
    qs[s][d] = qkv[a] + bq[bcol];
    ks[s][d] = qkv[a + 768] + bk[bcol];
    vs[s][d] = qkv[a + 1536] + bv[bcol];
  }
  __syncthreads();
  for (int idx = t; idx < 900; idx += 256) {
    int r = idx / 30, c = idx % 30;
    float acc = 0.f;
#pragma unroll
    for (int d = 0; d < 64; d++) acc += qs[r][d] * ks[c][d];
    ps[r][c] = acc * 0.125f;
  }
  __syncthreads();
  if (t < 30) {
    float mx = -1e30f;
#pragma unroll
    for (int c = 0; c < 30; c++) mx = fmaxf(mx, ps[t][c]);
    float sm = 0.f;
#pragma unroll
    for (int c = 0; c < 30; c++) sm += expf(ps[t][c] - mx);
    float inv = 1.0f / sm;
#pragma unroll
    for (int c = 0; c < 30; c++) ps[t][c] = expf(ps[t][c] - mx) * inv;
  }
  __syncthreads();
  for (int idx = t; idx < 1920; idx += 256) {
    int r = idx >> 6, d = idx & 63;
    float acc = 0.f;
#pragma unroll
    for (int c = 0; c < 30; c++) acc += ps[r][c] * vs[c][d];
    long a = obase + (long)r * kD + d;
    unsigned short hb = f2bf_u(acc);
    oh[a] = (short)hb;
    ol[a] = (short)f2bf_u(acc - bfu2f(hb));
  }
}

// pooled = (sum_r mask*ao_nobias)/cc + bao
__global__ __launch_bounds__(256) void pool_k(const float* __restrict__ ao,
                                              const float* __restrict__ bao,
                                              const float* __restrict__ mask,
                                              const float* __restrict__ cc,
                                              float* __restrict__ pooled) {
  int blk = blockIdx.x;
  int d = blk >> 6, b = blk & 63;
  __shared__ float mr[32];
  int t = threadIdx.x;
  if (t < kSR) mr[t] = mask[t * kND + d];
  __syncthreads();
  float inv = 1.0f / cc[d];
  for (int hd = t; hd < kD; hd += 256) {
    float acc = 0.f;
    for (int r = 0; r < kSR; r++) acc += mr[r] * ao[((long)b * kS + 1 + r) * kD + hd];
    pooled[(long)blk * kD + hd] = acc * inv + bao[hd];
  }
}

__global__ __launch_bounds__(256) void cls2_k(const float* __restrict__ z,
                                              const float* __restrict__ lng,
                                              const float* __restrict__ lnb,
                                              const float* __restrict__ w2,
                                              const float* __restrict__ b2,
                                              float* __restrict__ da) {
  int blk = blockIdx.x;
  int d = blk >> 6, b = blk & 63;
  int t = threadIdx.x;
  const float* zr = z + (long)blk * 384;
  float v0 = zr[t];
  float v1 = (t < 128) ? zr[256 + t] : 0.f;
  float m = block_sum(v0 + v1) * (1.0f / 384.0f);
  float d0 = v0 - m;
  float d1 = (t < 128) ? v1 - m : 0.f;
  float q = block_sum(d0 * d0 + d1 * d1);
  float inv = rsqrtf(q * (1.0f / 384.0f) + 1e-5f);
  const float* lg = lng + (long)d * 384;
  const float* lb = lnb + (long)d * 384;
  const float* wd = w2 + (long)d * 384;
  float p = gelu_f(d0 * inv * lg[t] + lb[t]) * wd[t];
  if (t < 128) p += gelu_f(d1 * inv * lg[256 + t] + lb[256 + t]) * wd[256 + t];
  float ps = block_sum(p);
  if (t == 0) da[b * kND + d] = (ps + b2[d] > 0.f) ? 1.f : 0.f;
}

__global__ __launch_bounds__(256) void vcomb_k(const float* __restrict__ u,
                                               const float* __restrict__ ia,
                                               const float* __restrict__ Mm,
                                               float* __restrict__ vv) {
  int idx = blockIdx.x * 256 + threadIdx.x;
  if (idx >= kRows * 120) return;
  int row = idx / 120, c = idx % 120;
  int e = c >> 3, rp = c & 7;
  const float* Me = Mm + e * 64 + rp * 8;
  const float* ur = u + (long)row * 128 + e * 8;
  float acc = ia[(long)row * 128 + c];
#pragma unroll
  for (int r = 0; r < 8; r++) acc += 2.0f * Me[r] * ur[r];
  vv[(long)row * 128 + c] = acc;
}

// Per (b,s): base = cwo + bo; expert loop LN_plain + weighted sum; h = acc+res1.
__global__ __launch_bounds__(256) void finaleven_k(
    const float* __restrict__ cwo, const float* __restrict__ bo,
    const float* __restrict__ res1, const float* __restrict__ vv,
    const float* __restrict__ Bd, const float* __restrict__ da,
    const float* __restrict__ mask, float* __restrict__ h) {
  int row = blockIdx.x;
  int b = row / kS, s = row % kS;
  int t = threadIdx.x;
  __shared__ float w[16];
  __shared__ float vvs[120];
  if (t < 120) vvs[t] = vv[(long)row * 128 + t];
  if (t < kND) w[t] = (s >= 1) ? da[b * kND + t] * mask[(s - 1) * kND + t] : 0.f;
  if (t == kND) w[kND] = 1.f;
  __syncthreads();
  float wsum = 0.f;
#pragma unroll
  for (int e = 0; e < kE; e++) wsum += w[e];
  float winv = 1.0f / wsum;
  long rb = (long)row * kD;
  float b0 = cwo[rb + t] + bo[t];
  float b1 = cwo[rb + t + 256] + bo[t + 256];
  float b2v = cwo[rb + t + 512] + bo[t + 512];
  float a0 = 0.f, a1 = 0.f, a2 = 0.f;
  for (int e = 0; e < kE; e++) {
    float we = w[e];
    if (we == 0.f) continue;
    const float* vr = vvs + e * 8;
    float y0 = b0 + 2.0f * dot8(Bd + ((long)(e * kD + t)) * 8, vr);
    float y1 = b1 + 2.0f * dot8(Bd + ((long)(e * kD + t + 256)) * 8, vr);
    float y2 = b2v + 2.0f * dot8(Bd + ((long)(e * kD + t + 512)) * 8, vr);
    float m = block_sum(y0 + y1 + y2) * (1.0f / 768.0f);
    float d0 = y0 - m, d1 = y1 - m, d2 = y2 - m;
    float q = block_sum(d0 * d0 + d1 * d1 + d2 * d2);
    float inv = rsqrtf(q * (1.0f / 768.0f) + 1e-5f);
    float sc = we * winv * inv;
    a0 += sc * d0;
    a1 += sc * d1;
    a2 += sc * d2;
  }
  h[rb + t] = a0 + res1[rb + t];
  h[rb + t + 256] = a1 + res1[rb + t + 256];
  h[rb + t + 512] = a2 + res1[rb + t + 512];
}

}  // namespace

extern "C" void kernel_launch(void* const* d_in, const int* in_sizes, int n_in,
                              void* d_out, int out_size, void* d_ws, size_t ws_size,
                              hipStream_t stream) {
  const float* region = (const float*)d_in[0];
  const float* mask = (const float*)d_in[1];
  const float* cls = (const float*)d_in[2];
  const float* ln1g = (const float*)d_in[3];
  const float* ln1b = (const float*)d_in[4];
  const float* ln2g = (const float*)d_in[5];
  const float* ln2b = (const float*)d_in[6];
  const float* Wq = (const float*)d_in[7];
  const float* bq = (const float*)d_in[8];
  const float* Wk = (const float*)d_in[9];
  const float* bk = (const float*)d_in[10];
  const float* Wv = (const float*)d_in[11];
  const float* bv = (const float*)d_in[12];
  const float* Wao = (const float*)d_in[13];
  const float* bao = (const float*)d_in[14];
  const float* Wi = (const float*)d_in[15];
  const float* bi = (const float*)d_in[16];
  const float* Wo = (const float*)d_in[17];
  const float* bo = (const float*)d_in[18];
  const float* fg = (const float*)d_in[19];
  const float* fb = (const float*)d_in[20];
  const float* cW1 = (const float*)d_in[21];
  const float* cb1 = (const float*)d_in[22];
  const float* clng = (const float*)d_in[23];
  const float* clnb = (const float*)d_in[24];
  const float* cW2 = (const float*)d_in[25];
  const float* cb2 = (const float*)d_in[26];
  const float* Aup = (const float*)d_in[27];
  const float* Bup = (const float*)d_in[28];
  const float* Adn = (const float*)d_in[29];
  const float* Bdn = (const float*)d_in[30];
  float* out = (float*)d_out;

  char* wsb = (char*)d_ws;
  size_t off = 0;
  auto alloc = [&](size_t bytes) {
    char* p = wsb + off;
    off = (off + bytes + 255) & ~(size_t)255;
    return (void*)p;
  };
  float* h = (float*)alloc((size_t)kRows * kD * 4);
  float* qkv = (float*)alloc((size_t)kRows * kQKV * 4);
  float* ao = (float*)alloc((size_t)kRows * kD * 4);
  float* res1 = (float*)alloc((size_t)kRows * kD * 4);
  float* cwo = (float*)alloc((size_t)kRows * kD * 4);
  float* pooled = (float*)alloc((size_t)kND * kB * kD * 4);
  float* zb = (float*)alloc((size_t)kND * kB * 384 * 4);
  float* da = (float*)alloc((size_t)kB * kND * 4);
  float* ub = (float*)alloc((size_t)kRows * 128 * 4);
  float* ia = (float*)alloc((size_t)kRows * 128 * 4);
  float* vvb = (float*)alloc((size_t)kRows * 128 * 4);
  float* Mm = (float*)alloc((size_t)kNE * kE * 64 * 4);
  float* cc = (float*)alloc(64);
  short* n1h = (short*)alloc((size_t)kRows * kD * 2);
  short* n1l = (short*)alloc((size_t)kRows * kD * 2);
  short* n2h = (short*)alloc((size_t)kRows * kD * 2);
  short* n2l = (short*)alloc((size_t)kRows * kD * 2);
  short* inth = (short*)alloc((size_t)kRows * kH * 2);
  short* intl = (short*)alloc((size_t)kRows * kH * 2);
  short* wqkh = (short*)alloc((size_t)4 * kD * kD * 2);
  short* wqkl = (short*)alloc((size_t)4 * kD * kD * 2);
  short* wioh = (short*)alloc((size_t)2 * kD * kH * 2);
  short* wiol = (short*)alloc((size_t)2 * kD * kH * 2);
  short* luh = (short*)alloc((size_t)128 * kD * 2);
  short* lul = (short*)alloc((size_t)128 * kD * 2);
  short* ldh = (short*)alloc((size_t)128 * kH * 2);
  short* ldl = (short*)alloc((size_t)128 * kH * 2);

  concat_k<<<(kRows * kD + 255) / 256, 256, 0, stream>>>(region, cls, h);
  cc_k<<<1, 32, 0, stream>>>(mask, cc);
  mmat_k<<<kNE * kE, 256, 0, stream>>>(Adn, Bup, Mm);

  const int nDD = kD * kD;
  const int nDH = kD * kH;

  // n1 planes for layer 0
  ln_bf_k<<<kRows, 256, 0, stream>>>(h, nullptr, nullptr, nullptr, nullptr, ln1g,
                                     ln1b, n1h, n1l, 1e-12f);

  for (int i = 0; i < kL; i++) {
    int le = i >> 1;
    bool even = (i % 2) == 0;
    conv4_k<<<dim3(nDD / 1024, 4), 256, 0, stream>>>(
        Wq + (long)i * nDD, Wk + (long)i * nDD, Wv + (long)i * nDD,
        Wao + (long)i * nDD, wqkh, wqkl, nDD);
    conv4_k<<<dim3(nDH / 1024, 2), 256, 0, stream>>>(
        Wi + (long)i * nDH, Wo + (long)i * nDH, Wi, Wi, wioh, wiol, nDH);

    // QKV fused: B = [Wq;Wk;Wv], biases folded into attn_k.
    gemm_hl<false><<<dim3(kQKV / 128, 15), 256, 0, stream>>>(
        n1h, n1l, wqkh, wqkl, nullptr, nullptr, qkv, nullptr, nullptr, kD, kQKV,
        0, 0);
    attn_k<<<kB * kNH, 256, 0, stream>>>(qkv, bq + i * kD, bk + i * kD,
                                         bv + i * kD, n1h, n1l);
    hipMemsetAsync(ao, 0, (size_t)kRows * kD * 4, stream);
    gemm_hl<true><<<dim3(6, 15, 2), 256, 0, stream>>>(
        n1h, n1l, wqkh + 3L * nDD, wqkl + 3L * nDD, nullptr, nullptr, ao,
        nullptr, nullptr, kD, kD, 0, 384);
    addln_bf_k<<<kRows, 256, 0, stream>>>(ao, bao + i * kD, h, ln2g + i * kD,
                                          ln2b + i * kD, res1, n2h, n2l, 1e-12f);
    gemm_hl<false><<<dim3(24, 15), 256, 0, stream>>>(
        n2h, n2l, wioh, wiol, bi + i * kH, nullptr, nullptr, inth, intl, kD, kH,
        1, 0);
    hipMemsetAsync(cwo, 0, (size_t)kRows * kD * 4, stream);
    gemm_hl<true><<<dim3(6, 15, 4), 256, 0, stream>>>(
        inth, intl, wioh + (long)nDH, wiol + (long)nDH, nullptr, nullptr, cwo,
        nullptr, nullptr, kH, kD, 0, 768);
    if (even) {
      convpad_k<<<(128 * kD) / 1024, 256, 0, stream>>>(
          Aup + (long)le * kE * 8 * kD, luh, lul, kD);
      convpad_k<<<(128 * kH) / 1024, 256, 0, stream>>>(
          Adn + (long)le * kE * 8 * kH, ldh, ldl, kH);
      hipMemsetAsync(ub, 0, (size_t)kRows * 128 * 4, stream);
      hipMemsetAsync(ia, 0, (size_t)kRows * 128 * 4, stream);
      gemm_hl<true><<<dim3(1, 15, 8), 256, 0, stream>>>(
          n2h, n2l, luh, lul, nullptr, nullptr, ub, nullptr, nullptr, kD, 128, 0,
          96);
      gemm_hl<true><<<dim3(1, 15, 16), 256, 0, stream>>>(
          inth, intl, ldh, ldl, nullptr, nullptr, ia, nullptr, nullptr, kH, 128,
          0, 192);
      pool_k<<<kND * kB, 256, 0, stream>>>(ao, bao + i * kD, mask, cc, pooled);
      gemm_nt<64, 4><<<dim3(6, 1, kND), 256, 0, stream>>>(
          pooled, cW1 + (long)le * kND * 384 * kD, cb1 + (long)le * kND * 384, zb,
          64, 384, kD, (long)64 * kD, (long)384 * kD, 384, (long)64 * 384);
      cls2_k<<<kND * kB, 256, 0, stream>>>(zb, clng + (long)le * kND * 384,
                                           clnb + (long)le * kND * 384,
                                           cW2 + (long)le * kND * 384,
                                           cb2 + le * kND, da);
      vcomb_k<<<(kRows * 120 + 255) / 256, 256, 0, stream>>>(
          ub, ia, Mm + le * kE * 64, vvb);
      finaleven_k<<<kRows, 256, 0, stream>>>(cwo, bo + i * kD, res1, vvb,
                                             Bdn + (long)le * kE * kD * 8, da,
                                             mask, h);
      // n1 planes for layer i+1
      ln_bf_k<<<kRows, 256, 0, stream>>>(h, nullptr, nullptr, nullptr, nullptr,
                                         ln1g + (i + 1) * kD, ln1b + (i + 1) * kD,
                                         n1h, n1l, 1e-12f);
    } else if (i < kL - 1) {
      // h = cwo + bo + res1, then LN -> n1 planes for layer i+1
      ln_bf_k<<<kRows, 256, 0, stream>>>(nullptr, cwo, bo + i * kD, res1, h,
                                         ln1g + (i + 1) * kD, ln1b + (i + 1) * kD,
                                         n1h, n1l, 1e-12f);
    } else {
      ln_row_k<<<kRows, 256, 0, stream>>>(cwo, bo + i * kD, res1, fg, fb, out,
                                          1e-12f);
    }
  }
}

// Round 5
// 3339.526 us; speedup vs baseline: 2.4696x; 1.1568x over previous
//
#include <hip/hip_runtime.h>

namespace {

constexpr int kB = 64, kSR = 29, kS = 30, kD = 768, kH = 3072, kL = 12;
constexpr int kNH = 12, kND = 14, kE = 15, kNE = 6;
constexpr int kRows = kB * kS;  // 1920
constexpr int kQKV = 2304;

typedef __attribute__((ext_vector_type(8))) short s16x8;
typedef __attribute__((ext_vector_type(4))) float fx4;

__device__ __forceinline__ float gelu_f(float x) {
  return 0.5f * x * (1.0f + erff(x * 0.70710678118654752f));
}

__device__ __forceinline__ unsigned short f2bf_u(float x) {
  union { float f; unsigned u; } v;
  v.f = x;
  unsigned r = v.u + 0x7fffu + ((v.u >> 16) & 1u);
  return (unsigned short)(r >> 16);
}
__device__ __forceinline__ float bfu2f(unsigned short h) {
  union { unsigned u; float f; } v;
  v.u = ((unsigned)h) << 16;
  return v.f;
}

// async global->LDS, 16B per lane. LDS dest = uniform base + lane*16.
__device__ __forceinline__ void g2l16(const short* g, short* l) {
  __builtin_amdgcn_global_load_lds(
      (const __attribute__((address_space(1))) unsigned int*)g,
      (__attribute__((address_space(3))) unsigned int*)l, 16, 0, 0);
}

// XCD-aware bijective block swizzle (8 XCDs).
__device__ __forceinline__ void swz_block(int& bx, int& by, int& bz) {
  int gx = gridDim.x, gy = gridDim.y;
  int nwg = gx * gy * (int)gridDim.z;
  int orig = blockIdx.x + gx * (blockIdx.y + gy * blockIdx.z);
  int q = nwg >> 3, r = nwg & 7;
  int xcd = orig & 7, idx = orig >> 3;
  int s = (xcd < r ? xcd * (q + 1) : r * (q + 1) + (xcd - r) * q) + idx;
  bx = s % gx;
  int t2 = s / gx;
  by = t2 % gy;
  bz = t2 / gy;
}

__device__ __forceinline__ float block_sum(float v) {
  __shared__ float sb[4];
#pragma unroll
  for (int o = 32; o > 0; o >>= 1) v += __shfl_down(v, o, 64);
  int w = threadIdx.x >> 6;
  __syncthreads();
  if ((threadIdx.x & 63) == 0) sb[w] = v;
  __syncthreads();
  return sb[0] + sb[1] + sb[2] + sb[3];
}

__device__ __forceinline__ float dot8(const float* __restrict__ p,
                                      const float* __restrict__ q) {
  float4 x = *(const float4*)p;
  float4 y = *(const float4*)(p + 4);
  return x.x * q[0] + x.y * q[1] + x.z * q[2] + x.w * q[3] +
         y.x * q[4] + y.y * q[5] + y.z * q[6] + y.w * q[7];
}

// ---------------------------------------------------------------------------
// MFMA GEMM, C = A @ B^T, hi/lo bf16 planes, 3-pass (hh+hl+lh ~ fp32).
// A: row-major [M][K] planes. B: PRE-PACKED fragment-linear planes
// (tile (nf,ks) at offset (nf*(K/32)+ks)*512 + lane*8, lane=(kgrp*16+row)).
// Tile BMxBN, BK=32, 4 waves (2x2). Double-buffered LDS, global_load_lds,
// one __syncthreads per K-step. MODE: 0 plain, 1 split-K (atomicAdd into
// pre-zeroed Cf), 2 batched over blockIdx.z.
// ---------------------------------------------------------------------------
template <int BM, int BN, int MODE>
__global__ __launch_bounds__(256) void gemm_hl(
    const short* __restrict__ Ah, const short* __restrict__ Al,
    const short* __restrict__ Bh, const short* __restrict__ Bl,
    const float* __restrict__ bias, float* __restrict__ Cf,
    short* __restrict__ Ch, short* __restrict__ Cl, int K, int ldc, int act,
    int kchunk, long bsA, long bsB, long bsBias, long bsC) {
  constexpr int MFR = BM / 16, NFR = BN / 16;
  constexpr int NA = 2 * MFR, NB = 2 * NFR, LPW = (NA + NB) / 4;
  constexpr int MF_W = MFR / 2, NF_W = NFR / 2;
  __shared__ __align__(16) short As[2][2][MFR][512];
  __shared__ __align__(16) short Bs[2][2][NFR][512];
  int bx, by, bz;
  swz_block(bx, by, bz);
  const int t = threadIdx.x, w = t >> 6, lane = t & 63;
  const int lr = lane & 15, lg = lane >> 4;
  const int m0 = by * BM, n0 = bx * BN;
  const int kst = K >> 5;
  int k0 = 0;
  if (MODE == 1) k0 = bz * kchunk;
  if (MODE == 2) {
    Ah += bz * bsA;
    Al += bz * bsA;
    Bh += bz * bsB;
    Bl += bz * bsB;
    if (bias) bias += bz * bsBias;
    Cf += bz * bsC;
  }
  const int nsteps = (MODE == 1 ? kchunk : K) >> 5;
  const int wmf = (w & 1) * MF_W, wnf = (w >> 1) * NF_W;

  const short* gp[LPW];
  short* lp[LPW];
  int bo[LPW], adv[LPW];
#pragma unroll
  for (int q = 0; q < LPW; q++) {
    int f = w * LPW + q;
    if (f < NA) {
      int p = f & 1, mf = f >> 1;
      gp[q] = (p ? Al : Ah) + (size_t)(m0 + mf * 16 + lr) * K + k0 + lg * 8;
      lp[q] = &As[0][p][mf][0];
      bo[q] = 2 * MFR * 512;
      adv[q] = 32;
    } else {
      int fb = f - NA, p = fb & 1, nf = fb >> 1;
      gp[q] = (p ? Bl : Bh) + ((size_t)(n0 / 16 + nf) * kst + (k0 >> 5)) * 512 +
              lane * 8;
      lp[q] = &Bs[0][p][nf][0];
      bo[q] = 2 * NFR * 512;
      adv[q] = 512;
    }
  }

  fx4 acc[MF_W][NF_W];
#pragma unroll
  for (int i = 0; i < MF_W; i++)
#pragma unroll
    for (int j = 0; j < NF_W; j++) acc[i][j] = (fx4)0.f;

  // prologue
#pragma unroll
  for (int q = 0; q < LPW; q++) {
    g2l16(gp[q], lp[q]);
    gp[q] += adv[q];
  }
  __syncthreads();

  int cur = 0;
  for (int s = 0; s < nsteps; s++) {
    if (s + 1 < nsteps) {
#pragma unroll
      for (int q = 0; q < LPW; q++) {
        g2l16(gp[q], lp[q] + (cur ^ 1) * bo[q]);
        gp[q] += adv[q];
      }
    }
    s16x8 af[MF_W][2], bf[NF_W][2];
#pragma unroll
    for (int fm = 0; fm < MF_W; fm++) {
      af[fm][0] = *(const s16x8*)&As[cur][0][wmf + fm][lane * 8];
      af[fm][1] = *(const s16x8*)&As[cur][1][wmf + fm][lane * 8];
    }
#pragma unroll
    for (int fn = 0; fn < NF_W; fn++) {
      bf[fn][0] = *(const s16x8*)&Bs[cur][0][wnf + fn][lane * 8];
      bf[fn][1] = *(const s16x8*)&Bs[cur][1][wnf + fn][lane * 8];
    }
    // pass-outermost: all accs independent between reuses
#pragma unroll
    for (int fm = 0; fm < MF_W; fm++)
#pragma unroll
      for (int fn = 0; fn < NF_W; fn++)
        acc[fm][fn] = __builtin_amdgcn_mfma_f32_16x16x32_bf16(
            af[fm][0], bf[fn][0], acc[fm][fn], 0, 0, 0);
#pragma unroll
    for (int fm = 0; fm < MF_W; fm++)
#pragma unroll
      for (int fn = 0; fn < NF_W; fn++)
        acc[fm][fn] = __builtin_amdgcn_mfma_f32_16x16x32_bf16(
            af[fm][0], bf[fn][1], acc[fm][fn], 0, 0, 0);
#pragma unroll
    for (int fm = 0; fm < MF_W; fm++)
#pragma unroll
      for (int fn = 0; fn < NF_W; fn++)
        acc[fm][fn] = __builtin_amdgcn_mfma_f32_16x16x32_bf16(
            af[fm][1], bf[fn][0], acc[fm][fn], 0, 0, 0);
    __syncthreads();
    cur ^= 1;
  }

  const int orow = (lane >> 4) * 4;
#pragma unroll
  for (int fm = 0; fm < MF_W; fm++) {
#pragma unroll
    for (int fn = 0; fn < NF_W; fn++) {
      int col = n0 + (wnf + fn) * 16 + lr;
      if (MODE == 1) {
#pragma unroll
        for (int j = 0; j < 4; j++) {
          int row = m0 + (wmf + fm) * 16 + orow + j;
          atomicAdd(&Cf[(size_t)row * ldc + col], acc[fm][fn][j]);
        }
      } else {
        float bv = bias ? bias[col] : 0.f;
#pragma unroll
        for (int j = 0; j < 4; j++) {
          int row = m0 + (wmf + fm) * 16 + orow + j;
          float v = acc[fm][fn][j] + bv;
          if (act) v = gelu_f(v);
          size_t idx = (size_t)row * ldc + col;
          if (Cf) Cf[idx] = v;
          if (Ch) {
            unsigned short hb = f2bf_u(v);
            Ch[idx] = (short)hb;
            Cl[idx] = (short)f2bf_u(v - bfu2f(hb));
          }
        }
      }
    }
  }
}

// ---------- weight packing: fp32 [N][K] -> fragment-linear hi/lo planes ----
__device__ __forceinline__ void pack_store(const float* src, short* ph,
                                           short* pl, size_t o) {
  float4 a = *(const float4*)src;
  float4 b = *(const float4*)(src + 4);
  float v[8] = {a.x, a.y, a.z, a.w, b.x, b.y, b.z, b.w};
  s16x8 hv, lv;
#pragma unroll
  for (int e = 0; e < 8; e++) {
    unsigned short h = f2bf_u(v[e]);
    hv[e] = (short)h;
    lv[e] = (short)f2bf_u(v[e] - bfu2f(h));
  }
  *(s16x8*)(ph + o) = hv;
  *(s16x8*)(pl + o) = lv;
}

__global__ __launch_bounds__(256) void pack_w_k(const float* __restrict__ W,
                                                short* __restrict__ ph,
                                                short* __restrict__ pl, int K,
                                                int ntiles) {
  int tile = blockIdx.x * 4 + (threadIdx.x >> 6);
  if (tile >= ntiles) return;
  int kst = K >> 5;
  int nf = tile / kst, ks = tile - nf * kst;
  int lane = threadIdx.x & 63;
  int lr = lane & 15, lg = lane >> 4;
  const float* src = W + (size_t)(nf * 16 + lr) * K + ks * 32 + lg * 8;
  pack_store(src, ph, pl, (size_t)tile * 512 + lane * 8);
}

// Packs [Wq;Wk;Wv] (N=2304, K=768).
__global__ __launch_bounds__(256) void pack_qkv_k(const float* __restrict__ Wq,
                                                  const float* __restrict__ Wk,
                                                  const float* __restrict__ Wv,
                                                  short* __restrict__ ph,
                                                  short* __restrict__ pl) {
  int tile = blockIdx.x * 4 + (threadIdx.x >> 6);
  if (tile >= 144 * 24) return;
  int nf = tile / 24, ks = tile - nf * 24;
  int lane = threadIdx.x & 63;
  int lr = lane & 15, lg = lane >> 4;
  int row = nf * 16 + lr;
  const float* src;
  if (row < 768)
    src = Wq + (size_t)row * 768;
  else if (row < 1536)
    src = Wk + (size_t)(row - 768) * 768;
  else
    src = Wv + (size_t)(row - 1536) * 768;
  pack_store(src + ks * 32 + lg * 8, ph, pl, (size_t)tile * 512 + lane * 8);
}

// Packs 120xK matrix into 128-row frags (rows 120..127 zero).
__global__ __launch_bounds__(256) void pack_pad_k(const float* __restrict__ W,
                                                  short* __restrict__ ph,
                                                  short* __restrict__ pl,
                                                  int K) {
  int tile = blockIdx.x * 4 + (threadIdx.x >> 6);
  int kst = K >> 5;
  if (tile >= 8 * kst) return;
  int nf = tile / kst, ks = tile - nf * kst;
  int lane = threadIdx.x & 63;
  int lr = lane & 15, lg = lane >> 4;
  int row = nf * 16 + lr;
  size_t o = (size_t)tile * 512 + lane * 8;
  if (row < 120) {
    pack_store(W + (size_t)row * K + ks * 32 + lg * 8, ph, pl, o);
  } else {
    *(s16x8*)(ph + o) = (s16x8)0;
    *(s16x8*)(pl + o) = (s16x8)0;
  }
}

__global__ __launch_bounds__(256) void concat_k(const float* __restrict__ rf,
                                                const float* __restrict__ cls,
                                                float* __restrict__ h) {
  int idx = blockIdx.x * 256 + threadIdx.x;
  if (idx >= kRows * kD) return;
  int d = idx % kD;
  int row = idx / kD;
  int s = row % kS;
  int b = row / kS;
  h[idx] = (s == 0) ? cls[d] : rf[((long)b * kSR + (s - 1)) * kD + d];
}

__global__ void cc_k(const float* __restrict__ mask, float* __restrict__ cc) {
  int d = threadIdx.x;
  if (d < kND) {
    float s = 0.f;
    for (int r = 0; r < kSR; r++) s += mask[r * kND + d];
    cc[d] = s;
  }
}

__global__ __launch_bounds__(256) void mmat_k(const float* __restrict__ Adn,
                                              const float* __restrict__ Bup,
                                              float* __restrict__ Mm) {
  int g = blockIdx.x;
  int t = threadIdx.x;
  int pair = t & 63;
  int quarter = t >> 6;
  int rp = pair >> 3, r = pair & 7;
  const float* ad = Adn + (long)(g * 8 + rp) * kH;
  const float* bu = Bup + (long)g * kH * 8 + r;
  float acc = 0.f;
  for (int hh = quarter * 768; hh < quarter * 768 + 768; hh++)
    acc += ad[hh] * bu[hh * 8];
  __shared__ float red[256];
  red[t] = acc;
  __syncthreads();
  if (t < 64) Mm[g * 64 + pair] = red[t] + red[t + 64] + red[t + 128] + red[t + 192];
}

// LN -> hi/lo bf16 planes. Optional fused pre-add: x = c2 + b2 + r2 (written
// to hout) when c2 != null, else x read directly.
__global__ __launch_bounds__(256) void ln_bf_k(
    const float* __restrict__ x, const float* __restrict__ c2,
    const float* __restrict__ b2, const float* __restrict__ r2,
    float* __restrict__ hout, const float* __restrict__ g,
    const float* __restrict__ b, short* __restrict__ yh,
    short* __restrict__ yl, float eps) {
  int row = blockIdx.x;
  int t = threadIdx.x;
  long rb = (long)row * kD;
  float v0, v1, v2;
  if (c2) {
    v0 = c2[rb + t] + b2[t] + r2[rb + t];
    v1 = c2[rb + t + 256] + b2[t + 256] + r2[rb + t + 256];
    v2 = c2[rb + t + 512] + b2[t + 512] + r2[rb + t + 512];
    hout[rb + t] = v0;
    hout[rb + t + 256] = v1;
    hout[rb + t + 512] = v2;
  } else {
    v0 = x[rb + t];
    v1 = x[rb + t + 256];
    v2 = x[rb + t + 512];
  }
  float m = block_sum(v0 + v1 + v2) * (1.0f / 768.0f);
  float d0 = v0 - m, d1 = v1 - m, d2 = v2 - m;
  float q = block_sum(d0 * d0 + d1 * d1 + d2 * d2);
  float inv = rsqrtf(q * (1.0f / 768.0f) + eps);
#pragma unroll
  for (int c = 0; c < 3; c++) {
    int tt = t + c * 256;
    float dd = (c == 0 ? d0 : c == 1 ? d1 : d2);
    float val = dd * inv * g[tt] + b[tt];
    unsigned short hb = f2bf_u(val);
    yh[rb + tt] = (short)hb;
    yl[rb + tt] = (short)f2bf_u(val - bfu2f(hb));
  }
}

// Final LN -> fp32 out, fused h = c2 + b2 + r2.
__global__ __launch_bounds__(256) void ln_row_k(
    const float* __restrict__ c2, const float* __restrict__ b2,
    const float* __restrict__ r2, const float* __restrict__ g,
    const float* __restrict__ b, float* __restrict__ y, float eps) {
  int row = blockIdx.x;
  int t = threadIdx.x;
  long rb = (long)row * kD;
  float v0 = c2[rb + t] + b2[t] + r2[rb + t];
  float v1 = c2[rb + t + 256] + b2[t + 256] + r2[rb + t + 256];
  float v2 = c2[rb + t + 512] + b2[t + 512] + r2[rb + t + 512];
  float m = block_sum(v0 + v1 + v2) * (1.0f / 768.0f);
  float d0 = v0 - m, d1 = v1 - m, d2 = v2 - m;
  float q = block_sum(d0 * d0 + d1 * d1 + d2 * d2);
  float inv = rsqrtf(q * (1.0f / 768.0f) + eps);
  y[rb + t] = d0 * inv * g[t] + b[t];
  y[rb + t + 256] = d1 * inv * g[t + 256] + b[t + 256];
  y[rb + t + 512] = d2 * inv * g[t + 512] + b[t + 512];
}

// res1 = a + abias + h ; n2 = LN(res1) -> hi/lo planes
__global__ __launch_bounds__(256) void addln_bf_k(
    const float* __restrict__ a, const float* __restrict__ abias,
    const float* __restrict__ hh, const float* __restrict__ g,
    const float* __restrict__ b, float* __restrict__ r1,
    short* __restrict__ n2h, short* __restrict__ n2l, float eps) {
  int row = blockIdx.x;
  int t = threadIdx.x;
  long rb = (long)row * kD;
  float v0 = a[rb + t] + abias[t] + hh[rb + t];
  float v1 = a[rb + t + 256] + abias[t + 256] + hh[rb + t + 256];
  float v2 = a[rb + t + 512] + abias[t + 512] + hh[rb + t + 512];
  r1[rb + t] = v0;
  r1[rb + t + 256] = v1;
  r1[rb + t + 512] = v2;
  float m = block_sum(v0 + v1 + v2) * (1.0f / 768.0f);
  float d0 = v0 - m, d1 = v1 - m, d2 = v2 - m;
  float q = block_sum(d0 * d0 + d1 * d1 + d2 * d2);
  float inv = rsqrtf(q * (1.0f / 768.0f) + eps);
#pragma unroll
  for (int c = 0; c < 3; c++) {
    int tt = t + c * 256;
    float dd = (c == 0 ? d0 : c == 1 ? d1 : d2);
    float val = dd * inv * g[tt] + b[tt];
    unsigned short hb = f2bf_u(val);
    n2h[rb + tt] = (short)hb;
    n2l[rb + tt] = (short)f2bf_u(val - bfu2f(hb));
  }
}

// One block per (b, head). Reads packed qkv [1920][2304], adds biases inline.
__global__ __launch_bounds__(256) void attn_k(const float* __restrict__ qkv,
                                              const float* __restrict__ bq,
                                              const float* __restrict__ bk,
                                              const float* __restrict__ bv,
                                              short* __restrict__ oh,
                                              short* __restrict__ ol) {
  int blk = blockIdx.x;
  int b = blk / kNH, hh = blk % kNH;
  __shared__ float qs[30][65], ks[30][65], vs[30][65], ps[30][32];
  int t = threadIdx.x;
  long ibase = (long)b * kS * kQKV + hh * 64;
  long obase = (long)b * kS * kD + hh * 64;
  for (int idx = t; idx < 1920; idx += 256) {
    int s = idx >> 6, d = idx & 63;
    long a = ibase + (long)s * kQKV + d;
    int bcol = hh * 64 + d;
    qs[s][d] = qkv[a] + bq[bcol];
    ks[s][d] = qkv[a + 768] + bk[bcol];
    vs[s][d] = qkv[a + 1536] + bv[bcol];
  }
  __syncthreads();
  for (int idx = t; idx < 900; idx += 256) {
    int r = idx / 30, c = idx % 30;
    float acc = 0.f;
#pragma unroll
    for (int d = 0; d < 64; d++) acc += qs[r][d] * ks[c][d];
    ps[r][c] = acc * 0.125f;
  }
  __syncthreads();
  if (t < 30) {
    float mx = -1e30f;
#pragma unroll
    for (int c = 0; c < 30; c++) mx = fmaxf(mx, ps[t][c]);
    float sm = 0.f;
#pragma unroll
    for (int c = 0; c < 30; c++) sm += expf(ps[t][c] - mx);
    float inv = 1.0f / sm;
#pragma unroll
    for (int c = 0; c < 30; c++) ps[t][c] = expf(ps[t][c] - mx) * inv;
  }
  __syncthreads();
  for (int idx = t; idx < 1920; idx += 256) {
    int r = idx >> 6, d = idx & 63;
    float acc = 0.f;
#pragma unroll
    for (int c = 0; c < 30; c++) acc += ps[r][c] * vs[c][d];
    long a = obase + (long)r * kD + d;
    unsigned short hb = f2bf_u(acc);
    oh[a] = (short)hb;
    ol[a] = (short)f2bf_u(acc - bfu2f(hb));
  }
}

// pooled (row d*64+b) = (sum_r mask*ao_nobias)/cc + bao -> hi/lo planes
__global__ __launch_bounds__(256) void pool_k(const float* __restrict__ ao,
                                              const float* __restrict__ bao,
                                              const float* __restrict__ mask,
                                              const float* __restrict__ cc,
                                              short* __restrict__ ph,
                                              short* __restrict__ pl) {
  int blk = blockIdx.x;
  int d = blk >> 6, b = blk & 63;
  __shared__ float mr[32];
  int t = threadIdx.x;
  if (t < kSR) mr[t] = mask[t * kND + d];
  __syncthreads();
  float inv = 1.0f / cc[d];
  for (int hd = t; hd < kD; hd += 256) {
    float acc = 0.f;
    for (int r = 0; r < kSR; r++) acc += mr[r] * ao[((long)b * kS + 1 + r) * kD + hd];
    float v = acc * inv + bao[hd];
    unsigned short hb = f2bf_u(v);
    size_t o = (size_t)blk * kD + hd;
    ph[o] = (short)hb;
    pl[o] = (short)f2bf_u(v - bfu2f(hb));
  }
}

__global__ __launch_bounds__(256) void cls2_k(const float* __restrict__ z,
                                              const float* __restrict__ lng,
                                              const float* __restrict__ lnb,
                                              const float* __restrict__ w2,
                                              const float* __restrict__ b2,
                                              float* __restrict__ da) {
  int blk = blockIdx.x;
  int d = blk >> 6, b = blk & 63;
  int t = threadIdx.x;
  const float* zr = z + (long)blk * 384;
  float v0 = zr[t];
  float v1 = (t < 128) ? zr[256 + t] : 0.f;
  float m = block_sum(v0 + v1) * (1.0f / 384.0f);
  float d0 = v0 - m;
  float d1 = (t < 128) ? v1 - m : 0.f;
  float q = block_sum(d0 * d0 + d1 * d1);
  float inv = rsqrtf(q * (1.0f / 384.0f) + 1e-5f);
  const float* lg = lng + (long)d * 384;
  const float* lb = lnb + (long)d * 384;
  const float* wd = w2 + (long)d * 384;
  float p = gelu_f(d0 * inv * lg[t] + lb[t]) * wd[t];
  if (t < 128) p += gelu_f(d1 * inv * lg[256 + t] + lb[256 + t]) * wd[256 + t];
  float ps = block_sum(p);
  if (t == 0) da[b * kND + d] = (ps + b2[d] > 0.f) ? 1.f : 0.f;
}

__global__ __launch_bounds__(256) void vcomb_k(const float* __restrict__ u,
                                               const float* __restrict__ ia,
                                               const float* __restrict__ Mm,
                                               float* __restrict__ vv) {
  int idx = blockIdx.x * 256 + threadIdx.x;
  if (idx >= kRows * 120) return;
  int row = idx / 120, c = idx % 120;
  int e = c >> 3, rp = c & 7;
  const float* Me = Mm + e * 64 + rp * 8;
  const float* ur = u + (long)row * 128 + e * 8;
  float acc = ia[(long)row * 128 + c];
#pragma unroll
  for (int r = 0; r < 8; r++) acc += 2.0f * Me[r] * ur[r];
  vv[(long)row * 128 + c] = acc;
}

// Per (b,s): base = cwo + bo; expert loop LN_plain + weighted sum; h = acc+res1.
__global__ __launch_bounds__(256) void finaleven_k(
    const float* __restrict__ cwo, const float* __restrict__ bo,
    const float* __restrict__ res1, const float* __restrict__ vv,
    const float* __restrict__ Bd, const float* __restrict__ da,
    const float* __restrict__ mask, float* __restrict__ h) {
  int row = blockIdx.x;
  int b = row / kS, s = row % kS;
  int t = threadIdx.x;
  __shared__ float w[16];
  __shared__ float vvs[120];
  if (t < 120) vvs[t] = vv[(long)row * 128 + t];
  if (t < kND) w[t] = (s >= 1) ? da[b * kND + t] * mask[(s - 1) * kND + t] : 0.f;
  if (t == kND) w[kND] = 1.f;
  __syncthreads();
  float wsum = 0.f;
#pragma unroll
  for (int e = 0; e < kE; e++) wsum += w[e];
  float winv = 1.0f / wsum;
  long rb = (long)row * kD;
  float b0 = cwo[rb + t] + bo[t];
  float b1 = cwo[rb + t + 256] + bo[t + 256];
  float b2v = cwo[rb + t + 512] + bo[t + 512];
  float a0 = 0.f, a1 = 0.f, a2 = 0.f;
  for (int e = 0; e < kE; e++) {
    float we = w[e];
    if (we == 0.f) continue;
    const float* vr = vvs + e * 8;
    float y0 = b0 + 2.0f * dot8(Bd + ((long)(e * kD + t)) * 8, vr);
    float y1 = b1 + 2.0f * dot8(Bd + ((long)(e * kD + t + 256)) * 8, vr);
    float y2 = b2v + 2.0f * dot8(Bd + ((long)(e * kD + t + 512)) * 8, vr);
    float m = block_sum(y0 + y1 + y2) * (1.0f / 768.0f);
    float d0 = y0 - m, d1 = y1 - m, d2 = y2 - m;
    float q = block_sum(d0 * d0 + d1 * d1 + d2 * d2);
    float inv = rsqrtf(q * (1.0f / 768.0f) + 1e-5f);
    float sc = we * winv * inv;
    a0 += sc * d0;
    a1 += sc * d1;
    a2 += sc * d2;
  }
  h[rb + t] = a0 + res1[rb + t];
  h[rb + t + 256] = a1 + res1[rb + t + 256];
  h[rb + t + 512] = a2 + res1[rb + t + 512];
}

}  // namespace

extern "C" void kernel_launch(void* const* d_in, const int* in_sizes, int n_in,
                              void* d_out, int out_size, void* d_ws, size_t ws_size,
                              hipStream_t stream) {
  const float* region = (const float*)d_in[0];
  const float* mask = (const float*)d_in[1];
  const float* cls = (const float*)d_in[2];
  const float* ln1g = (const float*)d_in[3];
  const float* ln1b = (const float*)d_in[4];
  const float* ln2g = (const float*)d_in[5];
  const float* ln2b = (const float*)d_in[6];
  const float* Wq = (const float*)d_in[7];
  const float* bq = (const float*)d_in[8];
  const float* Wk = (const float*)d_in[9];
  const float* bk = (const float*)d_in[10];
  const float* Wv = (const float*)d_in[11];
  const float* bv = (const float*)d_in[12];
  const float* Wao = (const float*)d_in[13];
  const float* bao = (const float*)d_in[14];
  const float* Wi = (const float*)d_in[15];
  const float* bi = (const float*)d_in[16];
  const float* Wo = (const float*)d_in[17];
  const float* bo = (const float*)d_in[18];
  const float* fg = (const float*)d_in[19];
  const float* fb = (const float*)d_in[20];
  const float* cW1 = (const float*)d_in[21];
  const float* cb1 = (const float*)d_in[22];
  const float* clng = (const float*)d_in[23];
  const float* clnb = (const float*)d_in[24];
  const float* cW2 = (const float*)d_in[25];
  const float* cb2 = (const float*)d_in[26];
  const float* Aup = (const float*)d_in[27];
  const float* Bup = (const float*)d_in[28];
  const float* Adn = (const float*)d_in[29];
  const float* Bdn = (const float*)d_in[30];
  float* out = (float*)d_out;

  char* wsb = (char*)d_ws;
  size_t off = 0;
  auto alloc = [&](size_t bytes) {
    char* p = wsb + off;
    off = (off + bytes + 255) & ~(size_t)255;
    return (void*)p;
  };
  float* h = (float*)alloc((size_t)kRows * kD * 4);
  float* qkv = (float*)alloc((size_t)kRows * kQKV * 4);
  float* ao = (float*)alloc((size_t)kRows * kD * 4);
  float* res1 = (float*)alloc((size_t)kRows * kD * 4);
  float* cwo = (float*)alloc((size_t)kRows * kD * 4);
  float* zb = (float*)alloc((size_t)kND * kB * 384 * 4);
  float* da = (float*)alloc((size_t)kB * kND * 4);
  float* ub = (float*)alloc((size_t)kRows * 128 * 4);
  float* ia = (float*)alloc((size_t)kRows * 128 * 4);
  float* vvb = (float*)alloc((size_t)kRows * 128 * 4);
  float* Mm = (float*)alloc((size_t)kNE * kE * 64 * 4);
  float* cc = (float*)alloc(64);
  short* n1h = (short*)alloc((size_t)kRows * kD * 2);
  short* n1l = (short*)alloc((size_t)kRows * kD * 2);
  short* n2h = (short*)alloc((size_t)kRows * kD * 2);
  short* n2l = (short*)alloc((size_t)kRows * kD * 2);
  short* inth = (short*)alloc((size_t)kRows * kH * 2);
  short* intl = (short*)alloc((size_t)kRows * kH * 2);
  short* pooledh = (short*)alloc((size_t)kND * kB * kD * 2);
  short* pooledl = (short*)alloc((size_t)kND * kB * kD * 2);
  // packed weights (frag-linear): tiles * 512 shorts
  short* qkvph = (short*)alloc((size_t)144 * 24 * 512 * 2);
  short* qkvpl = (short*)alloc((size_t)144 * 24 * 512 * 2);
  short* waoph = (short*)alloc((size_t)48 * 24 * 512 * 2);
  short* waopl = (short*)alloc((size_t)48 * 24 * 512 * 2);
  short* wiph = (short*)alloc((size_t)192 * 24 * 512 * 2);
  short* wipl = (short*)alloc((size_t)192 * 24 * 512 * 2);
  short* woph = (short*)alloc((size_t)48 * 96 * 512 * 2);
  short* wopl = (short*)alloc((size_t)48 * 96 * 512 * 2);
  short* luph = (short*)alloc((size_t)8 * 24 * 512 * 2);
  short* lupl = (short*)alloc((size_t)8 * 24 * 512 * 2);
  short* ldph = (short*)alloc((size_t)8 * 96 * 512 * 2);
  short* ldpl = (short*)alloc((size_t)8 * 96 * 512 * 2);
  short* cw1ph = (short*)alloc((size_t)336 * 24 * 512 * 2);
  short* cw1pl = (short*)alloc((size_t)336 * 24 * 512 * 2);

  concat_k<<<(kRows * kD + 255) / 256, 256, 0, stream>>>(region, cls, h);
  cc_k<<<1, 32, 0, stream>>>(mask, cc);
  mmat_k<<<kNE * kE, 256, 0, stream>>>(Adn, Bup, Mm);

  const int nDD = kD * kD;
  const int nDH = kD * kH;

  // n1 planes for layer 0
  ln_bf_k<<<kRows, 256, 0, stream>>>(h, nullptr, nullptr, nullptr, nullptr, ln1g,
                                     ln1b, n1h, n1l, 1e-12f);

  for (int i = 0; i < kL; i++) {
    int le = i >> 1;
    bool even = (i % 2) == 0;
    // weight packing
    pack_qkv_k<<<(144 * 24) / 4, 256, 0, stream>>>(
        Wq + (long)i * nDD, Wk + (long)i * nDD, Wv + (long)i * nDD, qkvph, qkvpl);
    pack_w_k<<<(48 * 24) / 4, 256, 0, stream>>>(Wao + (long)i * nDD, waoph, waopl,
                                                768, 48 * 24);
    pack_w_k<<<(192 * 24) / 4, 256, 0, stream>>>(Wi + (long)i * nDH, wiph, wipl,
                                                 768, 192 * 24);
    pack_w_k<<<(48 * 96) / 4, 256, 0, stream>>>(Wo + (long)i * nDH, woph, wopl,
                                                3072, 48 * 96);

    // QKV (N=2304, plain)
    gemm_hl<128, 64, 0><<<dim3(36, 15), 256, 0, stream>>>(
        n1h, n1l, qkvph, qkvpl, nullptr, qkv, nullptr, nullptr, 768, kQKV, 0, 0,
        0, 0, 0, 0);
    attn_k<<<kB * kNH, 256, 0, stream>>>(qkv, bq + i * kD, bk + i * kD,
                                         bv + i * kD, n1h, n1l);
    // Wao (split-K x2)
    hipMemsetAsync(ao, 0, (size_t)kRows * kD * 4, stream);
    gemm_hl<128, 64, 1><<<dim3(12, 15, 2), 256, 0, stream>>>(
        n1h, n1l, waoph, waopl, nullptr, ao, nullptr, nullptr, 768, kD, 0, 384,
        0, 0, 0, 0);
    addln_bf_k<<<kRows, 256, 0, stream>>>(ao, bao + i * kD, h, ln2g + i * kD,
                                          ln2b + i * kD, res1, n2h, n2l, 1e-12f);
    // Wi (N=3072, gelu, planes out)
    gemm_hl<128, 64, 0><<<dim3(48, 15), 256, 0, stream>>>(
        n2h, n2l, wiph, wipl, bi + i * kH, nullptr, inth, intl, 768, kH, 1, 0,
        0, 0, 0, 0);
    // Wo (split-K x4)
    hipMemsetAsync(cwo, 0, (size_t)kRows * kD * 4, stream);
    gemm_hl<128, 64, 1><<<dim3(12, 15, 4), 256, 0, stream>>>(
        inth, intl, woph, wopl, nullptr, cwo, nullptr, nullptr, 3072, kD, 0, 768,
        0, 0, 0, 0);
    if (even) {
      pack_pad_k<<<(8 * 24 + 3) / 4, 256, 0, stream>>>(
          Aup + (long)le * kE * 8 * kD, luph, lupl, 768);
      pack_pad_k<<<(8 * 96) / 4, 256, 0, stream>>>(
          Adn + (long)le * kE * 8 * kH, ldph, ldpl, 3072);
      pack_w_k<<<(336 * 24) / 4, 256, 0, stream>>>(
          cW1 + (long)le * kND * 384 * kD, cw1ph, cw1pl, 768, 336 * 24);
      hipMemsetAsync(ub, 0, (size_t)kRows * 128 * 4, stream);
      hipMemsetAsync(ia, 0, (size_t)kRows * 128 * 4, stream);
      gemm_hl<128, 64, 1><<<dim3(2, 15, 8), 256, 0, stream>>>(
          n2h, n2l, luph, lupl, nullptr, ub, nullptr, nullptr, 768, 128, 0, 96,
          0, 0, 0, 0);
      gemm_hl<128, 64, 1><<<dim3(2, 15, 16), 256, 0, stream>>>(
          inth, intl, ldph, ldpl, nullptr, ia, nullptr, nullptr, 3072, 128, 0,
          192, 0, 0, 0, 0);
      pool_k<<<kND * kB, 256, 0, stream>>>(ao, bao + i * kD, mask, cc, pooledh,
                                           pooledl);
      // batched classifier GEMM: z = disease d (14), M=64, N=384, K=768
      gemm_hl<64, 64, 2><<<dim3(6, 1, 14), 256, 0, stream>>>(
          pooledh, pooledl, cw1ph, cw1pl, cb1 + (long)le * kND * 384, zb,
          nullptr, nullptr, 768, 384, 0, 0, (long)64 * kD, (long)576 * 512, 384,
          (long)64 * 384);
      cls2_k<<<kND * kB, 256, 0, stream>>>(zb, clng + (long)le * kND * 384,
                                           clnb + (long)le * kND * 384,
                                           cW2 + (long)le * kND * 384,
                                           cb2 + le * kND, da);
      vcomb_k<<<(kRows * 120 + 255) / 256, 256, 0, stream>>>(
          ub, ia, Mm + le * kE * 64, vvb);
      finaleven_k<<<kRows, 256, 0, stream>>>(cwo, bo + i * kD, res1, vvb,
                                             Bdn + (long)le * kE * kD * 8, da,
                                             mask, h);
      ln_bf_k<<<kRows, 256, 0, stream>>>(h, nullptr, nullptr, nullptr, nullptr,
                                         ln1g + (i + 1) * kD, ln1b + (i + 1) * kD,
                                         n1h, n1l, 1e-12f);
    } else if (i < kL - 1) {
      ln_bf_k<<<kRows, 256, 0, stream>>>(nullptr, cwo, bo + i * kD, res1, h,
                                         ln1g + (i + 1) * kD, ln1b + (i + 1) * kD,
                                         n1h, n1l, 1e-12f);
    } else {
      ln_row_k<<<kRows, 256, 0, stream>>>(cwo, bo + i * kD, res1, fg, fb, out,
                                          1e-12f);
    }
  }
}

// Round 6
// 3262.141 us; speedup vs baseline: 2.5282x; 1.0237x over previous
//
#include <hip/hip_runtime.h>

namespace {

constexpr int kB = 64, kSR = 29, kS = 30, kD = 768, kH = 3072, kL = 12;
constexpr int kNH = 12, kND = 14, kE = 15, kNE = 6;
constexpr int kRows = kB * kS;  // 1920
constexpr int kQKV = 2304;

typedef __attribute__((ext_vector_type(8))) short s16x8;
typedef __attribute__((ext_vector_type(4))) float fx4;

__device__ __forceinline__ float gelu_f(float x) {
  return 0.5f * x * (1.0f + erff(x * 0.70710678118654752f));
}

__device__ __forceinline__ unsigned short f2bf_u(float x) {
  union { float f; unsigned u; } v;
  v.f = x;
  unsigned r = v.u + 0x7fffu + ((v.u >> 16) & 1u);
  return (unsigned short)(r >> 16);
}
__device__ __forceinline__ float bfu2f(unsigned short h) {
  union { unsigned u; float f; } v;
  v.u = ((unsigned)h) << 16;
  return v.f;
}

// async global->LDS, 16B per lane. LDS dest = uniform base + lane*16.
__device__ __forceinline__ void g2l16(const short* g, short* l) {
  __builtin_amdgcn_global_load_lds(
      (const __attribute__((address_space(1))) unsigned int*)g,
      (__attribute__((address_space(3))) unsigned int*)l, 16, 0, 0);
}

template <int N>
__device__ __forceinline__ void waitcnt_vm() {
  if constexpr (N == 0)
    asm volatile("s_waitcnt vmcnt(0)" ::: "memory");
  else if constexpr (N == 4)
    asm volatile("s_waitcnt vmcnt(4)" ::: "memory");
  else if constexpr (N == 6)
    asm volatile("s_waitcnt vmcnt(6)" ::: "memory");
  else
    asm volatile("s_waitcnt vmcnt(8)" ::: "memory");
  __builtin_amdgcn_sched_barrier(0);
}

// XCD-aware bijective block swizzle (8 XCDs).
__device__ __forceinline__ void swz_block(int& bx, int& by, int& bz) {
  int gx = gridDim.x, gy = gridDim.y;
  int nwg = gx * gy * (int)gridDim.z;
  int orig = blockIdx.x + gx * (blockIdx.y + gy * blockIdx.z);
  int q = nwg >> 3, r = nwg & 7;
  int xcd = orig & 7, idx = orig >> 3;
  int s = (xcd < r ? xcd * (q + 1) : r * (q + 1) + (xcd - r) * q) + idx;
  bx = s % gx;
  int t2 = s / gx;
  by = t2 % gy;
  bz = t2 / gy;
}

__device__ __forceinline__ float block_sum(float v) {
  __shared__ float sb[4];
#pragma unroll
  for (int o = 32; o > 0; o >>= 1) v += __shfl_down(v, o, 64);
  int w = threadIdx.x >> 6;
  __syncthreads();
  if ((threadIdx.x & 63) == 0) sb[w] = v;
  __syncthreads();
  return sb[0] + sb[1] + sb[2] + sb[3];
}

__device__ __forceinline__ float dot8(const float* __restrict__ p,
                                      const float* __restrict__ q) {
  float4 x = *(const float4*)p;
  float4 y = *(const float4*)(p + 4);
  return x.x * q[0] + x.y * q[1] + x.z * q[2] + x.w * q[3] +
         y.x * q[4] + y.y * q[5] + y.z * q[6] + y.w * q[7];
}

// ---------------------------------------------------------------------------
// MFMA GEMM, C = A @ B^T, hi/lo bf16 planes, 3-pass (hh+hl+lh ~ fp32).
// A: row-major [M][K] planes. B: PRE-PACKED fragment-linear planes.
// Tile BMxBN, BK=32, 4 waves (2x2). TRIPLE-buffered LDS, issue-2-ahead
// global_load_lds pipeline with counted s_waitcnt vmcnt(LPW) + raw s_barrier
// (loads for stage s+2 stay in flight across the barrier; never drain to 0
// in the main loop). Requires nsteps >= 3 (all call sites satisfy).
// MODE: 0 plain, 1 split-K (atomicAdd into pre-zeroed Cf), 2 batched (bz).
// ---------------------------------------------------------------------------
template <int BM, int BN, int MODE>
__global__ __launch_bounds__(256) void gemm_hl(
    const short* __restrict__ Ah, const short* __restrict__ Al,
    const short* __restrict__ Bh, const short* __restrict__ Bl,
    const float* __restrict__ bias, float* __restrict__ Cf,
    short* __restrict__ Ch, short* __restrict__ Cl, int K, int ldc, int act,
    int kchunk, long bsA, long bsB, long bsBias, long bsC) {
  constexpr int MFR = BM / 16, NFR = BN / 16;
  constexpr int NA = 2 * MFR, NB = 2 * NFR, LPW = (NA + NB) / 4;
  constexpr int MF_W = MFR / 2, NF_W = NFR / 2;
  constexpr int ABUF = 2 * MFR * 512, BBUF = 2 * NFR * 512;
  __shared__ __align__(16) short As[3][2][MFR][512];
  __shared__ __align__(16) short Bs[3][2][NFR][512];
  int bx, by, bz;
  swz_block(bx, by, bz);
  const int t = threadIdx.x, w = t >> 6, lane = t & 63;
  const int lr = lane & 15, lg = lane >> 4;
  const int m0 = by * BM, n0 = bx * BN;
  const int kst = K >> 5;
  int k0 = 0;
  if (MODE == 1) k0 = bz * kchunk;
  if (MODE == 2) {
    Ah += bz * bsA;
    Al += bz * bsA;
    Bh += bz * bsB;
    Bl += bz * bsB;
    if (bias) bias += bz * bsBias;
    Cf += bz * bsC;
  }
  const int nsteps = (MODE == 1 ? kchunk : K) >> 5;
  const int wmf = (w & 1) * MF_W, wnf = (w >> 1) * NF_W;

  const short* gp[LPW];
  short* lp[LPW];
  int bo[LPW], adv[LPW];
#pragma unroll
  for (int q = 0; q < LPW; q++) {
    int f = w * LPW + q;
    if (f < NA) {
      int p = f & 1, mf = f >> 1;
      gp[q] = (p ? Al : Ah) + (size_t)(m0 + mf * 16 + lr) * K + k0 + lg * 8;
      lp[q] = &As[0][p][mf][0];
      bo[q] = ABUF;
      adv[q] = 32;
    } else {
      int fb = f - NA, p = fb & 1, nf = fb >> 1;
      gp[q] = (p ? Bl : Bh) + ((size_t)(n0 / 16 + nf) * kst + (k0 >> 5)) * 512 +
              lane * 8;
      lp[q] = &Bs[0][p][nf][0];
      bo[q] = BBUF;
      adv[q] = 512;
    }
  }

  auto stage = [&](int bufidx) {
#pragma unroll
    for (int q = 0; q < LPW; q++) {
      g2l16(gp[q], lp[q] + bufidx * bo[q]);
      gp[q] += adv[q];
    }
  };

  fx4 acc[MF_W][NF_W];
#pragma unroll
  for (int i = 0; i < MF_W; i++)
#pragma unroll
    for (int j = 0; j < NF_W; j++) acc[i][j] = (fx4)0.f;

  // prologue: stages 0 and 1 in flight; wait stage 0 landed.
  stage(0);
  stage(1);
  waitcnt_vm<LPW>();
  __builtin_amdgcn_s_barrier();
  __builtin_amdgcn_sched_barrier(0);

  int cur = 0;
  for (int s = 0; s < nsteps; s++) {
    if (s + 2 < nsteps) {
      int nb = cur + 2;
      if (nb >= 3) nb -= 3;
      stage(nb);
    }
    s16x8 af[MF_W][2], bf[NF_W][2];
#pragma unroll
    for (int fm = 0; fm < MF_W; fm++) {
      af[fm][0] = *(const s16x8*)&As[cur][0][wmf + fm][lane * 8];
      af[fm][1] = *(const s16x8*)&As[cur][1][wmf + fm][lane * 8];
    }
#pragma unroll
    for (int fn = 0; fn < NF_W; fn++) {
      bf[fn][0] = *(const s16x8*)&Bs[cur][0][wnf + fn][lane * 8];
      bf[fn][1] = *(const s16x8*)&Bs[cur][1][wnf + fn][lane * 8];
    }
    // pass-outermost: all accs independent between reuses
#pragma unroll
    for (int fm = 0; fm < MF_W; fm++)
#pragma unroll
      for (int fn = 0; fn < NF_W; fn++)
        acc[fm][fn] = __builtin_amdgcn_mfma_f32_16x16x32_bf16(
            af[fm][0], bf[fn][0], acc[fm][fn], 0, 0, 0);
#pragma unroll
    for (int fm = 0; fm < MF_W; fm++)
#pragma unroll
      for (int fn = 0; fn < NF_W; fn++)
        acc[fm][fn] = __builtin_amdgcn_mfma_f32_16x16x32_bf16(
            af[fm][0], bf[fn][1], acc[fm][fn], 0, 0, 0);
#pragma unroll
    for (int fm = 0; fm < MF_W; fm++)
#pragma unroll
      for (int fn = 0; fn < NF_W; fn++)
        acc[fm][fn] = __builtin_amdgcn_mfma_f32_16x16x32_bf16(
            af[fm][1], bf[fn][0], acc[fm][fn], 0, 0, 0);
    // stage s+1 must have landed before next step reads it; stage s+2 stays
    // in flight across the barrier.
    if (s + 2 < nsteps)
      waitcnt_vm<LPW>();
    else
      waitcnt_vm<0>();
    __builtin_amdgcn_s_barrier();
    __builtin_amdgcn_sched_barrier(0);
    cur = (cur == 2) ? 0 : cur + 1;
  }

  const int orow = (lane >> 4) * 4;
#pragma unroll
  for (int fm = 0; fm < MF_W; fm++) {
#pragma unroll
    for (int fn = 0; fn < NF_W; fn++) {
      int col = n0 + (wnf + fn) * 16 + lr;
      if (MODE == 1) {
#pragma unroll
        for (int j = 0; j < 4; j++) {
          int row = m0 + (wmf + fm) * 16 + orow + j;
          atomicAdd(&Cf[(size_t)row * ldc + col], acc[fm][fn][j]);
        }
      } else {
        float bv = bias ? bias[col] : 0.f;
#pragma unroll
        for (int j = 0; j < 4; j++) {
          int row = m0 + (wmf + fm) * 16 + orow + j;
          float v = acc[fm][fn][j] + bv;
          if (act) v = gelu_f(v);
          size_t idx = (size_t)row * ldc + col;
          if (Cf) Cf[idx] = v;
          if (Ch) {
            unsigned short hb = f2bf_u(v);
            Ch[idx] = (short)hb;
            Cl[idx] = (short)f2bf_u(v - bfu2f(hb));
          }
        }
      }
    }
  }
}

// ---------- weight packing: fp32 [N][K] -> fragment-linear hi/lo planes ----
__device__ __forceinline__ void pack_store(const float* src, short* ph,
                                           short* pl, size_t o) {
  float4 a = *(const float4*)src;
  float4 b = *(const float4*)(src + 4);
  float v[8] = {a.x, a.y, a.z, a.w, b.x, b.y, b.z, b.w};
  s16x8 hv, lv;
#pragma unroll
  for (int e = 0; e < 8; e++) {
    unsigned short h = f2bf_u(v[e]);
    hv[e] = (short)h;
    lv[e] = (short)f2bf_u(v[e] - bfu2f(h));
  }
  *(s16x8*)(ph + o) = hv;
  *(s16x8*)(pl + o) = lv;
}

__global__ __launch_bounds__(256) void pack_w_k(const float* __restrict__ W,
                                                short* __restrict__ ph,
                                                short* __restrict__ pl, int K,
                                                int ntiles) {
  int tile = blockIdx.x * 4 + (threadIdx.x >> 6);
  if (tile >= ntiles) return;
  int kst = K >> 5;
  int nf = tile / kst, ks = tile - nf * kst;
  int lane = threadIdx.x & 63;
  int lr = lane & 15, lg = lane >> 4;
  const float* src = W + (size_t)(nf * 16 + lr) * K + ks * 32 + lg * 8;
  pack_store(src, ph, pl, (size_t)tile * 512 + lane * 8);
}

// Packs [Wq;Wk;Wv] (N=2304, K=768).
__global__ __launch_bounds__(256) void pack_qkv_k(const float* __restrict__ Wq,
                                                  const float* __restrict__ Wk,
                                                  const float* __restrict__ Wv,
                                                  short* __restrict__ ph,
                                                  short* __restrict__ pl) {
  int tile = blockIdx.x * 4 + (threadIdx.x >> 6);
  if (tile >= 144 * 24) return;
  int nf = tile / 24, ks = tile - nf * 24;
  int lane = threadIdx.x & 63;
  int lr = lane & 15, lg = lane >> 4;
  int row = nf * 16 + lr;
  const float* src;
  if (row < 768)
    src = Wq + (size_t)row * 768;
  else if (row < 1536)
    src = Wk + (size_t)(row - 768) * 768;
  else
    src = Wv + (size_t)(row - 1536) * 768;
  pack_store(src + ks * 32 + lg * 8, ph, pl, (size_t)tile * 512 + lane * 8);
}

// Packs 120xK matrix into 128-row frags (rows 120..127 zero).
__global__ __launch_bounds__(256) void pack_pad_k(const float* __restrict__ W,
                                                  short* __restrict__ ph,
                                                  short* __restrict__ pl,
                                                  int K) {
  int tile = blockIdx.x * 4 + (threadIdx.x >> 6);
  int kst = K >> 5;
  if (tile >= 8 * kst) return;
  int nf = tile / kst, ks = tile - nf * kst;
  int lane = threadIdx.x & 63;
  int lr = lane & 15, lg = lane >> 4;
  int row = nf * 16 + lr;
  size_t o = (size_t)tile * 512 + lane * 8;
  if (row < 120) {
    pack_store(W + (size_t)row * K + ks * 32 + lg * 8, ph, pl, o);
  } else {
    *(s16x8*)(ph + o) = (s16x8)0;
    *(s16x8*)(pl + o) = (s16x8)0;
  }
}

__global__ __launch_bounds__(256) void concat_k(const float* __restrict__ rf,
                                                const float* __restrict__ cls,
                                                float* __restrict__ h) {
  int idx = blockIdx.x * 256 + threadIdx.x;
  if (idx >= kRows * kD) return;
  int d = idx % kD;
  int row = idx / kD;
  int s = row % kS;
  int b = row / kS;
  h[idx] = (s == 0) ? cls[d] : rf[((long)b * kSR + (s - 1)) * kD + d];
}

__global__ void cc_k(const float* __restrict__ mask, float* __restrict__ cc) {
  int d = threadIdx.x;
  if (d < kND) {
    float s = 0.f;
    for (int r = 0; r < kSR; r++) s += mask[r * kND + d];
    cc[d] = s;
  }
}

__global__ __launch_bounds__(256) void mmat_k(const float* __restrict__ Adn,
                                              const float* __restrict__ Bup,
                                              float* __restrict__ Mm) {
  int g = blockIdx.x;
  int t = threadIdx.x;
  int pair = t & 63;
  int quarter = t >> 6;
  int rp = pair >> 3, r = pair & 7;
  const float* ad = Adn + (long)(g * 8 + rp) * kH;
  const float* bu = Bup + (long)g * kH * 8 + r;
  float acc = 0.f;
  for (int hh = quarter * 768; hh < quarter * 768 + 768; hh++)
    acc += ad[hh] * bu[hh * 8];
  __shared__ float red[256];
  red[t] = acc;
  __syncthreads();
  if (t < 64) Mm[g * 64 + pair] = red[t] + red[t + 64] + red[t + 128] + red[t + 192];
}

// LN -> hi/lo bf16 planes. Optional fused pre-add: x = c2 + b2 + r2 (written
// to hout) when c2 != null, else x read directly.
__global__ __launch_bounds__(256) void ln_bf_k(
    const float* __restrict__ x, const float* __restrict__ c2,
    const float* __restrict__ b2, const float* __restrict__ r2,
    float* __restrict__ hout, const float* __restrict__ g,
    const float* __restrict__ b, short* __restrict__ yh,
    short* __restrict__ yl, float eps) {
  int row = blockIdx.x;
  int t = threadIdx.x;
  long rb = (long)row * kD;
  float v0, v1, v2;
  if (c2) {
    v0 = c2[rb + t] + b2[t] + r2[rb + t];
    v1 = c2[rb + t + 256] + b2[t + 256] + r2[rb + t + 256];
    v2 = c2[rb + t + 512] + b2[t + 512] + r2[rb + t + 512];
    hout[rb + t] = v0;
    hout[rb + t + 256] = v1;
    hout[rb + t + 512] = v2;
  } else {
    v0 = x[rb + t];
    v1 = x[rb + t + 256];
    v2 = x[rb + t + 512];
  }
  float m = block_sum(v0 + v1 + v2) * (1.0f / 768.0f);
  float d0 = v0 - m, d1 = v1 - m, d2 = v2 - m;
  float q = block_sum(d0 * d0 + d1 * d1 + d2 * d2);
  float inv = rsqrtf(q * (1.0f / 768.0f) + eps);
#pragma unroll
  for (int c = 0; c < 3; c++) {
    int tt = t + c * 256;
    float dd = (c == 0 ? d0 : c == 1 ? d1 : d2);
    float val = dd * inv * g[tt] + b[tt];
    unsigned short hb = f2bf_u(val);
    yh[rb + tt] = (short)hb;
    yl[rb + tt] = (short)f2bf_u(val - bfu2f(hb));
  }
}

// Final LN -> fp32 out, fused h = c2 + b2 + r2.
__global__ __launch_bounds__(256) void ln_row_k(
    const float* __restrict__ c2, const float* __restrict__ b2,
    const float* __restrict__ r2, const float* __restrict__ g,
    const float* __restrict__ b, float* __restrict__ y, float eps) {
  int row = blockIdx.x;
  int t = threadIdx.x;
  long rb = (long)row * kD;
  float v0 = c2[rb + t] + b2[t] + r2[rb + t];
  float v1 = c2[rb + t + 256] + b2[t + 256] + r2[rb + t + 256];
  float v2 = c2[rb + t + 512] + b2[t + 512] + r2[rb + t + 512];
  float m = block_sum(v0 + v1 + v2) * (1.0f / 768.0f);
  float d0 = v0 - m, d1 = v1 - m, d2 = v2 - m;
  float q = block_sum(d0 * d0 + d1 * d1 + d2 * d2);
  float inv = rsqrtf(q * (1.0f / 768.0f) + eps);
  y[rb + t] = d0 * inv * g[t] + b[t];
  y[rb + t + 256] = d1 * inv * g[t + 256] + b[t + 256];
  y[rb + t + 512] = d2 * inv * g[t + 512] + b[t + 512];
}

// res1 = a + abias + h ; n2 = LN(res1) -> hi/lo planes
__global__ __launch_bounds__(256) void addln_bf_k(
    const float* __restrict__ a, const float* __restrict__ abias,
    const float* __restrict__ hh, const float* __restrict__ g,
    const float* __restrict__ b, float* __restrict__ r1,
    short* __restrict__ n2h, short* __restrict__ n2l, float eps) {
  int row = blockIdx.x;
  int t = threadIdx.x;
  long rb = (long)row * kD;
  float v0 = a[rb + t] + abias[t] + hh[rb + t];
  float v1 = a[rb + t + 256] + abias[t + 256] + hh[rb + t + 256];
  float v2 = a[rb + t + 512] + abias[t + 512] + hh[rb + t + 512];
  r1[rb + t] = v0;
  r1[rb + t + 256] = v1;
  r1[rb + t + 512] = v2;
  float m = block_sum(v0 + v1 + v2) * (1.0f / 768.0f);
  float d0 = v0 - m, d1 = v1 - m, d2 = v2 - m;
  float q = block_sum(d0 * d0 + d1 * d1 + d2 * d2);
  float inv = rsqrtf(q * (1.0f / 768.0f) + eps);
#pragma unroll
  for (int c = 0; c < 3; c++) {
    int tt = t + c * 256;
    float dd = (c == 0 ? d0 : c == 1 ? d1 : d2);
    float val = dd * inv * g[tt] + b[tt];
    unsigned short hb = f2bf_u(val);
    n2h[rb + tt] = (short)hb;
    n2l[rb + tt] = (short)f2bf_u(val - bfu2f(hb));
  }
}

// One block per (b, head). Reads packed qkv [1920][2304], adds biases inline.
__global__ __launch_bounds__(256) void attn_k(const float* __restrict__ qkv,
                                              const float* __restrict__ bq,
                                              const float* __restrict__ bk,
                                              const float* __restrict__ bv,
                                              short* __restrict__ oh,
                                              short* __restrict__ ol) {
  int blk = blockIdx.x;
  int b = blk / kNH, hh = blk % kNH;
  __shared__ float qs[30][65], ks[30][65], vs[30][65], ps[30][32];
  int t = threadIdx.x;
  long ibase = (long)b * kS * kQKV + hh * 64;
  long obase = (long)b * kS * kD + hh * 64;
  for (int idx = t; idx < 1920; idx += 256) {
    int s = idx >> 6, d = idx & 63;
    long a = ibase + (long)s * kQKV + d;
    int bcol = hh * 64 + d;
    qs[s][d] = qkv[a] + bq[bcol];
    ks[s][d] = qkv[a + 768] + bk[bcol];
    vs[s][d] = qkv[a + 1536] + bv[bcol];
  }
  __syncthreads();
  for (int idx = t; idx < 900; idx += 256) {
    int r = idx / 30, c = idx % 30;
    float acc = 0.f;
#pragma unroll
    for (int d = 0; d < 64; d++) acc += qs[r][d] * ks[c][d];
    ps[r][c] = acc * 0.125f;
  }
  __syncthreads();
  if (t < 30) {
    float mx = -1e30f;
#pragma unroll
    for (int c = 0; c < 30; c++) mx = fmaxf(mx, ps[t][c]);
    float sm = 0.f;
#pragma unroll
    for (int c = 0; c < 30; c++) sm += expf(ps[t][c] - mx);
    float inv = 1.0f / sm;
#pragma unroll
    for (int c = 0; c < 30; c++) ps[t][c] = expf(ps[t][c] - mx) * inv;
  }
  __syncthreads();
  for (int idx = t; idx < 1920; idx += 256) {
    int r = idx >> 6, d = idx & 63;
    float acc = 0.f;
#pragma unroll
    for (int c = 0; c < 30; c++) acc += ps[r][c] * vs[c][d];
    long a = obase + (long)r * kD + d;
    unsigned short hb = f2bf_u(acc);
    oh[a] = (short)hb;
    ol[a] = (short)f2bf_u(acc - bfu2f(hb));
  }
}

// pooled (row d*64+b) = (sum_r mask*ao_nobias)/cc + bao -> hi/lo planes
__global__ __launch_bounds__(256) void pool_k(const float* __restrict__ ao,
                                              const float* __restrict__ bao,
                                              const float* __restrict__ mask,
                                              const float* __restrict__ cc,
                                              short* __restrict__ ph,
                                              short* __restrict__ pl) {
  int blk = blockIdx.x;
  int d = blk >> 6, b = blk & 63;
  __shared__ float mr[32];
  int t = threadIdx.x;
  if (t < kSR) mr[t] = mask[t * kND + d];
  __syncthreads();
  float inv = 1.0f / cc[d];
  for (int hd = t; hd < kD; hd += 256) {
    float acc = 0.f;
    for (int r = 0; r < kSR; r++) acc += mr[r] * ao[((long)b * kS + 1 + r) * kD + hd];
    float v = acc * inv + bao[hd];
    unsigned short hb = f2bf_u(v);
    size_t o = (size_t)blk * kD + hd;
    ph[o] = (short)hb;
    pl[o] = (short)f2bf_u(v - bfu2f(hb));
  }
}

__global__ __launch_bounds__(256) void cls2_k(const float* __restrict__ z,
                                              const float* __restrict__ lng,
                                              const float* __restrict__ lnb,
                                              const float* __restrict__ w2,
                                              const float* __restrict__ b2,
                                              float* __restrict__ da) {
  int blk = blockIdx.x;
  int d = blk >> 6, b = blk & 63;
  int t = threadIdx.x;
  const float* zr = z + (long)blk * 384;
  float v0 = zr[t];
  float v1 = (t < 128) ? zr[256 + t] : 0.f;
  float m = block_sum(v0 + v1) * (1.0f / 384.0f);
  float d0 = v0 - m;
  float d1 = (t < 128) ? v1 - m : 0.f;
  float q = block_sum(d0 * d0 + d1 * d1);
  float inv = rsqrtf(q * (1.0f / 384.0f) + 1e-5f);
  const float* lg = lng + (long)d * 384;
  const float* lb = lnb + (long)d * 384;
  const float* wd = w2 + (long)d * 384;
  float p = gelu_f(d0 * inv * lg[t] + lb[t]) * wd[t];
  if (t < 128) p += gelu_f(d1 * inv * lg[256 + t] + lb[256 + t]) * wd[256 + t];
  float ps = block_sum(p);
  if (t == 0) da[b * kND + d] = (ps + b2[d] > 0.f) ? 1.f : 0.f;
}

__global__ __launch_bounds__(256) void vcomb_k(const float* __restrict__ u,
                                               const float* __restrict__ ia,
                                               const float* __restrict__ Mm,
                                               float* __restrict__ vv) {
  int idx = blockIdx.x * 256 + threadIdx.x;
  if (idx >= kRows * 120) return;
  int row = idx / 120, c = idx % 120;
  int e = c >> 3, rp = c & 7;
  const float* Me = Mm + e * 64 + rp * 8;
  const float* ur = u + (long)row * 128 + e * 8;
  float acc = ia[(long)row * 128 + c];
#pragma unroll
  for (int r = 0; r < 8; r++) acc += 2.0f * Me[r] * ur[r];
  vv[(long)row * 128 + c] = acc;
}

// Per (b,s): base = cwo + bo; expert loop LN_plain + weighted sum; h = acc+res1.
__global__ __launch_bounds__(256) void finaleven_k(
    const float* __restrict__ cwo, const float* __restrict__ bo,
    const float* __restrict__ res1, const float* __restrict__ vv,
    const float* __restrict__ Bd, const float* __restrict__ da,
    const float* __restrict__ mask, float* __restrict__ h) {
  int row = blockIdx.x;
  int b = row / kS, s = row % kS;
  int t = threadIdx.x;
  __shared__ float w[16];
  __shared__ float vvs[120];
  if (t < 120) vvs[t] = vv[(long)row * 128 + t];
  if (t < kND) w[t] = (s >= 1) ? da[b * kND + t] * mask[(s - 1) * kND + t] : 0.f;
  if (t == kND) w[kND] = 1.f;
  __syncthreads();
  float wsum = 0.f;
#pragma unroll
  for (int e = 0; e < kE; e++) wsum += w[e];
  float winv = 1.0f / wsum;
  long rb = (long)row * kD;
  float b0 = cwo[rb + t] + bo[t];
  float b1 = cwo[rb + t + 256] + bo[t + 256];
  float b2v = cwo[rb + t + 512] + bo[t + 512];
  float a0 = 0.f, a1 = 0.f, a2 = 0.f;
  for (int e = 0; e < kE; e++) {
    float we = w[e];
    if (we == 0.f) continue;
    const float* vr = vvs + e * 8;
    float y0 = b0 + 2.0f * dot8(Bd + ((long)(e * kD + t)) * 8, vr);
    float y1 = b1 + 2.0f * dot8(Bd + ((long)(e * kD + t + 256)) * 8, vr);
    float y2 = b2v + 2.0f * dot8(Bd + ((long)(e * kD + t + 512)) * 8, vr);
    float m = block_sum(y0 + y1 + y2) * (1.0f / 768.0f);
    float d0 = y0 - m, d1 = y1 - m, d2 = y2 - m;
    float q = block_sum(d0 * d0 + d1 * d1 + d2 * d2);
    float inv = rsqrtf(q * (1.0f / 768.0f) + 1e-5f);
    float sc = we * winv * inv;
    a0 += sc * d0;
    a1 += sc * d1;
    a2 += sc * d2;
  }
  h[rb + t] = a0 + res1[rb + t];
  h[rb + t + 256] = a1 + res1[rb + t + 256];
  h[rb + t + 512] = a2 + res1[rb + t + 512];
}

}  // namespace

extern "C" void kernel_launch(void* const* d_in, const int* in_sizes, int n_in,
                              void* d_out, int out_size, void* d_ws, size_t ws_size,
                              hipStream_t stream) {
  const float* region = (const float*)d_in[0];
  const float* mask = (const float*)d_in[1];
  const float* cls = (const float*)d_in[2];
  const float* ln1g = (const float*)d_in[3];
  const float* ln1b = (const float*)d_in[4];
  const float* ln2g = (const float*)d_in[5];
  const float* ln2b = (const float*)d_in[6];
  const float* Wq = (const float*)d_in[7];
  const float* bq = (const float*)d_in[8];
  const float* Wk = (const float*)d_in[9];
  const float* bk = (const float*)d_in[10];
  const float* Wv = (const float*)d_in[11];
  const float* bv = (const float*)d_in[12];
  const float* Wao = (const float*)d_in[13];
  const float* bao = (const float*)d_in[14];
  const float* Wi = (const float*)d_in[15];
  const float* bi = (const float*)d_in[16];
  const float* Wo = (const float*)d_in[17];
  const float* bo = (const float*)d_in[18];
  const float* fg = (const float*)d_in[19];
  const float* fb = (const float*)d_in[20];
  const float* cW1 = (const float*)d_in[21];
  const float* cb1 = (const float*)d_in[22];
  const float* clng = (const float*)d_in[23];
  const float* clnb = (const float*)d_in[24];
  const float* cW2 = (const float*)d_in[25];
  const float* cb2 = (const float*)d_in[26];
  const float* Aup = (const float*)d_in[27];
  const float* Bup = (const float*)d_in[28];
  const float* Adn = (const float*)d_in[29];
  const float* Bdn = (const float*)d_in[30];
  float* out = (float*)d_out;

  char* wsb = (char*)d_ws;
  size_t off = 0;
  auto alloc = [&](size_t bytes) {
    char* p = wsb + off;
    off = (off + bytes + 255) & ~(size_t)255;
    return (void*)p;
  };
  float* h = (float*)alloc((size_t)kRows * kD * 4);
  float* qkv = (float*)alloc((size_t)kRows * kQKV * 4);
  float* ao = (float*)alloc((size_t)kRows * kD * 4);
  float* res1 = (float*)alloc((size_t)kRows * kD * 4);
  float* cwo = (float*)alloc((size_t)kRows * kD * 4);
  float* zb = (float*)alloc((size_t)kND * kB * 384 * 4);
  float* da = (float*)alloc((size_t)kB * kND * 4);
  float* ub = (float*)alloc((size_t)kRows * 128 * 4);
  float* ia = (float*)alloc((size_t)kRows * 128 * 4);
  float* vvb = (float*)alloc((size_t)kRows * 128 * 4);
  float* Mm = (float*)alloc((size_t)kNE * kE * 64 * 4);
  float* cc = (float*)alloc(64);
  short* n1h = (short*)alloc((size_t)kRows * kD * 2);
  short* n1l = (short*)alloc((size_t)kRows * kD * 2);
  short* n2h = (short*)alloc((size_t)kRows * kD * 2);
  short* n2l = (short*)alloc((size_t)kRows * kD * 2);
  short* inth = (short*)alloc((size_t)kRows * kH * 2);
  short* intl = (short*)alloc((size_t)kRows * kH * 2);
  short* pooledh = (short*)alloc((size_t)kND * kB * kD * 2);
  short* pooledl = (short*)alloc((size_t)kND * kB * kD * 2);
  // packed weights (frag-linear): tiles * 512 shorts
  short* qkvph = (short*)alloc((size_t)144 * 24 * 512 * 2);
  short* qkvpl = (short*)alloc((size_t)144 * 24 * 512 * 2);
  short* waoph = (short*)alloc((size_t)48 * 24 * 512 * 2);
  short* waopl = (short*)alloc((size_t)48 * 24 * 512 * 2);
  short* wiph = (short*)alloc((size_t)192 * 24 * 512 * 2);
  short* wipl = (short*)alloc((size_t)192 * 24 * 512 * 2);
  short* woph = (short*)alloc((size_t)48 * 96 * 512 * 2);
  short* wopl = (short*)alloc((size_t)48 * 96 * 512 * 2);
  short* luph = (short*)alloc((size_t)8 * 24 * 512 * 2);
  short* lupl = (short*)alloc((size_t)8 * 24 * 512 * 2);
  short* ldph = (short*)alloc((size_t)8 * 96 * 512 * 2);
  short* ldpl = (short*)alloc((size_t)8 * 96 * 512 * 2);
  short* cw1ph = (short*)alloc((size_t)336 * 24 * 512 * 2);
  short* cw1pl = (short*)alloc((size_t)336 * 24 * 512 * 2);

  concat_k<<<(kRows * kD + 255) / 256, 256, 0, stream>>>(region, cls, h);
  cc_k<<<1, 32, 0, stream>>>(mask, cc);
  mmat_k<<<kNE * kE, 256, 0, stream>>>(Adn, Bup, Mm);

  const int nDD = kD * kD;
  const int nDH = kD * kH;

  // n1 planes for layer 0
  ln_bf_k<<<kRows, 256, 0, stream>>>(h, nullptr, nullptr, nullptr, nullptr, ln1g,
                                     ln1b, n1h, n1l, 1e-12f);

  for (int i = 0; i < kL; i++) {
    int le = i >> 1;
    bool even = (i % 2) == 0;
    // weight packing
    pack_qkv_k<<<(144 * 24) / 4, 256, 0, stream>>>(
        Wq + (long)i * nDD, Wk + (long)i * nDD, Wv + (long)i * nDD, qkvph, qkvpl);
    pack_w_k<<<(48 * 24) / 4, 256, 0, stream>>>(Wao + (long)i * nDD, waoph, waopl,
                                                768, 48 * 24);
    pack_w_k<<<(192 * 24) / 4, 256, 0, stream>>>(Wi + (long)i * nDH, wiph, wipl,
                                                 768, 192 * 24);
    pack_w_k<<<(48 * 96) / 4, 256, 0, stream>>>(Wo + (long)i * nDH, woph, wopl,
                                                3072, 48 * 96);

    // QKV (N=2304, plain)
    gemm_hl<128, 64, 0><<<dim3(36, 15), 256, 0, stream>>>(
        n1h, n1l, qkvph, qkvpl, nullptr, qkv, nullptr, nullptr, 768, kQKV, 0, 0,
        0, 0, 0, 0);
    attn_k<<<kB * kNH, 256, 0, stream>>>(qkv, bq + i * kD, bk + i * kD,
                                         bv + i * kD, n1h, n1l);
    // Wao (split-K x2)
    hipMemsetAsync(ao, 0, (size_t)kRows * kD * 4, stream);
    gemm_hl<128, 64, 1><<<dim3(12, 15, 2), 256, 0, stream>>>(
        n1h, n1l, waoph, waopl, nullptr, ao, nullptr, nullptr, 768, kD, 0, 384,
        0, 0, 0, 0);
    addln_bf_k<<<kRows, 256, 0, stream>>>(ao, bao + i * kD, h, ln2g + i * kD,
                                          ln2b + i * kD, res1, n2h, n2l, 1e-12f);
    // Wi (N=3072, gelu, planes out)
    gemm_hl<128, 64, 0><<<dim3(48, 15), 256, 0, stream>>>(
        n2h, n2l, wiph, wipl, bi + i * kH, nullptr, inth, intl, 768, kH, 1, 0,
        0, 0, 0, 0);
    // Wo (split-K x4)
    hipMemsetAsync(cwo, 0, (size_t)kRows * kD * 4, stream);
    gemm_hl<128, 64, 1><<<dim3(12, 15, 4), 256, 0, stream>>>(
        inth, intl, woph, wopl, nullptr, cwo, nullptr, nullptr, 3072, kD, 0, 768,
        0, 0, 0, 0);
    if (even) {
      pack_pad_k<<<(8 * 24 + 3) / 4, 256, 0, stream>>>(
          Aup + (long)le * kE * 8 * kD, luph, lupl, 768);
      pack_pad_k<<<(8 * 96) / 4, 256, 0, stream>>>(
          Adn + (long)le * kE * 8 * kH, ldph, ldpl, 3072);
      pack_w_k<<<(336 * 24) / 4, 256, 0, stream>>>(
          cW1 + (long)le * kND * 384 * kD, cw1ph, cw1pl, 768, 336 * 24);
      hipMemsetAsync(ub, 0, (size_t)kRows * 128 * 4, stream);
      hipMemsetAsync(ia, 0, (size_t)kRows * 128 * 4, stream);
      gemm_hl<128, 64, 1><<<dim3(2, 15, 8), 256, 0, stream>>>(
          n2h, n2l, luph, lupl, nullptr, ub, nullptr, nullptr, 768, 128, 0, 96,
          0, 0, 0, 0);
      gemm_hl<128, 64, 1><<<dim3(2, 15, 16), 256, 0, stream>>>(
          inth, intl, ldph, ldpl, nullptr, ia, nullptr, nullptr, 3072, 128, 0,
          192, 0, 0, 0, 0);
      pool_k<<<kND * kB, 256, 0, stream>>>(ao, bao + i * kD, mask, cc, pooledh,
                                           pooledl);
      // batched classifier GEMM: z = disease d (14), M=64, N=384, K=768
      gemm_hl<64, 64, 2><<<dim3(6, 1, 14), 256, 0, stream>>>(
          pooledh, pooledl, cw1ph, cw1pl, cb1 + (long)le * kND * 384, zb,
          nullptr, nullptr, 768, 384, 0, 0, (long)64 * kD, (long)576 * 512, 384,
          (long)64 * 384);
      cls2_k<<<kND * kB, 256, 0, stream>>>(zb, clng + (long)le * kND * 384,
                                           clnb + (long)le * kND * 384,
                                           cW2 + (long)le * kND * 384,
                                           cb2 + le * kND, da);
      vcomb_k<<<(kRows * 120 + 255) / 256, 256, 0, stream>>>(
          ub, ia, Mm + le * kE * 64, vvb);
      finaleven_k<<<kRows, 256, 0, stream>>>(cwo, bo + i * kD, res1, vvb,
                                             Bdn + (long)le * kE * kD * 8, da,
                                             mask, h);
      ln_bf_k<<<kRows, 256, 0, stream>>>(h, nullptr, nullptr, nullptr, nullptr,
                                         ln1g + (i + 1) * kD, ln1b + (i + 1) * kD,
                                         n1h, n1l, 1e-12f);
    } else if (i < kL - 1) {
      ln_bf_k<<<kRows, 256, 0, stream>>>(nullptr, cwo, bo + i * kD, res1, h,
                                         ln1g + (i + 1) * kD, ln1b + (i + 1) * kD,
                                         n1h, n1l, 1e-12f);
    } else {
      ln_row_k<<<kRows, 256, 0, stream>>>(cwo, bo + i * kD, res1, fg, fb, out,
                                          1e-12f);
    }
  }
}